// Round 2
// baseline (10823.989 us; speedup 1.0000x reference)
//
#include <hip/hip_runtime.h>
#include <math.h>

#define NN 50000
#define NE 120000
#define FN 64
#define NEA 16
#define NR 4
#define NH 4
#define HID 128
#define NL 3
#define IDE 32
#define RED 8
#define NG 64
#define NC 10
#define KH 128
#define FFH 256
#define HH 512  // NH*HID

// ---- monotone float<->uint key for atomic max (handles negatives & -0.0) ----
__device__ __forceinline__ unsigned fkey(float f) {
  unsigned u = __float_as_uint(f);
  return (u & 0x80000000u) ? ~u : (u | 0x80000000u);
}
__device__ __forceinline__ float unkey(unsigned k) {
  unsigned u = (k & 0x80000000u) ? (k ^ 0x80000000u) : ~k;
  return __uint_as_float(u);
}

// ---- generic fp32 GEMM: C[n][m] = A[n][:K] . W[m][:K] + bias[m], opt silu ----
// W row-major (mout, K). mout multiple of 64, K multiple of 32.
__global__ __launch_bounds__(256) void gemm_nt(
    const float* __restrict__ A, const float* __restrict__ W,
    const float* __restrict__ bias, float* __restrict__ C,
    int nrows, int K, int mout, int act) {
  __shared__ float As[64][33];
  __shared__ float Ws[64][33];
  int tid = threadIdx.x;
  int tx = tid & 15, ty = tid >> 4;
  int rowBase = blockIdx.x * 64;
  int colBase = blockIdx.y * 64;
  float acc[4][4] = {{0.f}};
  for (int k0 = 0; k0 < K; k0 += 32) {
#pragma unroll
    for (int i = 0; i < 8; ++i) {
      int idx = i * 256 + tid;
      int r = idx >> 5, c = idx & 31;
      int gr = rowBase + r;
      As[r][c] = (gr < nrows) ? A[(size_t)gr * K + k0 + c] : 0.f;
      Ws[r][c] = W[(size_t)(colBase + r) * K + k0 + c];
    }
    __syncthreads();
#pragma unroll
    for (int kk = 0; kk < 32; ++kk) {
      float a[4], b[4];
#pragma unroll
      for (int i = 0; i < 4; ++i) a[i] = As[ty * 4 + i][kk];
#pragma unroll
      for (int j = 0; j < 4; ++j) b[j] = Ws[tx * 4 + j][kk];
#pragma unroll
      for (int i = 0; i < 4; ++i)
#pragma unroll
        for (int j = 0; j < 4; ++j) acc[i][j] += a[i] * b[j];
    }
    __syncthreads();
  }
#pragma unroll
  for (int i = 0; i < 4; ++i) {
    int r = rowBase + ty * 4 + i;
    if (r >= nrows) continue;
#pragma unroll
    for (int j = 0; j < 4; ++j) {
      int c = colBase + tx * 4 + j;
      float v = acc[i][j] + bias[c];
      if (act) v = v / (1.f + expf(-v));  // silu
      C[(size_t)r * mout + c] = v;
    }
  }
}

// ---- build concat(x, id_emb[id_token]) -> (N, 96) ----
__global__ void build_xin(const float* __restrict__ x, const int* __restrict__ idtok,
                          const float* __restrict__ emb, float* __restrict__ xin) {
  int i = blockIdx.x * blockDim.x + threadIdx.x;
  if (i >= NN * 96) return;
  int n = i / 96, k = i - n * 96;
  xin[i] = (k < FN) ? x[(size_t)n * FN + k] : emb[(size_t)idtok[n] * IDE + (k - FN)];
}

// ---- per-layer gate = softmax(rel_gate[l]); cb = sum_r gate[r]*conv_bias[l,r,:] ----
__global__ void gate_cb(const float* __restrict__ rg, const float* __restrict__ cbias,
                        float* __restrict__ gate, float* __restrict__ cb) {
  __shared__ float g[NR];
  int t = threadIdx.x;
  if (t == 0) {
    float mx = rg[0];
    for (int r = 1; r < NR; ++r) mx = fmaxf(mx, rg[r]);
    float s = 0.f, tmp[NR];
    for (int r = 0; r < NR; ++r) { tmp[r] = expf(rg[r] - mx); s += tmp[r]; }
    for (int r = 0; r < NR; ++r) { g[r] = tmp[r] / s; gate[r] = g[r]; }
  }
  __syncthreads();
  float c = 0.f;
  for (int r = 0; r < NR; ++r) c += g[r] * cbias[r * HID + t];
  cb[t] = c;
}

// ---- pass A (per rel,head): per-edge logit + segment max. One wave per edge. ----
__global__ __launch_bounds__(256) void edge_logit_h(
    const int* __restrict__ ei, const int* __restrict__ et,
    const float* __restrict__ eattr, const float* __restrict__ relemb,
    const float* __restrict__ wedge, const float* __restrict__ attw,
    const float* __restrict__ xl, const float* __restrict__ xr,
    float* __restrict__ logit, unsigned* __restrict__ mkey, int rel) {
  int wave = threadIdx.x >> 6, lane = threadIdx.x & 63;
  int e = blockIdx.x * 4 + wave;
  if (e >= NE || et[e] != rel) return;
  int src = ei[e], dst = ei[NE + e];
  const float* eap = eattr + (size_t)e * NEA;
  const float* xls = xl + (size_t)src * HID;
  const float* xrd = xr + (size_t)dst * HID;
  float acc = 0.f;
#pragma unroll
  for (int j = 0; j < 2; ++j) {
    int c = lane + j * 64;
    const float* wr = wedge + (size_t)c * 24;
    float eev = 0.f;
#pragma unroll
    for (int k = 0; k < NEA; ++k) eev += eap[k] * wr[k];
#pragma unroll
    for (int k = 0; k < RED; ++k) eev += relemb[k] * wr[NEA + k];
    float s = xls[c] + xrd[c] + eev;
    s = (s > 0.f) ? s : 0.2f * s;  // leaky_relu 0.2
    acc += s * attw[c];
  }
#pragma unroll
  for (int o = 32; o > 0; o >>= 1) acc += __shfl_xor(acc, o);
  if (lane == 0) {
    logit[e] = acc;
    atomicMax(mkey + dst, fkey(acc));
  }
}

// ---- pass B: aexp = exp(logit - m[dst]); den += aexp ----
__global__ void edge_exp_h(const int* __restrict__ ei, const int* __restrict__ et,
                           const float* __restrict__ logit, const unsigned* __restrict__ mkey,
                           float* __restrict__ aexp, float* __restrict__ den, int rel) {
  int e = blockIdx.x * blockDim.x + threadIdx.x;
  if (e >= NE || et[e] != rel) return;
  int dst = ei[NE + e];
  float m = unkey(mkey[dst]);
  float a = expf(logit[e] - m);
  aexp[e] = a;
  atomicAdd(den + dst, a);
}

// ---- pass C: hmsg[dst] += gate[r]/H * (aexp/den) * xl[src,:] ----
__global__ __launch_bounds__(128) void edge_aggr_h(
    const int* __restrict__ ei, const int* __restrict__ et,
    const float* __restrict__ aexp, const float* __restrict__ den,
    const float* __restrict__ xl, float* __restrict__ hmsg,
    const float* __restrict__ gate, int rel) {
  int e = blockIdx.x;
  if (et[e] != rel) return;
  int t = threadIdx.x;
  int src = ei[e], dst = ei[NE + e];
  float d = den[dst];
  d = (d == 0.f) ? 1.f : d;
  float w = gate[rel] * 0.25f * aexp[e] / d;
  atomicAdd(hmsg + (size_t)dst * HID + t, w * xl[(size_t)src * HID + t]);
}

// ---- h = layernorm(h + add (+ cb)) * w + b, one wave per 128-dim row ----
__global__ __launch_bounds__(256) void add_ln(
    float* __restrict__ h, const float* __restrict__ add, const float* __restrict__ cb,
    const float* __restrict__ w, const float* __restrict__ b, int nrows) {
  int wave = threadIdx.x >> 6, lane = threadIdx.x & 63;
  int row = blockIdx.x * 4 + wave;
  if (row >= nrows) return;
  size_t base = (size_t)row * HID;
  float x0 = h[base + lane] + add[base + lane];
  float x1 = h[base + 64 + lane] + add[base + 64 + lane];
  if (cb) { x0 += cb[lane]; x1 += cb[64 + lane]; }
  float s = x0 + x1;
#pragma unroll
  for (int o = 32; o > 0; o >>= 1) s += __shfl_xor(s, o);
  float mean = s * (1.f / 128.f);
  float d0 = x0 - mean, d1 = x1 - mean;
  float v = d0 * d0 + d1 * d1;
#pragma unroll
  for (int o = 32; o > 0; o >>= 1) v += __shfl_xor(v, o);
  float inv = 1.f / sqrtf(v * (1.f / 128.f) + 1e-5f);
  h[base + lane] = d0 * inv * w[lane] + b[lane];
  h[base + 64 + lane] = d1 * inv * w[64 + lane] + b[64 + lane];
}

// ---- readout accumulation ----
__global__ __launch_bounds__(128) void readout_acc(
    const float* __restrict__ h, const int* __restrict__ batch,
    float* __restrict__ cnt, float* __restrict__ sum, unsigned* __restrict__ maxk) {
  int n = blockIdx.x, t = threadIdx.x;
  int b = batch[n];
  float v = h[(size_t)n * HID + t];
  atomicAdd(sum + (size_t)b * HID + t, v);
  atomicMax(maxk + (size_t)b * HID + t, fkey(v));
  if (t == 0) atomicAdd(cnt + b, 1.f);
}

// ---- g = layernorm(concat(mean, max)) ----
__global__ __launch_bounds__(256) void readout_final(
    const float* __restrict__ cnt, const float* __restrict__ sum,
    const unsigned* __restrict__ maxk, const float* __restrict__ w,
    const float* __restrict__ b, float* __restrict__ g) {
  int bg = blockIdx.x, t = threadIdx.x;
  __shared__ float red[256];
  float c = fmaxf(cnt[bg], 1.f);
  float x = (t < HID) ? sum[(size_t)bg * HID + t] / c
                      : unkey(maxk[(size_t)bg * HID + (t - HID)]);
  red[t] = x;
  __syncthreads();
  for (int s = 128; s > 0; s >>= 1) {
    if (t < s) red[t] += red[t + s];
    __syncthreads();
  }
  float mean = red[0] * (1.f / 256.f);
  __syncthreads();
  float d = x - mean;
  red[t] = d * d;
  __syncthreads();
  for (int s = 128; s > 0; s >>= 1) {
    if (t < s) red[t] += red[t + s];
    __syncthreads();
  }
  float inv = 1.f / sqrtf(red[0] * (1.f / 256.f) + 1e-5f);
  g[(size_t)bg * 256 + t] = d * inv * w[t] + b[t];
}

// ---- order-3 B-spline bases on 12-knot grid -> 8 bases ----
__device__ __forceinline__ void bspline8(float x, const float* __restrict__ t,
                                         float* __restrict__ out) {
  float bs[11];
#pragma unroll
  for (int j = 0; j < 11; ++j) bs[j] = (x >= t[j] && x < t[j + 1]) ? 1.f : 0.f;
#pragma unroll
  for (int k = 1; k <= 3; ++k) {
    for (int j = 0; j < 11 - k; ++j) {
      bs[j] = (x - t[j]) / (t[j + k] - t[j]) * bs[j] +
              (t[j + k + 1] - x) / (t[j + k + 1] - t[j + 1]) * bs[j + 1];
    }
  }
#pragma unroll
  for (int j = 0; j < 8; ++j) out[j] = bs[j];
}

// ---- KAN layer 1: (64,256) -> (64,128) ----
__global__ __launch_bounds__(128) void kan1(
    const float* __restrict__ g, const float* __restrict__ bw,
    const float* __restrict__ sw, const float* __restrict__ sc,
    const float* __restrict__ grid, float* __restrict__ z) {
  int bg = blockIdx.x, t = threadIdx.x;
  __shared__ float B[256][8];
  __shared__ float sg[256];
  for (int i = t; i < 256; i += 128) {
    float x = g[(size_t)bg * 256 + i];
    sg[i] = x / (1.f + expf(-x));
    bspline8(x, grid + (size_t)i * 12, B[i]);
  }
  __syncthreads();
  float acc = 0.f;
  for (int i = 0; i < 256; ++i) {
    acc += sg[i] * bw[(size_t)t * 256 + i];
    const float* swp = sw + ((size_t)t * 256 + i) * 8;
    float sp = 0.f;
#pragma unroll
    for (int k = 0; k < 8; ++k) sp += B[i][k] * swp[k];
    acc += sp * sc[(size_t)t * 256 + i];
  }
  z[(size_t)bg * KH + t] = acc;
}

// ---- KAN layer 2: (64,128) -> (64,10) ----
__global__ __launch_bounds__(128) void kan2(
    const float* __restrict__ z, const float* __restrict__ bw,
    const float* __restrict__ sw, const float* __restrict__ sc,
    const float* __restrict__ grid, float* __restrict__ out) {
  int bg = blockIdx.x, t = threadIdx.x;
  __shared__ float B[128][8];
  __shared__ float sz[128];
  float x = z[(size_t)bg * KH + t];
  sz[t] = x / (1.f + expf(-x));
  bspline8(x, grid + (size_t)t * 12, B[t]);
  __syncthreads();
  if (t < NC) {
    float acc = 0.f;
    for (int i = 0; i < 128; ++i) {
      acc += sz[i] * bw[(size_t)t * 128 + i];
      const float* swp = sw + ((size_t)t * 128 + i) * 8;
      float sp = 0.f;
#pragma unroll
      for (int k = 0; k < 8; ++k) sp += B[i][k] * swp[k];
      acc += sp * sc[(size_t)t * 128 + i];
    }
    out[(size_t)bg * NC + t] = acc;
  }
}

extern "C" void kernel_launch(void* const* d_in, const int* in_sizes, int n_in,
                              void* d_out, int out_size, void* d_ws, size_t ws_size,
                              hipStream_t stream) {
  const float* x       = (const float*)d_in[0];
  const float* eattr   = (const float*)d_in[1];
  const int*   idtok   = (const int*)d_in[2];
  const int*   ei      = (const int*)d_in[3];
  const int*   etype   = (const int*)d_in[4];
  const int*   batch   = (const int*)d_in[5];
  const float* idemb   = (const float*)d_in[6];
  const float* inw     = (const float*)d_in[7];
  const float* inb     = (const float*)d_in[8];
  const float* relemb  = (const float*)d_in[9];
  const float* linlw   = (const float*)d_in[10];
  const float* linlb   = (const float*)d_in[11];
  const float* linrw   = (const float*)d_in[12];
  const float* linrb   = (const float*)d_in[13];
  const float* linew   = (const float*)d_in[14];
  const float* attw    = (const float*)d_in[15];
  const float* convb   = (const float*)d_in[16];
  const float* relgate = (const float*)d_in[17];
  const float* n1w     = (const float*)d_in[18];
  const float* n1b     = (const float*)d_in[19];
  const float* n2w     = (const float*)d_in[20];
  const float* n2b     = (const float*)d_in[21];
  const float* f1w     = (const float*)d_in[22];
  const float* f1b     = (const float*)d_in[23];
  const float* f2w     = (const float*)d_in[24];
  const float* f2b     = (const float*)d_in[25];
  const float* rnw     = (const float*)d_in[26];
  const float* rnb     = (const float*)d_in[27];
  const float* bw1     = (const float*)d_in[28];
  const float* sw1     = (const float*)d_in[29];
  const float* sc1     = (const float*)d_in[30];
  const float* grid1   = (const float*)d_in[31];
  const float* bw2     = (const float*)d_in[32];
  const float* sw2     = (const float*)d_in[33];
  const float* sc2     = (const float*)d_in[34];
  const float* grid2   = (const float*)d_in[35];
  float* out = (float*)d_out;
  float* ws  = (float*)d_ws;

  // Workspace layout (~104 MB total; per-(rel,head) processing keeps it small)
  size_t off = 0;
  float* h    = ws + off; off += (size_t)NN * HID;   //  6.4M
  float* hmsg = ws + off; off += (size_t)NN * HID;   //  6.4M
  float* pool = ws + off; off += (size_t)NN * FFH;   // 12.8M (xin | xl_h+xr_h | f1)
  float* logit = ws + off; off += (size_t)NE;        //  0.12M
  float* aexp  = ws + off; off += (size_t)NE;        //  0.12M
  unsigned* mkey = (unsigned*)(ws + off); off += (size_t)NN;  // contiguous with den
  float* den  = ws + off; off += (size_t)NN;
  float* gate = ws + off; off += NR;
  float* cb   = ws + off; off += HID;
  float* cnt  = ws + off; off += NG;                 // cnt+sum+maxk contiguous
  float* sum  = ws + off; off += (size_t)NG * HID;
  unsigned* maxk = (unsigned*)(ws + off); off += (size_t)NG * HID;
  float* g    = ws + off; off += (size_t)NG * 256;
  float* z    = ws + off; off += (size_t)NG * KH;
  float* xin  = pool;                  // N*96, only before layer loop
  float* xl_h = pool;                  // N*128, edge phase
  float* xr_h = pool + (size_t)NN * HID;
  float* f1   = pool;                  // N*256, FFN phase (xl/xr dead by then)
  (void)in_sizes; (void)n_in; (void)out_size; (void)ws_size;

  // input projection: h = silu(concat(x, id_emb[tok]) @ in_proj_w.T + b)
  build_xin<<<(NN * 96 + 255) / 256, 256, 0, stream>>>(x, idtok, idemb, xin);
  dim3 gin((NN + 63) / 64, HID / 64);
  gemm_nt<<<gin, 256, 0, stream>>>(xin, inw, inb, h, NN, 96, HID, 1);

  for (int l = 0; l < NL; ++l) {
    gate_cb<<<1, 128, 0, stream>>>(relgate + l * NR, convb + (size_t)l * NR * HID, gate, cb);
    hipMemsetAsync(hmsg, 0, (size_t)NN * HID * sizeof(float), stream);
    for (int r = 0; r < NR; ++r) {
      int lr = l * NR + r;
      for (int hh = 0; hh < NH; ++hh) {
        dim3 g128((NN + 63) / 64, HID / 64);
        gemm_nt<<<g128, 256, 0, stream>>>(
            h, linlw + (size_t)lr * HH * HID + (size_t)hh * HID * HID,
            linlb + (size_t)lr * HH + hh * HID, xl_h, NN, HID, HID, 0);
        gemm_nt<<<g128, 256, 0, stream>>>(
            h, linrw + (size_t)lr * HH * HID + (size_t)hh * HID * HID,
            linrb + (size_t)lr * HH + hh * HID, xr_h, NN, HID, HID, 0);
        hipMemsetAsync(mkey, 0, (size_t)NN * sizeof(float) * 2, stream);  // mkey+den
        edge_logit_h<<<(NE + 3) / 4, 256, 0, stream>>>(
            ei, etype, eattr, relemb + (size_t)lr * RED,
            linew + (size_t)lr * HH * 24 + (size_t)hh * HID * 24,
            attw + (size_t)lr * NH * HID + (size_t)hh * HID,
            xl_h, xr_h, logit, mkey, r);
        edge_exp_h<<<(NE + 255) / 256, 256, 0, stream>>>(ei, etype, logit, mkey, aexp, den, r);
        edge_aggr_h<<<NE, 128, 0, stream>>>(ei, etype, aexp, den, xl_h, hmsg, gate, r);
      }
    }
    add_ln<<<(NN + 3) / 4, 256, 0, stream>>>(h, hmsg, cb, n1w + l * HID, n1b + l * HID, NN);
    dim3 gf1((NN + 63) / 64, FFH / 64);
    gemm_nt<<<gf1, 256, 0, stream>>>(h, f1w + (size_t)l * FFH * HID,
                                     f1b + (size_t)l * FFH, f1, NN, HID, FFH, 1);
    dim3 gf2((NN + 63) / 64, HID / 64);
    gemm_nt<<<gf2, 256, 0, stream>>>(f1, f2w + (size_t)l * HID * FFH,
                                     f2b + (size_t)l * HID, hmsg, NN, FFH, HID, 0);
    add_ln<<<(NN + 3) / 4, 256, 0, stream>>>(h, hmsg, nullptr, n2w + l * HID, n2b + l * HID, NN);
  }

  hipMemsetAsync(cnt, 0, (size_t)(NG + NG * HID * 2) * sizeof(float), stream);
  readout_acc<<<NN, 128, 0, stream>>>(h, batch, cnt, sum, maxk);
  readout_final<<<NG, 256, 0, stream>>>(cnt, sum, maxk, rnw, rnb, g);
  kan1<<<NG, 128, 0, stream>>>(g, bw1, sw1, sc1, grid1, z);
  kan2<<<NG, 128, 0, stream>>>(z, bw2, sw2, sc2, grid2, out);
}

// Round 3
// 5428.894 us; speedup vs baseline: 1.9938x; 1.9938x over previous
//
#include <hip/hip_runtime.h>
#include <math.h>

#define NN 50000
#define NE 120000
#define FN 64
#define NEA 16
#define NR 4
#define NH 4
#define HID 128
#define NL 3
#define IDE 32
#define RED 8
#define NG 64
#define NC 10
#define KH 128
#define FFH 256
#define EPB 8

typedef short bf16x8 __attribute__((ext_vector_type(8)));
typedef float f32x4 __attribute__((ext_vector_type(4)));

// ---- bf16 helpers (RNE) ----
__device__ __forceinline__ unsigned short f2b(float f) {
  unsigned u = __float_as_uint(f);
  unsigned r = (u + 0x7FFFu + ((u >> 16) & 1u)) >> 16;
  return (unsigned short)r;
}
__device__ __forceinline__ float b2f(unsigned short b) {
  return __uint_as_float((unsigned)b << 16);
}

// ---- monotone float<->uint key for atomic max ----
__device__ __forceinline__ unsigned fkey(float f) {
  unsigned u = __float_as_uint(f);
  return (u & 0x80000000u) ? ~u : (u | 0x80000000u);
}
__device__ __forceinline__ float unkey(unsigned k) {
  unsigned u = (k & 0x80000000u) ? (k ^ 0x80000000u) : ~k;
  return __uint_as_float(u);
}

// ---- f32 -> bf16 bulk convert (n multiple of 4) ----
__global__ void cvt_bf16(const float* __restrict__ s, unsigned short* __restrict__ d, int n4) {
  int i = blockIdx.x * blockDim.x + threadIdx.x;
  if (i >= n4) return;
  float4 v = ((const float4*)s)[i];
  ushort4 o;
  o.x = f2b(v.x); o.y = f2b(v.y); o.z = f2b(v.z); o.w = f2b(v.w);
  ((ushort4*)d)[i] = o;
}

// ---- MFMA bf16 GEMM: C[n][m] = A[n][:K].W[m][:K] + bias[m]; opt silu; out f32 or bf16 ----
// A (nrows,K) bf16 row-major; W (mout,K) bf16 row-major. K mult of 32, mout mult of 128.
__global__ __launch_bounds__(256) void gemm_bf16(
    const unsigned short* __restrict__ A, const unsigned short* __restrict__ W,
    const float* __restrict__ bias, float* __restrict__ Cf, unsigned short* __restrict__ Cb,
    int nrows, int K, int mout, int act) {
  __shared__ unsigned short As[128][40];  // +8 pad: ds_read_b128 2-way (free)
  __shared__ unsigned short Ws[128][40];
  int t = threadIdx.x;
  int lane = t & 63, w = t >> 6;
  int wm = w >> 1, wn = w & 1;
  int q = lane >> 4, mr = lane & 15;
  int rowBase = blockIdx.x * 128;
  int colBase = blockIdx.y * 128;
  f32x4 acc[4][4] = {};
  for (int k0 = 0; k0 < K; k0 += 32) {
#pragma unroll
    for (int half = 0; half < 2; ++half) {
      int c = t + half * 256;      // 0..511 : 128 rows x 4 chunks of 16B
      int row = c >> 2, c16 = c & 3;
      int gr = rowBase + row;
      bf16x8 av = {0, 0, 0, 0, 0, 0, 0, 0};
      if (gr < nrows) av = *(const bf16x8*)(A + (size_t)gr * K + k0 + c16 * 8);
      *(bf16x8*)&As[row][c16 * 8] = av;
      bf16x8 wv = *(const bf16x8*)(W + (size_t)(colBase + row) * K + k0 + c16 * 8);
      *(bf16x8*)&Ws[row][c16 * 8] = wv;
    }
    __syncthreads();
    bf16x8 af[4], bfr[4];
#pragma unroll
    for (int mt = 0; mt < 4; ++mt) af[mt] = *(const bf16x8*)&As[wm * 64 + mt * 16 + mr][q * 8];
#pragma unroll
    for (int nt = 0; nt < 4; ++nt) bfr[nt] = *(const bf16x8*)&Ws[wn * 64 + nt * 16 + mr][q * 8];
#pragma unroll
    for (int mt = 0; mt < 4; ++mt)
#pragma unroll
      for (int nt = 0; nt < 4; ++nt)
        acc[mt][nt] = __builtin_amdgcn_mfma_f32_16x16x32_bf16(af[mt], bfr[nt], acc[mt][nt], 0, 0, 0);
    __syncthreads();
  }
#pragma unroll
  for (int mt = 0; mt < 4; ++mt)
#pragma unroll
    for (int nt = 0; nt < 4; ++nt)
#pragma unroll
      for (int r = 0; r < 4; ++r) {
        int row = rowBase + wm * 64 + mt * 16 + q * 4 + r;
        int col = colBase + wn * 64 + nt * 16 + mr;
        if (row < nrows) {
          float v = acc[mt][nt][r] + bias[col];
          if (act) v = v / (1.f + expf(-v));
          if (Cb) Cb[(size_t)row * mout + col] = f2b(v);
          else    Cf[(size_t)row * mout + col] = v;
        }
      }
}

// ---- concat(x, id_emb[tok]) -> bf16 (N,96) ----
__global__ void build_xin_bf(const float* __restrict__ x, const int* __restrict__ idtok,
                             const float* __restrict__ emb, unsigned short* __restrict__ xin) {
  int i = blockIdx.x * blockDim.x + threadIdx.x;
  if (i >= NN * 96) return;
  int n = i / 96, k = i - n * 96;
  float v = (k < FN) ? x[(size_t)n * FN + k] : emb[(size_t)idtok[n] * IDE + (k - FN)];
  xin[i] = f2b(v);
}

// ---- edge lists per relation ----
__global__ void hist_et(const int* __restrict__ et, int* __restrict__ ecnt) {
  int i = blockIdx.x * blockDim.x + threadIdx.x;
  if (i < NE) atomicAdd(&ecnt[et[i]], 1);
}
__global__ void scan_et(const int* __restrict__ ecnt, int* __restrict__ ebase) {
  if (threadIdx.x == 0 && blockIdx.x == 0) {
    int b = 0;
    for (int r = 0; r < NR; ++r) { ebase[r] = b; b += ecnt[r]; }
    ebase[NR] = b;
  }
}
__global__ void scatter_et(const int* __restrict__ et, const int* __restrict__ ebase,
                           int* __restrict__ ecur, int* __restrict__ elist) {
  int i = blockIdx.x * blockDim.x + threadIdx.x;
  if (i >= NE) return;
  int r = et[i];
  int p = atomicAdd(&ecur[r], 1);
  elist[ebase[r] + p] = i;
}

// ---- per-layer gate + fused conv_bias ----
__global__ void gate_cb(const float* __restrict__ rg, const float* __restrict__ cbias,
                        float* __restrict__ gate, float* __restrict__ cb) {
  __shared__ float g[NR];
  int t = threadIdx.x;
  if (t == 0) {
    float mx = rg[0];
    for (int r = 1; r < NR; ++r) mx = fmaxf(mx, rg[r]);
    float s = 0.f, tmp[NR];
    for (int r = 0; r < NR; ++r) { tmp[r] = expf(rg[r] - mx); s += tmp[r]; }
    for (int r = 0; r < NR; ++r) { g[r] = tmp[r] / s; gate[r] = g[r]; }
  }
  __syncthreads();
  float c = 0.f;
  for (int r = 0; r < NR; ++r) c += g[r] * cbias[r * HID + t];
  cb[t] = c;
}

// ---- pass A (rel, head-pair): logits for 2 heads + segment max ----
__global__ __launch_bounds__(256) void edge_logit_hp(
    const int* __restrict__ ei, const int* __restrict__ elist, const int* __restrict__ ebase,
    const float* __restrict__ eattr, const float* __restrict__ relemb,
    const float* __restrict__ wedge, const float* __restrict__ attw,
    const unsigned short* __restrict__ xlb, const unsigned short* __restrict__ xrb,
    float* __restrict__ logit, unsigned* __restrict__ mkey, int rel) {
  int s = ebase[rel], cnt = ebase[rel + 1] - s;
  int li0 = blockIdx.x * EPB;
  if (li0 >= cnt) return;
  int nE = min(EPB, cnt - li0);
  int t = threadIdx.x;
  __shared__ unsigned short wE[24][264];  // transposed, padded
  __shared__ float aw[256];
  __shared__ float ea[EPB][24];
  __shared__ int elds[EPB];
  __shared__ float wsum[4];
#pragma unroll
  for (int k = 0; k < 24; ++k) wE[k][t] = f2b(wedge[(size_t)t * 24 + k]);
  aw[t] = attw[t];
  if (t < nE) elds[t] = elist[s + li0 + t];
  __syncthreads();
  if (t < EPB * 24) {
    int i = t / 24, k = t - i * 24;
    if (i < nE) {
      int e = elds[i];
      ea[i][k] = (k < NEA) ? eattr[(size_t)e * NEA + k] : relemb[k - NEA];
    }
  }
  float wreg[24];
#pragma unroll
  for (int k = 0; k < 24; ++k) wreg[k] = b2f(wE[k][t]);
  float areg = aw[t];
  __syncthreads();
  int lane = t & 63, w = t >> 6;
  for (int i = 0; i < nE; ++i) {
    int e = elds[i];
    int src = ei[e], dst = ei[NE + e];
    float eev = 0.f;
#pragma unroll
    for (int k = 0; k < 24; ++k) eev += ea[i][k] * wreg[k];
    float sv = b2f(xlb[(size_t)src * 256 + t]) + b2f(xrb[(size_t)dst * 256 + t]) + eev;
    sv = (sv > 0.f) ? sv : 0.2f * sv;
    float p = sv * areg;
#pragma unroll
    for (int o = 32; o > 0; o >>= 1) p += __shfl_xor(p, o, 64);
    if (lane == 0) wsum[w] = p;
    __syncthreads();
    if (t < 2) {
      float lg = wsum[2 * t] + wsum[2 * t + 1];
      logit[(size_t)(li0 + i) * 2 + t] = lg;
      atomicMax(mkey + (size_t)dst * 2 + t, fkey(lg));
    }
    __syncthreads();
  }
}

// ---- pass B ----
__global__ void edge_exp_hp(const int* __restrict__ ei, const int* __restrict__ elist,
                            const int* __restrict__ ebase, const float* __restrict__ logit,
                            const unsigned* __restrict__ mkey, float* __restrict__ aexp,
                            float* __restrict__ den, int rel) {
  int s = ebase[rel], cnt = ebase[rel + 1] - s;
  int i = blockIdx.x * blockDim.x + threadIdx.x;
  int li = i >> 1, hh = i & 1;
  if (li >= cnt) return;
  int e = elist[s + li];
  int dst = ei[NE + e];
  float m = unkey(mkey[(size_t)dst * 2 + hh]);
  float a = expf(logit[(size_t)li * 2 + hh] - m);
  aexp[(size_t)li * 2 + hh] = a;
  atomicAdd(den + (size_t)dst * 2 + hh, a);
}

// ---- pass C ----
__global__ __launch_bounds__(256) void edge_aggr_hp(
    const int* __restrict__ ei, const int* __restrict__ elist, const int* __restrict__ ebase,
    const float* __restrict__ aexp, const float* __restrict__ den,
    const unsigned short* __restrict__ xlb, float* __restrict__ hmsg,
    const float* __restrict__ gate, int rel) {
  int s = ebase[rel], cnt = ebase[rel + 1] - s;
  int li = blockIdx.x * 2 + (threadIdx.x >> 7);
  int tt = threadIdx.x & 127;
  if (li >= cnt) return;
  int e = elist[s + li];
  int src = ei[e], dst = ei[NE + e];
  float g = gate[rel] * 0.25f;
  float d0 = den[(size_t)dst * 2];     d0 = (d0 == 0.f) ? 1.f : d0;
  float d1 = den[(size_t)dst * 2 + 1]; d1 = (d1 == 0.f) ? 1.f : d1;
  float w0 = g * aexp[(size_t)li * 2] / d0;
  float w1 = g * aexp[(size_t)li * 2 + 1] / d1;
  float v = w0 * b2f(xlb[(size_t)src * 256 + tt]) + w1 * b2f(xlb[(size_t)src * 256 + 128 + tt]);
  atomicAdd(hmsg + (size_t)dst * HID + tt, v);
}

// ---- h = layernorm(h + add (+ cb)) ----
__global__ __launch_bounds__(256) void add_ln(
    float* __restrict__ h, const float* __restrict__ add, const float* __restrict__ cb,
    const float* __restrict__ w, const float* __restrict__ b, int nrows) {
  int wave = threadIdx.x >> 6, lane = threadIdx.x & 63;
  int row = blockIdx.x * 4 + wave;
  if (row >= nrows) return;
  size_t base = (size_t)row * HID;
  float x0 = h[base + lane] + add[base + lane];
  float x1 = h[base + 64 + lane] + add[base + 64 + lane];
  if (cb) { x0 += cb[lane]; x1 += cb[64 + lane]; }
  float s = x0 + x1;
#pragma unroll
  for (int o = 32; o > 0; o >>= 1) s += __shfl_xor(s, o, 64);
  float mean = s * (1.f / 128.f);
  float d0 = x0 - mean, d1 = x1 - mean;
  float v = d0 * d0 + d1 * d1;
#pragma unroll
  for (int o = 32; o > 0; o >>= 1) v += __shfl_xor(v, o, 64);
  float inv = 1.f / sqrtf(v * (1.f / 128.f) + 1e-5f);
  h[base + lane] = d0 * inv * w[lane] + b[lane];
  h[base + 64 + lane] = d1 * inv * w[64 + lane] + b[64 + lane];
}

// ---- readout ----
__global__ __launch_bounds__(128) void readout_acc(
    const float* __restrict__ h, const int* __restrict__ batch,
    float* __restrict__ cnt, float* __restrict__ sum, unsigned* __restrict__ maxk) {
  int n = blockIdx.x, t = threadIdx.x;
  int b = batch[n];
  float v = h[(size_t)n * HID + t];
  atomicAdd(sum + (size_t)b * HID + t, v);
  atomicMax(maxk + (size_t)b * HID + t, fkey(v));
  if (t == 0) atomicAdd(cnt + b, 1.f);
}

__global__ __launch_bounds__(256) void readout_final(
    const float* __restrict__ cnt, const float* __restrict__ sum,
    const unsigned* __restrict__ maxk, const float* __restrict__ w,
    const float* __restrict__ b, float* __restrict__ g) {
  int bg = blockIdx.x, t = threadIdx.x;
  __shared__ float red[256];
  float c = fmaxf(cnt[bg], 1.f);
  float x = (t < HID) ? sum[(size_t)bg * HID + t] / c
                      : unkey(maxk[(size_t)bg * HID + (t - HID)]);
  red[t] = x;
  __syncthreads();
  for (int s = 128; s > 0; s >>= 1) {
    if (t < s) red[t] += red[t + s];
    __syncthreads();
  }
  float mean = red[0] * (1.f / 256.f);
  __syncthreads();
  float d = x - mean;
  red[t] = d * d;
  __syncthreads();
  for (int s = 128; s > 0; s >>= 1) {
    if (t < s) red[t] += red[t + s];
    __syncthreads();
  }
  float inv = 1.f / sqrtf(red[0] * (1.f / 256.f) + 1e-5f);
  g[(size_t)bg * 256 + t] = d * inv * w[t] + b[t];
}

// ---- B-splines ----
__device__ __forceinline__ void bspline8(float x, const float* __restrict__ t,
                                         float* __restrict__ out) {
  float bs[11];
#pragma unroll
  for (int j = 0; j < 11; ++j) bs[j] = (x >= t[j] && x < t[j + 1]) ? 1.f : 0.f;
#pragma unroll
  for (int k = 1; k <= 3; ++k) {
    for (int j = 0; j < 11 - k; ++j) {
      bs[j] = (x - t[j]) / (t[j + k] - t[j]) * bs[j] +
              (t[j + k + 1] - x) / (t[j + k + 1] - t[j + 1]) * bs[j + 1];
    }
  }
#pragma unroll
  for (int j = 0; j < 8; ++j) out[j] = bs[j];
}

__global__ __launch_bounds__(128) void kan1(
    const float* __restrict__ g, const float* __restrict__ bw,
    const float* __restrict__ sw, const float* __restrict__ sc,
    const float* __restrict__ grid, float* __restrict__ z) {
  int bg = blockIdx.x, t = threadIdx.x;
  __shared__ float B[256][8];
  __shared__ float sg[256];
  for (int i = t; i < 256; i += 128) {
    float x = g[(size_t)bg * 256 + i];
    sg[i] = x / (1.f + expf(-x));
    bspline8(x, grid + (size_t)i * 12, B[i]);
  }
  __syncthreads();
  float acc = 0.f;
  for (int i = 0; i < 256; ++i) {
    acc += sg[i] * bw[(size_t)t * 256 + i];
    const float* swp = sw + ((size_t)t * 256 + i) * 8;
    float sp = 0.f;
#pragma unroll
    for (int k = 0; k < 8; ++k) sp += B[i][k] * swp[k];
    acc += sp * sc[(size_t)t * 256 + i];
  }
  z[(size_t)bg * KH + t] = acc;
}

__global__ __launch_bounds__(128) void kan2(
    const float* __restrict__ z, const float* __restrict__ bw,
    const float* __restrict__ sw, const float* __restrict__ sc,
    const float* __restrict__ grid, float* __restrict__ out) {
  int bg = blockIdx.x, t = threadIdx.x;
  __shared__ float B[128][8];
  __shared__ float sz[128];
  float x = z[(size_t)bg * KH + t];
  sz[t] = x / (1.f + expf(-x));
  bspline8(x, grid + (size_t)t * 12, B[t]);
  __syncthreads();
  if (t < NC) {
    float acc = 0.f;
    for (int i = 0; i < 128; ++i) {
      acc += sz[i] * bw[(size_t)t * 128 + i];
      const float* swp = sw + ((size_t)t * 128 + i) * 8;
      float sp = 0.f;
#pragma unroll
      for (int k = 0; k < 8; ++k) sp += B[i][k] * swp[k];
      acc += sp * sc[(size_t)t * 128 + i];
    }
    out[(size_t)bg * NC + t] = acc;
  }
}

extern "C" void kernel_launch(void* const* d_in, const int* in_sizes, int n_in,
                              void* d_out, int out_size, void* d_ws, size_t ws_size,
                              hipStream_t stream) {
  const float* x       = (const float*)d_in[0];
  const float* eattr   = (const float*)d_in[1];
  const int*   idtok   = (const int*)d_in[2];
  const int*   ei      = (const int*)d_in[3];
  const int*   etype   = (const int*)d_in[4];
  const int*   batch   = (const int*)d_in[5];
  const float* idemb   = (const float*)d_in[6];
  const float* inw     = (const float*)d_in[7];
  const float* inb     = (const float*)d_in[8];
  const float* relemb  = (const float*)d_in[9];
  const float* linlw   = (const float*)d_in[10];
  const float* linlb   = (const float*)d_in[11];
  const float* linrw   = (const float*)d_in[12];
  const float* linrb   = (const float*)d_in[13];
  const float* linew   = (const float*)d_in[14];
  const float* attw    = (const float*)d_in[15];
  const float* convb   = (const float*)d_in[16];
  const float* relgate = (const float*)d_in[17];
  const float* n1w     = (const float*)d_in[18];
  const float* n1b     = (const float*)d_in[19];
  const float* n2w     = (const float*)d_in[20];
  const float* n2b     = (const float*)d_in[21];
  const float* f1w     = (const float*)d_in[22];
  const float* f1bias  = (const float*)d_in[23];
  const float* f2w     = (const float*)d_in[24];
  const float* f2bias  = (const float*)d_in[25];
  const float* rnw     = (const float*)d_in[26];
  const float* rnb     = (const float*)d_in[27];
  const float* bw1     = (const float*)d_in[28];
  const float* sw1     = (const float*)d_in[29];
  const float* sc1     = (const float*)d_in[30];
  const float* grid1   = (const float*)d_in[31];
  const float* bw2     = (const float*)d_in[32];
  const float* sw2     = (const float*)d_in[33];
  const float* sc2     = (const float*)d_in[34];
  const float* grid2   = (const float*)d_in[35];
  float* out = (float*)d_out;
  (void)in_sizes; (void)n_in; (void)out_size; (void)ws_size;

  // ---- workspace carve (~122 MB) ----
  char* p = (char*)d_ws;
  auto alloc = [&](size_t bytes) { void* q = (void*)p; p += (bytes + 255) & ~(size_t)255; return q; };
  float* h    = (float*)alloc((size_t)NN * HID * 4);
  float* hmsg = (float*)alloc((size_t)NN * HID * 4);
  unsigned short* hbf = (unsigned short*)alloc((size_t)NN * HID * 2);
  unsigned short* pool = (unsigned short*)alloc((size_t)NN * 512 * 2);  // xl|xr / xin / f1
  float* logit = (float*)alloc((size_t)NE * 2 * 4);
  float* aexp  = (float*)alloc((size_t)NE * 2 * 4);
  unsigned* mkey = (unsigned*)alloc((size_t)NN * 4 * 4);  // mkey(2N u32) + den(2N f32)
  float* den = (float*)(mkey + (size_t)NN * 2);
  int* elist = (int*)alloc((size_t)NE * 4);
  int* ecnt  = (int*)alloc(16 * 4);  // ecnt[4] ecur[4] ebase[5]
  int* ecur  = ecnt + 4;
  int* ebase = ecnt + 8;
  unsigned short* linlwb = (unsigned short*)alloc((size_t)NL * NR * 512 * 128 * 2);
  unsigned short* linrwb = (unsigned short*)alloc((size_t)NL * NR * 512 * 128 * 2);
  unsigned short* f1wb   = (unsigned short*)alloc((size_t)NL * 256 * 128 * 2);
  unsigned short* f2wb   = (unsigned short*)alloc((size_t)NL * 128 * 256 * 2);
  unsigned short* inwb   = (unsigned short*)alloc((size_t)128 * 96 * 2);
  float* gate = (float*)alloc(NR * 4);
  float* cb   = (float*)alloc(HID * 4);
  float* rcnt = (float*)alloc((size_t)(NG + NG * HID * 2) * 4);  // cnt+sum+maxk
  float* rsum = rcnt + NG;
  unsigned* rmaxk = (unsigned*)(rsum + (size_t)NG * HID);
  float* g = (float*)alloc((size_t)NG * 256 * 4);
  float* z = (float*)alloc((size_t)NG * KH * 4);
  unsigned short* xinbf = pool;                       // N*96
  unsigned short* xlb   = pool;                       // N*256
  unsigned short* xrb   = pool + (size_t)NN * 256;    // N*256
  unsigned short* f1buf = pool;                       // N*256

  const int NB = (NN + 127) / 128;  // 391 row-tiles

  // ---- weight conversions (once per call) ----
  {
    int n;
    n = NL * NR * 512 * 128 / 4;
    cvt_bf16<<<(n + 255) / 256, 256, 0, stream>>>(linlw, linlwb, n);
    cvt_bf16<<<(n + 255) / 256, 256, 0, stream>>>(linrw, linrwb, n);
    n = NL * 256 * 128 / 4;
    cvt_bf16<<<(n + 255) / 256, 256, 0, stream>>>(f1w, f1wb, n);
    cvt_bf16<<<(n + 255) / 256, 256, 0, stream>>>(f2w, f2wb, n);
    n = 128 * 96 / 4;
    cvt_bf16<<<(n + 255) / 256, 256, 0, stream>>>(inw, inwb, n);
  }

  // ---- edge lists ----
  hipMemsetAsync(ecnt, 0, 8 * 4, stream);
  hist_et<<<(NE + 255) / 256, 256, 0, stream>>>(etype, ecnt);
  scan_et<<<1, 64, 0, stream>>>(ecnt, ebase);
  scatter_et<<<(NE + 255) / 256, 256, 0, stream>>>(etype, ebase, ecur, elist);

  // ---- input projection ----
  build_xin_bf<<<(NN * 96 + 255) / 256, 256, 0, stream>>>(x, idtok, idemb, xinbf);
  gemm_bf16<<<dim3(NB, 1), 256, 0, stream>>>(xinbf, inwb, inb, h, nullptr, NN, 96, 128, 1);

  for (int l = 0; l < NL; ++l) {
    gate_cb<<<1, 128, 0, stream>>>(relgate + l * NR, convb + (size_t)l * NR * HID, gate, cb);
    hipMemsetAsync(hmsg, 0, (size_t)NN * HID * 4, stream);
    cvt_bf16<<<(NN * HID / 4 + 255) / 256, 256, 0, stream>>>(h, hbf, NN * HID / 4);
    for (int r = 0; r < NR; ++r) {
      int lr = l * NR + r;
      for (int hp = 0; hp < 2; ++hp) {
        const unsigned short* wl = linlwb + ((size_t)lr * 512 + hp * 256) * 128;
        const unsigned short* wr = linrwb + ((size_t)lr * 512 + hp * 256) * 128;
        const float* bl = linlb + (size_t)lr * 512 + hp * 256;
        const float* br = linrb + (size_t)lr * 512 + hp * 256;
        gemm_bf16<<<dim3(NB, 2), 256, 0, stream>>>(hbf, wl, bl, nullptr, xlb, NN, 128, 256, 0);
        gemm_bf16<<<dim3(NB, 2), 256, 0, stream>>>(hbf, wr, br, nullptr, xrb, NN, 128, 256, 0);
        hipMemsetAsync(mkey, 0, (size_t)NN * 4 * 4, stream);  // mkey + den
        edge_logit_hp<<<(NE + EPB - 1) / EPB, 256, 0, stream>>>(
            ei, elist, ebase, eattr, relemb + (size_t)lr * RED,
            linew + ((size_t)lr * 512 + hp * 256) * 24,
            attw + (size_t)lr * 512 + hp * 256, xlb, xrb, logit, mkey, r);
        edge_exp_hp<<<(2 * NE + 255) / 256, 256, 0, stream>>>(
            ei, elist, ebase, logit, mkey, aexp, den, r);
        edge_aggr_hp<<<(NE + 1) / 2, 256, 0, stream>>>(
            ei, elist, ebase, aexp, den, xlb, hmsg, gate, r);
      }
    }
    add_ln<<<(NN + 3) / 4, 256, 0, stream>>>(h, hmsg, cb, n1w + l * HID, n1b + l * HID, NN);
    cvt_bf16<<<(NN * HID / 4 + 255) / 256, 256, 0, stream>>>(h, hbf, NN * HID / 4);
    gemm_bf16<<<dim3(NB, 2), 256, 0, stream>>>(hbf, f1wb + (size_t)l * 256 * 128,
                                               f1bias + (size_t)l * 256, nullptr, f1buf,
                                               NN, 128, 256, 1);
    gemm_bf16<<<dim3(NB, 1), 256, 0, stream>>>(f1buf, f2wb + (size_t)l * 128 * 256,
                                               f2bias + (size_t)l * 128, hmsg, nullptr,
                                               NN, 256, 128, 0);
    add_ln<<<(NN + 3) / 4, 256, 0, stream>>>(h, hmsg, nullptr, n2w + l * HID, n2b + l * HID, NN);
  }

  hipMemsetAsync(rcnt, 0, (size_t)(NG + NG * HID * 2) * 4, stream);
  readout_acc<<<NN, 128, 0, stream>>>(h, batch, rcnt, rsum, rmaxk);
  readout_final<<<NG, 256, 0, stream>>>(rcnt, rsum, rmaxk, rnw, rnb, g);
  kan1<<<NG, 128, 0, stream>>>(g, bw1, sw1, sc1, grid1, z);
  kan2<<<NG, 128, 0, stream>>>(z, bw2, sw2, sc2, grid2, out);
}

// Round 4
// 4221.013 us; speedup vs baseline: 2.5643x; 1.2862x over previous
//
#include <hip/hip_runtime.h>
#include <math.h>

#define NN 50000
#define NE 120000
#define FN 64
#define NEA 16
#define NR 4
#define NH 4
#define HID 128
#define NL 3
#define IDE 32
#define RED 8
#define NG 64
#define NC 10
#define KH 128
#define FFH 256

typedef short bf16x8 __attribute__((ext_vector_type(8)));
typedef float f32x4 __attribute__((ext_vector_type(4)));

// ---- bf16 helpers (RNE) ----
__device__ __forceinline__ unsigned short f2b(float f) {
  unsigned u = __float_as_uint(f);
  unsigned r = (u + 0x7FFFu + ((u >> 16) & 1u)) >> 16;
  return (unsigned short)r;
}
__device__ __forceinline__ float b2f(unsigned short b) {
  return __uint_as_float((unsigned)b << 16);
}

// ---- monotone float<->uint key for atomic max ----
__device__ __forceinline__ unsigned fkey(float f) {
  unsigned u = __float_as_uint(f);
  return (u & 0x80000000u) ? ~u : (u | 0x80000000u);
}
__device__ __forceinline__ float unkey(unsigned k) {
  unsigned u = (k & 0x80000000u) ? (k ^ 0x80000000u) : ~k;
  return __uint_as_float(u);
}

// ---- f32 -> bf16 bulk convert (n multiple of 4) ----
__global__ void cvt_bf16(const float* __restrict__ s, unsigned short* __restrict__ d, int n4) {
  int i = blockIdx.x * blockDim.x + threadIdx.x;
  if (i >= n4) return;
  float4 v = ((const float4*)s)[i];
  ushort4 o;
  o.x = f2b(v.x); o.y = f2b(v.y); o.z = f2b(v.z); o.w = f2b(v.w);
  ((ushort4*)d)[i] = o;
}

// ---- MFMA bf16 GEMM: C[n][m] = A[n][:K].W[m][:K] + bias[m]; opt silu; out f32 or bf16 ----
__global__ __launch_bounds__(256) void gemm_bf16(
    const unsigned short* __restrict__ A, const unsigned short* __restrict__ W,
    const float* __restrict__ bias, float* __restrict__ Cf, unsigned short* __restrict__ Cb,
    int nrows, int K, int mout, int act) {
  __shared__ unsigned short As[128][40];
  __shared__ unsigned short Ws[128][40];
  int t = threadIdx.x;
  int lane = t & 63, w = t >> 6;
  int wm = w >> 1, wn = w & 1;
  int q = lane >> 4, mr = lane & 15;
  int rowBase = blockIdx.x * 128;
  int colBase = blockIdx.y * 128;
  f32x4 acc[4][4] = {};
  for (int k0 = 0; k0 < K; k0 += 32) {
#pragma unroll
    for (int half = 0; half < 2; ++half) {
      int c = t + half * 256;
      int row = c >> 2, c16 = c & 3;
      int gr = rowBase + row;
      bf16x8 av = {0, 0, 0, 0, 0, 0, 0, 0};
      if (gr < nrows) av = *(const bf16x8*)(A + (size_t)gr * K + k0 + c16 * 8);
      *(bf16x8*)&As[row][c16 * 8] = av;
      bf16x8 wv = *(const bf16x8*)(W + (size_t)(colBase + row) * K + k0 + c16 * 8);
      *(bf16x8*)&Ws[row][c16 * 8] = wv;
    }
    __syncthreads();
    bf16x8 af[4], bfr[4];
#pragma unroll
    for (int mt = 0; mt < 4; ++mt) af[mt] = *(const bf16x8*)&As[wm * 64 + mt * 16 + mr][q * 8];
#pragma unroll
    for (int nt = 0; nt < 4; ++nt) bfr[nt] = *(const bf16x8*)&Ws[wn * 64 + nt * 16 + mr][q * 8];
#pragma unroll
    for (int mt = 0; mt < 4; ++mt)
#pragma unroll
      for (int nt = 0; nt < 4; ++nt)
        acc[mt][nt] = __builtin_amdgcn_mfma_f32_16x16x32_bf16(af[mt], bfr[nt], acc[mt][nt], 0, 0, 0);
    __syncthreads();
  }
#pragma unroll
  for (int mt = 0; mt < 4; ++mt)
#pragma unroll
    for (int nt = 0; nt < 4; ++nt)
#pragma unroll
      for (int r = 0; r < 4; ++r) {
        int row = rowBase + wm * 64 + mt * 16 + q * 4 + r;
        int col = colBase + wn * 64 + nt * 16 + mr;
        if (row < nrows) {
          float v = acc[mt][nt][r] + bias[col];
          if (act) v = v / (1.f + expf(-v));
          if (Cb) Cb[(size_t)row * mout + col] = f2b(v);
          else    Cf[(size_t)row * mout + col] = v;
        }
      }
}

// ---- concat(x, id_emb[tok]) -> bf16 (N,96) ----
__global__ void build_xin_bf(const float* __restrict__ x, const int* __restrict__ idtok,
                             const float* __restrict__ emb, unsigned short* __restrict__ xin) {
  int i = blockIdx.x * blockDim.x + threadIdx.x;
  if (i >= NN * 96) return;
  int n = i / 96, k = i - n * 96;
  float v = (k < FN) ? x[(size_t)n * FN + k] : emb[(size_t)idtok[n] * IDE + (k - FN)];
  xin[i] = f2b(v);
}

// ---- edge lists per relation ----
__global__ void hist_et(const int* __restrict__ et, int* __restrict__ ecnt) {
  int i = blockIdx.x * blockDim.x + threadIdx.x;
  if (i < NE) atomicAdd(&ecnt[et[i]], 1);  // return unused -> wave-coalesced
}
__global__ void scan_et(const int* __restrict__ ecnt, int* __restrict__ ebase) {
  if (threadIdx.x == 0 && blockIdx.x == 0) {
    int b = 0;
    for (int r = 0; r < NR; ++r) { ebase[r] = b; b += ecnt[r]; }
    ebase[NR] = b;
  }
}
// ballot-aggregated scatter: 1 atomic per wave per relation (was 1/thread, serialized)
__global__ void scatter_et(const int* __restrict__ et, const int* __restrict__ ebase,
                           int* __restrict__ ecur, int* __restrict__ elist) {
  int i = blockIdx.x * blockDim.x + threadIdx.x;
  bool valid = i < NE;
  int r = valid ? et[i] : -1;
  int lane = threadIdx.x & 63;
  for (int rr = 0; rr < NR; ++rr) {
    unsigned long long m = __ballot(valid && r == rr);
    if (m == 0ull) continue;
    int leader = __ffsll((unsigned long long)m) - 1;
    int base = 0;
    if (lane == leader) base = atomicAdd(&ecur[rr], __popcll(m));
    base = __shfl(base, leader, 64);
    if (valid && r == rr) {
      unsigned long long below = m & ((1ull << lane) - 1ull);
      elist[ebase[rr] + base + __popcll(below)] = i;
    }
  }
}

// ---- per-layer gate + fused conv_bias ----
__global__ void gate_cb(const float* __restrict__ rg, const float* __restrict__ cbias,
                        float* __restrict__ gate, float* __restrict__ cb) {
  __shared__ float g[NR];
  int t = threadIdx.x;
  if (t == 0) {
    float mx = rg[0];
    for (int r = 1; r < NR; ++r) mx = fmaxf(mx, rg[r]);
    float s = 0.f, tmp[NR];
    for (int r = 0; r < NR; ++r) { tmp[r] = expf(rg[r] - mx); s += tmp[r]; }
    for (int r = 0; r < NR; ++r) { g[r] = tmp[r] / s; gate[r] = g[r]; }
  }
  __syncthreads();
  float c = 0.f;
  for (int r = 0; r < NR; ++r) c += g[r] * cbias[r * HID + t];
  cb[t] = c;
}

// ---- pass A: one wave per (edge-group, head); 4 edges/wave; no in-loop barriers ----
__global__ __launch_bounds__(256) void edge_logit_g(
    const int* __restrict__ ei, const int* __restrict__ elist, const int* __restrict__ ebase,
    const float* __restrict__ eattr, const float* __restrict__ relembp,
    const float* __restrict__ wedgep, const float* __restrict__ attwp,
    const unsigned short* __restrict__ xlb, const unsigned short* __restrict__ xrb,
    float* __restrict__ logit, unsigned* __restrict__ mkey,
    int rel, int HP, int lghp, int stride) {
  int s = ebase[rel], cnt = ebase[rel + 1] - s;
  int gw = blockIdx.x * 4 + (threadIdx.x >> 6);
  int eg = gw >> lghp, hh = gw & (HP - 1);
  int e0 = eg * 4;
  if (e0 >= cnt) return;
  int lane = threadIdx.x & 63;
  float wreg[2][24], areg[2], rreg[8];
#pragma unroll
  for (int j = 0; j < 2; ++j) {
    int col = hh * 128 + lane + j * 64;
    const float* wp = wedgep + (size_t)col * 24;
#pragma unroll
    for (int k = 0; k < 24; ++k) wreg[j][k] = wp[k];
    areg[j] = attwp[col];
  }
#pragma unroll
  for (int k = 0; k < 8; ++k) rreg[k] = relembp[k];
  for (int i = 0; i < 4; ++i) {
    int li = e0 + i;
    if (li >= cnt) break;
    int e = elist[s + li];
    int src = ei[e], dst = ei[NE + e];
    const float* eap = eattr + (size_t)e * NEA;
    float er[NEA];
#pragma unroll
    for (int k = 0; k < NEA; ++k) er[k] = eap[k];
    float p = 0.f;
#pragma unroll
    for (int j = 0; j < 2; ++j) {
      int col = hh * 128 + lane + j * 64;
      float eev = 0.f;
#pragma unroll
      for (int k = 0; k < NEA; ++k) eev += er[k] * wreg[j][k];
#pragma unroll
      for (int k = 0; k < 8; ++k) eev += rreg[k] * wreg[j][NEA + k];
      float sv = b2f(xlb[(size_t)src * stride + col]) + b2f(xrb[(size_t)dst * stride + col]) + eev;
      sv = (sv > 0.f) ? sv : 0.2f * sv;
      p += sv * areg[j];
    }
#pragma unroll
    for (int o = 32; o > 0; o >>= 1) p += __shfl_xor(p, o, 64);
    if (lane == 0) {
      logit[(size_t)li * HP + hh] = p;
      atomicMax(mkey + (size_t)dst * HP + hh, fkey(p));
    }
  }
}

// ---- pass B ----
__global__ void edge_exp_g(const int* __restrict__ ei, const int* __restrict__ elist,
                           const int* __restrict__ ebase, const float* __restrict__ logit,
                           const unsigned* __restrict__ mkey, float* __restrict__ aexp,
                           float* __restrict__ den, int rel, int HP, int lghp) {
  int i = blockIdx.x * blockDim.x + threadIdx.x;
  int li = i >> lghp, hh = i & (HP - 1);
  int s = ebase[rel], cnt = ebase[rel + 1] - s;
  if (li >= cnt) return;
  int e = elist[s + li];
  int dst = ei[NE + e];
  float m = unkey(mkey[(size_t)dst * HP + hh]);
  float a = expf(logit[i] - m);
  aexp[i] = a;
  atomicAdd(den + (size_t)dst * HP + hh, a);
}

// ---- pass C ----
__global__ __launch_bounds__(256) void edge_aggr_g(
    const int* __restrict__ ei, const int* __restrict__ elist, const int* __restrict__ ebase,
    const float* __restrict__ aexp, const float* __restrict__ den,
    const unsigned short* __restrict__ xlb, float* __restrict__ hmsg,
    const float* __restrict__ gate, int rel, int HP, int stride) {
  int s = ebase[rel], cnt = ebase[rel + 1] - s;
  int li = blockIdx.x * 2 + (threadIdx.x >> 7);
  int tt = threadIdx.x & 127;
  if (li >= cnt) return;
  int e = elist[s + li];
  int src = ei[e], dst = ei[NE + e];
  float g = gate[rel] * 0.25f;
  float v = 0.f;
  for (int h = 0; h < HP; ++h) {
    float d = den[(size_t)dst * HP + h];
    d = (d == 0.f) ? 1.f : d;
    float w = g * aexp[(size_t)li * HP + h] / d;
    v += w * b2f(xlb[(size_t)src * stride + h * 128 + tt]);
  }
  atomicAdd(hmsg + (size_t)dst * HID + tt, v);
}

// ---- h = layernorm(h + add (+ cb)) ----
__global__ __launch_bounds__(256) void add_ln(
    float* __restrict__ h, const float* __restrict__ add, const float* __restrict__ cb,
    const float* __restrict__ w, const float* __restrict__ b, int nrows) {
  int wave = threadIdx.x >> 6, lane = threadIdx.x & 63;
  int row = blockIdx.x * 4 + wave;
  if (row >= nrows) return;
  size_t base = (size_t)row * HID;
  float x0 = h[base + lane] + add[base + lane];
  float x1 = h[base + 64 + lane] + add[base + 64 + lane];
  if (cb) { x0 += cb[lane]; x1 += cb[64 + lane]; }
  float s = x0 + x1;
#pragma unroll
  for (int o = 32; o > 0; o >>= 1) s += __shfl_xor(s, o, 64);
  float mean = s * (1.f / 128.f);
  float d0 = x0 - mean, d1 = x1 - mean;
  float v = d0 * d0 + d1 * d1;
#pragma unroll
  for (int o = 32; o > 0; o >>= 1) v += __shfl_xor(v, o, 64);
  float inv = 1.f / sqrtf(v * (1.f / 128.f) + 1e-5f);
  h[base + lane] = d0 * inv * w[lane] + b[lane];
  h[base + 64 + lane] = d1 * inv * w[64 + lane] + b[64 + lane];
}

// ---- readout ----
__global__ __launch_bounds__(128) void readout_acc(
    const float* __restrict__ h, const int* __restrict__ batch,
    float* __restrict__ cnt, float* __restrict__ sum, unsigned* __restrict__ maxk) {
  int n = blockIdx.x, t = threadIdx.x;
  int b = batch[n];
  float v = h[(size_t)n * HID + t];
  atomicAdd(sum + (size_t)b * HID + t, v);
  atomicMax(maxk + (size_t)b * HID + t, fkey(v));
  if (t == 0) atomicAdd(cnt + b, 1.f);
}

__global__ __launch_bounds__(256) void readout_final(
    const float* __restrict__ cnt, const float* __restrict__ sum,
    const unsigned* __restrict__ maxk, const float* __restrict__ w,
    const float* __restrict__ b, float* __restrict__ g) {
  int bg = blockIdx.x, t = threadIdx.x;
  __shared__ float red[256];
  float c = fmaxf(cnt[bg], 1.f);
  float x = (t < HID) ? sum[(size_t)bg * HID + t] / c
                      : unkey(maxk[(size_t)bg * HID + (t - HID)]);
  red[t] = x;
  __syncthreads();
  for (int s = 128; s > 0; s >>= 1) {
    if (t < s) red[t] += red[t + s];
    __syncthreads();
  }
  float mean = red[0] * (1.f / 256.f);
  __syncthreads();
  float d = x - mean;
  red[t] = d * d;
  __syncthreads();
  for (int s = 128; s > 0; s >>= 1) {
    if (t < s) red[t] += red[t + s];
    __syncthreads();
  }
  float inv = 1.f / sqrtf(red[0] * (1.f / 256.f) + 1e-5f);
  g[(size_t)bg * 256 + t] = d * inv * w[t] + b[t];
}

// ---- B-splines ----
__device__ __forceinline__ void bspline8(float x, const float* __restrict__ t,
                                         float* __restrict__ out) {
  float bs[11];
#pragma unroll
  for (int j = 0; j < 11; ++j) bs[j] = (x >= t[j] && x < t[j + 1]) ? 1.f : 0.f;
#pragma unroll
  for (int k = 1; k <= 3; ++k) {
    for (int j = 0; j < 11 - k; ++j) {
      bs[j] = (x - t[j]) / (t[j + k] - t[j]) * bs[j] +
              (t[j + k + 1] - x) / (t[j + k + 1] - t[j + 1]) * bs[j + 1];
    }
  }
#pragma unroll
  for (int j = 0; j < 8; ++j) out[j] = bs[j];
}

__global__ __launch_bounds__(128) void kan1(
    const float* __restrict__ g, const float* __restrict__ bw,
    const float* __restrict__ sw, const float* __restrict__ sc,
    const float* __restrict__ grid, float* __restrict__ z) {
  int bg = blockIdx.x, t = threadIdx.x;
  __shared__ float B[256][8];
  __shared__ float sg[256];
  for (int i = t; i < 256; i += 128) {
    float x = g[(size_t)bg * 256 + i];
    sg[i] = x / (1.f + expf(-x));
    bspline8(x, grid + (size_t)i * 12, B[i]);
  }
  __syncthreads();
  float acc = 0.f;
  for (int i = 0; i < 256; ++i) {
    acc += sg[i] * bw[(size_t)t * 256 + i];
    const float* swp = sw + ((size_t)t * 256 + i) * 8;
    float sp = 0.f;
#pragma unroll
    for (int k = 0; k < 8; ++k) sp += B[i][k] * swp[k];
    acc += sp * sc[(size_t)t * 256 + i];
  }
  z[(size_t)bg * KH + t] = acc;
}

__global__ __launch_bounds__(128) void kan2(
    const float* __restrict__ z, const float* __restrict__ bw,
    const float* __restrict__ sw, const float* __restrict__ sc,
    const float* __restrict__ grid, float* __restrict__ out) {
  int bg = blockIdx.x, t = threadIdx.x;
  __shared__ float B[128][8];
  __shared__ float sz[128];
  float x = z[(size_t)bg * KH + t];
  sz[t] = x / (1.f + expf(-x));
  bspline8(x, grid + (size_t)t * 12, B[t]);
  __syncthreads();
  if (t < NC) {
    float acc = 0.f;
    for (int i = 0; i < 128; ++i) {
      acc += sz[i] * bw[(size_t)t * 128 + i];
      const float* swp = sw + ((size_t)t * 128 + i) * 8;
      float sp = 0.f;
#pragma unroll
      for (int k = 0; k < 8; ++k) sp += B[i][k] * swp[k];
      acc += sp * sc[(size_t)t * 128 + i];
    }
    out[(size_t)bg * NC + t] = acc;
  }
}

extern "C" void kernel_launch(void* const* d_in, const int* in_sizes, int n_in,
                              void* d_out, int out_size, void* d_ws, size_t ws_size,
                              hipStream_t stream) {
  const float* x       = (const float*)d_in[0];
  const float* eattr   = (const float*)d_in[1];
  const int*   idtok   = (const int*)d_in[2];
  const int*   ei      = (const int*)d_in[3];
  const int*   etype   = (const int*)d_in[4];
  const int*   batch   = (const int*)d_in[5];
  const float* idemb   = (const float*)d_in[6];
  const float* inw     = (const float*)d_in[7];
  const float* inb     = (const float*)d_in[8];
  const float* relemb  = (const float*)d_in[9];
  const float* linlw   = (const float*)d_in[10];
  const float* linlb   = (const float*)d_in[11];
  const float* linrw   = (const float*)d_in[12];
  const float* linrb   = (const float*)d_in[13];
  const float* linew   = (const float*)d_in[14];
  const float* attw    = (const float*)d_in[15];
  const float* convb   = (const float*)d_in[16];
  const float* relgate = (const float*)d_in[17];
  const float* n1w     = (const float*)d_in[18];
  const float* n1b     = (const float*)d_in[19];
  const float* n2w     = (const float*)d_in[20];
  const float* n2b     = (const float*)d_in[21];
  const float* f1w     = (const float*)d_in[22];
  const float* f1bias  = (const float*)d_in[23];
  const float* f2w     = (const float*)d_in[24];
  const float* f2bias  = (const float*)d_in[25];
  const float* rnw     = (const float*)d_in[26];
  const float* rnb     = (const float*)d_in[27];
  const float* bw1     = (const float*)d_in[28];
  const float* sw1     = (const float*)d_in[29];
  const float* sc1     = (const float*)d_in[30];
  const float* grid1   = (const float*)d_in[31];
  const float* bw2     = (const float*)d_in[32];
  const float* sw2     = (const float*)d_in[33];
  const float* sc2     = (const float*)d_in[34];
  const float* grid2   = (const float*)d_in[35];
  float* out = (float*)d_out;
  (void)in_sizes; (void)n_in; (void)out_size;

  // ---- pick heads-per-pass: full-head (4) if workspace allows, else head-pair ----
  auto needed = [](int HP) -> size_t {
    auto al = [](size_t b) { return (b + 255) & ~(size_t)255; };
    size_t o = 0;
    o += al((size_t)NN * HID * 4) * 2;            // h, hmsg
    o += al((size_t)NN * HID * 2);                // hbf
    o += al((size_t)NN * 128 * HP * 2) * 2;       // xlb, xrb
    o += al((size_t)NE * HP * 4) * 2;             // logit, aexp
    o += al((size_t)NN * HP * 8);                 // mkey+den
    o += al((size_t)NE * 4) + al(64);             // elist, ecnt
    o += al((size_t)NL * NR * 512 * 128 * 2) * 2; // linlwb, linrwb
    o += al((size_t)NL * 256 * 128 * 2) * 2;      // f1wb, f2wb
    o += al((size_t)128 * 96 * 2);                // inwb
    o += al(NR * 4) + al(HID * 4);
    o += al((size_t)(NG + NG * HID * 2) * 4);
    o += al((size_t)NG * 256 * 4) + al((size_t)NG * KH * 4);
    return o;
  };
  const int HP = (needed(4) <= ws_size) ? 4 : 2;
  const int lghp = (HP == 4) ? 2 : 1;
  const int passes = NH / HP;
  const int stride = HP * 128;

  // ---- workspace carve ----
  char* p = (char*)d_ws;
  auto alloc = [&](size_t bytes) { void* q = (void*)p; p += (bytes + 255) & ~(size_t)255; return q; };
  float* h    = (float*)alloc((size_t)NN * HID * 4);
  float* hmsg = (float*)alloc((size_t)NN * HID * 4);
  unsigned short* hbf = (unsigned short*)alloc((size_t)NN * HID * 2);
  unsigned short* xlb = (unsigned short*)alloc((size_t)NN * 128 * HP * 2);
  unsigned short* xrb = (unsigned short*)alloc((size_t)NN * 128 * HP * 2);
  float* logit = (float*)alloc((size_t)NE * HP * 4);
  float* aexp  = (float*)alloc((size_t)NE * HP * 4);
  unsigned* mkey = (unsigned*)alloc((size_t)NN * HP * 8);
  float* den = (float*)(mkey + (size_t)NN * HP);
  int* elist = (int*)alloc((size_t)NE * 4);
  int* ecnt  = (int*)alloc(64);
  int* ecur  = ecnt + 4;
  int* ebase = ecnt + 8;
  unsigned short* linlwb = (unsigned short*)alloc((size_t)NL * NR * 512 * 128 * 2);
  unsigned short* linrwb = (unsigned short*)alloc((size_t)NL * NR * 512 * 128 * 2);
  unsigned short* f1wb   = (unsigned short*)alloc((size_t)NL * 256 * 128 * 2);
  unsigned short* f2wb   = (unsigned short*)alloc((size_t)NL * 128 * 256 * 2);
  unsigned short* inwb   = (unsigned short*)alloc((size_t)128 * 96 * 2);
  float* gate = (float*)alloc(NR * 4);
  float* cb   = (float*)alloc(HID * 4);
  float* rcnt = (float*)alloc((size_t)(NG + NG * HID * 2) * 4);
  float* rsum = rcnt + NG;
  unsigned* rmaxk = (unsigned*)(rsum + (size_t)NG * HID);
  float* g = (float*)alloc((size_t)NG * 256 * 4);
  float* z = (float*)alloc((size_t)NG * KH * 4);
  unsigned short* xinbf = xlb;   // N*96 fits in xlb region
  unsigned short* f1buf = xlb;   // N*256 fits in xlb region (>= 25.6MB both modes)

  const int NB = (NN + 127) / 128;

  // ---- weight conversions ----
  {
    int n;
    n = NL * NR * 512 * 128 / 4;
    cvt_bf16<<<(n + 255) / 256, 256, 0, stream>>>(linlw, linlwb, n);
    cvt_bf16<<<(n + 255) / 256, 256, 0, stream>>>(linrw, linrwb, n);
    n = NL * 256 * 128 / 4;
    cvt_bf16<<<(n + 255) / 256, 256, 0, stream>>>(f1w, f1wb, n);
    cvt_bf16<<<(n + 255) / 256, 256, 0, stream>>>(f2w, f2wb, n);
    n = 128 * 96 / 4;
    cvt_bf16<<<(n + 255) / 256, 256, 0, stream>>>(inw, inwb, n);
  }

  // ---- edge lists ----
  hipMemsetAsync(ecnt, 0, 8 * 4, stream);
  hist_et<<<(NE + 255) / 256, 256, 0, stream>>>(etype, ecnt);
  scan_et<<<1, 64, 0, stream>>>(ecnt, ebase);
  scatter_et<<<(NE + 255) / 256, 256, 0, stream>>>(etype, ebase, ecur, elist);

  // ---- input projection ----
  build_xin_bf<<<(NN * 96 + 255) / 256, 256, 0, stream>>>(x, idtok, idemb, xinbf);
  gemm_bf16<<<dim3(NB, 1), 256, 0, stream>>>(xinbf, inwb, inb, h, nullptr, NN, 96, 128, 1);

  const int logit_blocks = (((NE + 3) / 4) * HP + 3) / 4;
  for (int l = 0; l < NL; ++l) {
    gate_cb<<<1, 128, 0, stream>>>(relgate + l * NR, convb + (size_t)l * NR * HID, gate, cb);
    hipMemsetAsync(hmsg, 0, (size_t)NN * HID * 4, stream);
    cvt_bf16<<<(NN * HID / 4 + 255) / 256, 256, 0, stream>>>(h, hbf, NN * HID / 4);
    for (int r = 0; r < NR; ++r) {
      int lr = l * NR + r;
      for (int hp = 0; hp < passes; ++hp) {
        int hpBase = hp * HP;
        const unsigned short* wl = linlwb + ((size_t)lr * 512 + hpBase * 128) * 128;
        const unsigned short* wr = linrwb + ((size_t)lr * 512 + hpBase * 128) * 128;
        const float* bl = linlb + (size_t)lr * 512 + hpBase * 128;
        const float* br = linrb + (size_t)lr * 512 + hpBase * 128;
        gemm_bf16<<<dim3(NB, HP), 256, 0, stream>>>(hbf, wl, bl, nullptr, xlb, NN, 128, stride, 0);
        gemm_bf16<<<dim3(NB, HP), 256, 0, stream>>>(hbf, wr, br, nullptr, xrb, NN, 128, stride, 0);
        hipMemsetAsync(mkey, 0, (size_t)NN * HP * 8, stream);
        edge_logit_g<<<logit_blocks, 256, 0, stream>>>(
            ei, elist, ebase, eattr, relemb + (size_t)lr * RED,
            linew + ((size_t)lr * 512 + hpBase * 128) * 24,
            attw + (size_t)lr * 512 + hpBase * 128,
            xlb, xrb, logit, mkey, r, HP, lghp, stride);
        edge_exp_g<<<(NE * HP + 255) / 256, 256, 0, stream>>>(
            ei, elist, ebase, logit, mkey, aexp, den, r, HP, lghp);
        edge_aggr_g<<<(NE + 1) / 2, 256, 0, stream>>>(
            ei, elist, ebase, aexp, den, xlb, hmsg, gate, r, HP, stride);
      }
    }
    add_ln<<<(NN + 3) / 4, 256, 0, stream>>>(h, hmsg, cb, n1w + l * HID, n1b + l * HID, NN);
    cvt_bf16<<<(NN * HID / 4 + 255) / 256, 256, 0, stream>>>(h, hbf, NN * HID / 4);
    gemm_bf16<<<dim3(NB, 2), 256, 0, stream>>>(hbf, f1wb + (size_t)l * 256 * 128,
                                               f1bias + (size_t)l * 256, nullptr, f1buf,
                                               NN, 128, 256, 1);
    gemm_bf16<<<dim3(NB, 1), 256, 0, stream>>>(f1buf, f2wb + (size_t)l * 128 * 256,
                                               f2bias + (size_t)l * 128, hmsg, nullptr,
                                               NN, 256, 128, 0);
    add_ln<<<(NN + 3) / 4, 256, 0, stream>>>(h, hmsg, nullptr, n2w + l * HID, n2b + l * HID, NN);
  }

  hipMemsetAsync(rcnt, 0, (size_t)(NG + NG * HID * 2) * 4, stream);
  readout_acc<<<NN, 128, 0, stream>>>(h, batch, rcnt, rsum, rmaxk);
  readout_final<<<NG, 256, 0, stream>>>(rcnt, rsum, rmaxk, rnw, rnb, g);
  kan1<<<NG, 128, 0, stream>>>(g, bw1, sw1, sc1, grid1, z);
  kan2<<<NG, 128, 0, stream>>>(z, bw2, sw2, sc2, grid2, out);
}

// Round 5
// 3247.796 us; speedup vs baseline: 3.3327x; 1.2997x over previous
//
#include <hip/hip_runtime.h>
#include <math.h>

#define NN 50000
#define NE 120000
#define FN 64
#define NEA 16
#define NR 4
#define NH 4
#define HID 128
#define NL 3
#define IDE 32
#define RED 8
#define NG 64
#define NC 10
#define KH 128
#define FFH 256

typedef short bf16x8 __attribute__((ext_vector_type(8)));
typedef float f32x4 __attribute__((ext_vector_type(4)));

// ---- bf16 helpers (RNE) ----
__device__ __forceinline__ unsigned short f2b(float f) {
  unsigned u = __float_as_uint(f);
  unsigned r = (u + 0x7FFFu + ((u >> 16) & 1u)) >> 16;
  return (unsigned short)r;
}
__device__ __forceinline__ float b2f(unsigned short b) {
  return __uint_as_float((unsigned)b << 16);
}

// ---- monotone float<->uint key for atomic max ----
__device__ __forceinline__ unsigned fkey(float f) {
  unsigned u = __float_as_uint(f);
  return (u & 0x80000000u) ? ~u : (u | 0x80000000u);
}
__device__ __forceinline__ float unkey(unsigned k) {
  unsigned u = (k & 0x80000000u) ? (k ^ 0x80000000u) : ~k;
  return __uint_as_float(u);
}

// ---- f32 -> bf16 bulk convert (n multiple of 4) ----
__global__ void cvt_bf16(const float* __restrict__ s, unsigned short* __restrict__ d, int n4) {
  int i = blockIdx.x * blockDim.x + threadIdx.x;
  if (i >= n4) return;
  float4 v = ((const float4*)s)[i];
  ushort4 o;
  o.x = f2b(v.x); o.y = f2b(v.y); o.z = f2b(v.z); o.w = f2b(v.w);
  ((ushort4*)d)[i] = o;
}

// ---- MFMA bf16 GEMM: C[n][m] = A[n][:K].W[m][:K] + bias[m]; opt silu; out f32 or bf16 ----
__global__ __launch_bounds__(256) void gemm_bf16(
    const unsigned short* __restrict__ A, const unsigned short* __restrict__ W,
    const float* __restrict__ bias, float* __restrict__ Cf, unsigned short* __restrict__ Cb,
    int nrows, int K, int mout, int act) {
  __shared__ unsigned short As[128][40];
  __shared__ unsigned short Ws[128][40];
  int t = threadIdx.x;
  int lane = t & 63, w = t >> 6;
  int wm = w >> 1, wn = w & 1;
  int q = lane >> 4, mr = lane & 15;
  int rowBase = blockIdx.x * 128;
  int colBase = blockIdx.y * 128;
  f32x4 acc[4][4] = {};
  for (int k0 = 0; k0 < K; k0 += 32) {
#pragma unroll
    for (int half = 0; half < 2; ++half) {
      int c = t + half * 256;
      int row = c >> 2, c16 = c & 3;
      int gr = rowBase + row;
      bf16x8 av = {0, 0, 0, 0, 0, 0, 0, 0};
      if (gr < nrows) av = *(const bf16x8*)(A + (size_t)gr * K + k0 + c16 * 8);
      *(bf16x8*)&As[row][c16 * 8] = av;
      bf16x8 wv = *(const bf16x8*)(W + (size_t)(colBase + row) * K + k0 + c16 * 8);
      *(bf16x8*)&Ws[row][c16 * 8] = wv;
    }
    __syncthreads();
    bf16x8 af[4], bfr[4];
#pragma unroll
    for (int mt = 0; mt < 4; ++mt) af[mt] = *(const bf16x8*)&As[wm * 64 + mt * 16 + mr][q * 8];
#pragma unroll
    for (int nt = 0; nt < 4; ++nt) bfr[nt] = *(const bf16x8*)&Ws[wn * 64 + nt * 16 + mr][q * 8];
#pragma unroll
    for (int mt = 0; mt < 4; ++mt)
#pragma unroll
      for (int nt = 0; nt < 4; ++nt)
        acc[mt][nt] = __builtin_amdgcn_mfma_f32_16x16x32_bf16(af[mt], bfr[nt], acc[mt][nt], 0, 0, 0);
    __syncthreads();
  }
#pragma unroll
  for (int mt = 0; mt < 4; ++mt)
#pragma unroll
    for (int nt = 0; nt < 4; ++nt)
#pragma unroll
      for (int r = 0; r < 4; ++r) {
        int row = rowBase + wm * 64 + mt * 16 + q * 4 + r;
        int col = colBase + wn * 64 + nt * 16 + mr;
        if (row < nrows) {
          float v = acc[mt][nt][r] + bias[col];
          if (act) v = v / (1.f + expf(-v));
          if (Cb) Cb[(size_t)row * mout + col] = f2b(v);
          else    Cf[(size_t)row * mout + col] = v;
        }
      }
}

// ---- dual-output GEMM: blockIdx.y selects (W1->C1) vs (W2->C2); K=HID ----
__global__ __launch_bounds__(256) void gemm_dual(
    const unsigned short* __restrict__ A,
    const unsigned short* __restrict__ W1, const unsigned short* __restrict__ W2,
    const float* __restrict__ b1, const float* __restrict__ b2,
    unsigned short* __restrict__ C1, unsigned short* __restrict__ C2,
    int nrows, int K, int mout, int HP) {
  int sel = (int)blockIdx.y / HP;
  int cy = (int)blockIdx.y - sel * HP;
  const unsigned short* W = sel ? W2 : W1;
  const float* bias = sel ? b2 : b1;
  unsigned short* Cb = sel ? C2 : C1;
  __shared__ unsigned short As[128][40];
  __shared__ unsigned short Ws[128][40];
  int t = threadIdx.x;
  int lane = t & 63, w = t >> 6;
  int wm = w >> 1, wn = w & 1;
  int q = lane >> 4, mr = lane & 15;
  int rowBase = blockIdx.x * 128;
  int colBase = cy * 128;
  f32x4 acc[4][4] = {};
  for (int k0 = 0; k0 < K; k0 += 32) {
#pragma unroll
    for (int half = 0; half < 2; ++half) {
      int c = t + half * 256;
      int row = c >> 2, c16 = c & 3;
      int gr = rowBase + row;
      bf16x8 av = {0, 0, 0, 0, 0, 0, 0, 0};
      if (gr < nrows) av = *(const bf16x8*)(A + (size_t)gr * K + k0 + c16 * 8);
      *(bf16x8*)&As[row][c16 * 8] = av;
      bf16x8 wv = *(const bf16x8*)(W + (size_t)(colBase + row) * K + k0 + c16 * 8);
      *(bf16x8*)&Ws[row][c16 * 8] = wv;
    }
    __syncthreads();
    bf16x8 af[4], bfr[4];
#pragma unroll
    for (int mt = 0; mt < 4; ++mt) af[mt] = *(const bf16x8*)&As[wm * 64 + mt * 16 + mr][q * 8];
#pragma unroll
    for (int nt = 0; nt < 4; ++nt) bfr[nt] = *(const bf16x8*)&Ws[wn * 64 + nt * 16 + mr][q * 8];
#pragma unroll
    for (int mt = 0; mt < 4; ++mt)
#pragma unroll
      for (int nt = 0; nt < 4; ++nt)
        acc[mt][nt] = __builtin_amdgcn_mfma_f32_16x16x32_bf16(af[mt], bfr[nt], acc[mt][nt], 0, 0, 0);
    __syncthreads();
  }
#pragma unroll
  for (int mt = 0; mt < 4; ++mt)
#pragma unroll
    for (int nt = 0; nt < 4; ++nt)
#pragma unroll
      for (int r = 0; r < 4; ++r) {
        int row = rowBase + wm * 64 + mt * 16 + q * 4 + r;
        int col = colBase + wn * 64 + nt * 16 + mr;
        if (row < nrows) {
          float v = acc[mt][nt][r] + bias[col];
          Cb[(size_t)row * mout + col] = f2b(v);
        }
      }
}

// ---- concat(x, id_emb[tok]) -> bf16 (N,96) ----
__global__ void build_xin_bf(const float* __restrict__ x, const int* __restrict__ idtok,
                             const float* __restrict__ emb, unsigned short* __restrict__ xin) {
  int i = blockIdx.x * blockDim.x + threadIdx.x;
  if (i >= NN * 96) return;
  int n = i / 96, k = i - n * 96;
  float v = (k < FN) ? x[(size_t)n * FN + k] : emb[(size_t)idtok[n] * IDE + (k - FN)];
  xin[i] = f2b(v);
}

// ---- edge lists per relation ----
// ballot-popcount histogram: 4 atomics/wave (data-dependent address defeats
// the compiler's per-wave atomic coalescing -> must aggregate manually)
__global__ void hist_et(const int* __restrict__ et, int* __restrict__ ecnt) {
  int i = blockIdx.x * blockDim.x + threadIdx.x;
  bool valid = i < NE;
  int r = valid ? et[i] : -1;
  int lane = threadIdx.x & 63;
  for (int rr = 0; rr < NR; ++rr) {
    unsigned long long m = __ballot(valid && r == rr);
    if (m != 0ull && lane == __ffsll((unsigned long long)m) - 1)
      atomicAdd(&ecnt[rr], __popcll(m));
  }
}
__global__ void scan_et(const int* __restrict__ ecnt, int* __restrict__ ebase) {
  if (threadIdx.x == 0 && blockIdx.x == 0) {
    int b = 0;
    for (int r = 0; r < NR; ++r) { ebase[r] = b; b += ecnt[r]; }
    ebase[NR] = b;
  }
}
__global__ void scatter_et(const int* __restrict__ et, const int* __restrict__ ebase,
                           int* __restrict__ ecur, int* __restrict__ elist) {
  int i = blockIdx.x * blockDim.x + threadIdx.x;
  bool valid = i < NE;
  int r = valid ? et[i] : -1;
  int lane = threadIdx.x & 63;
  for (int rr = 0; rr < NR; ++rr) {
    unsigned long long m = __ballot(valid && r == rr);
    if (m == 0ull) continue;
    int leader = __ffsll((unsigned long long)m) - 1;
    int base = 0;
    if (lane == leader) base = atomicAdd(&ecur[rr], __popcll(m));
    base = __shfl(base, leader, 64);
    if (valid && r == rr) {
      unsigned long long below = m & ((1ull << lane) - 1ull);
      elist[ebase[rr] + base + __popcll(below)] = i;
    }
  }
}

// ---- per-layer gate + fused conv_bias ----
__global__ void gate_cb(const float* __restrict__ rg, const float* __restrict__ cbias,
                        float* __restrict__ gate, float* __restrict__ cb) {
  __shared__ float g[NR];
  int t = threadIdx.x;
  if (t == 0) {
    float mx = rg[0];
    for (int r = 1; r < NR; ++r) mx = fmaxf(mx, rg[r]);
    float s = 0.f, tmp[NR];
    for (int r = 0; r < NR; ++r) { tmp[r] = expf(rg[r] - mx); s += tmp[r]; }
    for (int r = 0; r < NR; ++r) { g[r] = tmp[r] / s; gate[r] = g[r]; }
  }
  __syncthreads();
  float c = 0.f;
  for (int r = 0; r < NR; ++r) c += g[r] * cbias[r * HID + t];
  cb[t] = c;
}

// ---- pass A: one wave per (edge-group, head); 8 edges/wave ----
__global__ __launch_bounds__(256) void edge_logit_g(
    const int* __restrict__ ei, const int* __restrict__ elist, const int* __restrict__ ebase,
    const float* __restrict__ eattr, const float* __restrict__ relembp,
    const float* __restrict__ wedgep, const float* __restrict__ attwp,
    const unsigned short* __restrict__ xlb, const unsigned short* __restrict__ xrb,
    float* __restrict__ logit, unsigned* __restrict__ mkey,
    int rel, int HP, int lghp, int stride) {
  int s = ebase[rel], cnt = ebase[rel + 1] - s;
  int gw = blockIdx.x * 4 + (threadIdx.x >> 6);
  int eg = gw >> lghp, hh = gw & (HP - 1);
  int e0 = eg * 8;
  if (e0 >= cnt) return;
  int lane = threadIdx.x & 63;
  float wreg[2][24], areg[2], rreg[8];
#pragma unroll
  for (int j = 0; j < 2; ++j) {
    int col = hh * 128 + lane + j * 64;
    const float* wp = wedgep + (size_t)col * 24;
#pragma unroll
    for (int k = 0; k < 24; ++k) wreg[j][k] = wp[k];
    areg[j] = attwp[col];
  }
#pragma unroll
  for (int k = 0; k < 8; ++k) rreg[k] = relembp[k];
  for (int i = 0; i < 8; ++i) {
    int li = e0 + i;
    if (li >= cnt) break;
    int e = elist[s + li];
    int src = ei[e], dst = ei[NE + e];
    const float* eap = eattr + (size_t)e * NEA;
    float er[NEA];
#pragma unroll
    for (int k = 0; k < NEA; ++k) er[k] = eap[k];
    float p = 0.f;
#pragma unroll
    for (int j = 0; j < 2; ++j) {
      int col = hh * 128 + lane + j * 64;
      float eev = 0.f;
#pragma unroll
      for (int k = 0; k < NEA; ++k) eev += er[k] * wreg[j][k];
#pragma unroll
      for (int k = 0; k < 8; ++k) eev += rreg[k] * wreg[j][NEA + k];
      float sv = b2f(xlb[(size_t)src * stride + col]) + b2f(xrb[(size_t)dst * stride + col]) + eev;
      sv = (sv > 0.f) ? sv : 0.2f * sv;
      p += sv * areg[j];
    }
#pragma unroll
    for (int o = 32; o > 0; o >>= 1) p += __shfl_xor(p, o, 64);
    if (lane == 0) {
      logit[(size_t)li * HP + hh] = p;
      atomicMax(mkey + (size_t)dst * HP + hh, fkey(p));
    }
  }
}

// ---- pass B ----
__global__ void edge_exp_g(const int* __restrict__ ei, const int* __restrict__ elist,
                           const int* __restrict__ ebase, const float* __restrict__ logit,
                           const unsigned* __restrict__ mkey, float* __restrict__ aexp,
                           float* __restrict__ den, int rel, int HP, int lghp) {
  int i = blockIdx.x * blockDim.x + threadIdx.x;
  int li = i >> lghp, hh = i & (HP - 1);
  int s = ebase[rel], cnt = ebase[rel + 1] - s;
  if (li >= cnt) return;
  int e = elist[s + li];
  int dst = ei[NE + e];
  float m = unkey(mkey[(size_t)dst * HP + hh]);
  float a = expf(logit[i] - m);
  aexp[i] = a;
  atomicAdd(den + (size_t)dst * HP + hh, a);
}

// ---- pass C ----
__global__ __launch_bounds__(256) void edge_aggr_g(
    const int* __restrict__ ei, const int* __restrict__ elist, const int* __restrict__ ebase,
    const float* __restrict__ aexp, const float* __restrict__ den,
    const unsigned short* __restrict__ xlb, float* __restrict__ hmsg,
    const float* __restrict__ gate, int rel, int HP, int stride) {
  int s = ebase[rel], cnt = ebase[rel + 1] - s;
  int li = blockIdx.x * 2 + (threadIdx.x >> 7);
  int tt = threadIdx.x & 127;
  if (li >= cnt) return;
  int e = elist[s + li];
  int src = ei[e], dst = ei[NE + e];
  float g = gate[rel] * 0.25f;
  float v = 0.f;
  for (int h = 0; h < HP; ++h) {
    float d = den[(size_t)dst * HP + h];
    d = (d == 0.f) ? 1.f : d;
    float w = g * aexp[(size_t)li * HP + h] / d;
    v += w * b2f(xlb[(size_t)src * stride + h * 128 + tt]);
  }
  atomicAdd(hmsg + (size_t)dst * HID + tt, v);
}

// ---- h = layernorm(h + add (+ cb)) ----
__global__ __launch_bounds__(256) void add_ln(
    float* __restrict__ h, const float* __restrict__ add, const float* __restrict__ cb,
    const float* __restrict__ w, const float* __restrict__ b, int nrows) {
  int wave = threadIdx.x >> 6, lane = threadIdx.x & 63;
  int row = blockIdx.x * 4 + wave;
  if (row >= nrows) return;
  size_t base = (size_t)row * HID;
  float x0 = h[base + lane] + add[base + lane];
  float x1 = h[base + 64 + lane] + add[base + 64 + lane];
  if (cb) { x0 += cb[lane]; x1 += cb[64 + lane]; }
  float s = x0 + x1;
#pragma unroll
  for (int o = 32; o > 0; o >>= 1) s += __shfl_xor(s, o, 64);
  float mean = s * (1.f / 128.f);
  float d0 = x0 - mean, d1 = x1 - mean;
  float v = d0 * d0 + d1 * d1;
#pragma unroll
  for (int o = 32; o > 0; o >>= 1) v += __shfl_xor(v, o, 64);
  float inv = 1.f / sqrtf(v * (1.f / 128.f) + 1e-5f);
  h[base + lane] = d0 * inv * w[lane] + b[lane];
  h[base + 64 + lane] = d1 * inv * w[64 + lane] + b[64 + lane];
}

// ---- readout ----
__global__ __launch_bounds__(128) void readout_acc(
    const float* __restrict__ h, const int* __restrict__ batch,
    float* __restrict__ cnt, float* __restrict__ sum, unsigned* __restrict__ maxk) {
  int n = blockIdx.x, t = threadIdx.x;
  int b = batch[n];
  float v = h[(size_t)n * HID + t];
  atomicAdd(sum + (size_t)b * HID + t, v);
  atomicMax(maxk + (size_t)b * HID + t, fkey(v));
  if (t == 0) atomicAdd(cnt + b, 1.f);
}

__global__ __launch_bounds__(256) void readout_final(
    const float* __restrict__ cnt, const float* __restrict__ sum,
    const unsigned* __restrict__ maxk, const float* __restrict__ w,
    const float* __restrict__ b, float* __restrict__ g) {
  int bg = blockIdx.x, t = threadIdx.x;
  __shared__ float red[256];
  float c = fmaxf(cnt[bg], 1.f);
  float x = (t < HID) ? sum[(size_t)bg * HID + t] / c
                      : unkey(maxk[(size_t)bg * HID + (t - HID)]);
  red[t] = x;
  __syncthreads();
  for (int s = 128; s > 0; s >>= 1) {
    if (t < s) red[t] += red[t + s];
    __syncthreads();
  }
  float mean = red[0] * (1.f / 256.f);
  __syncthreads();
  float d = x - mean;
  red[t] = d * d;
  __syncthreads();
  for (int s = 128; s > 0; s >>= 1) {
    if (t < s) red[t] += red[t + s];
    __syncthreads();
  }
  float inv = 1.f / sqrtf(red[0] * (1.f / 256.f) + 1e-5f);
  g[(size_t)bg * 256 + t] = d * inv * w[t] + b[t];
}

// ---- B-splines ----
__device__ __forceinline__ void bspline8(float x, const float* __restrict__ t,
                                         float* __restrict__ out) {
  float bs[11];
#pragma unroll
  for (int j = 0; j < 11; ++j) bs[j] = (x >= t[j] && x < t[j + 1]) ? 1.f : 0.f;
#pragma unroll
  for (int k = 1; k <= 3; ++k) {
    for (int j = 0; j < 11 - k; ++j) {
      bs[j] = (x - t[j]) / (t[j + k] - t[j]) * bs[j] +
              (t[j + k + 1] - x) / (t[j + k + 1] - t[j + 1]) * bs[j + 1];
    }
  }
#pragma unroll
  for (int j = 0; j < 8; ++j) out[j] = bs[j];
}

__global__ __launch_bounds__(128) void kan1(
    const float* __restrict__ g, const float* __restrict__ bw,
    const float* __restrict__ sw, const float* __restrict__ sc,
    const float* __restrict__ grid, float* __restrict__ z) {
  int bg = blockIdx.x, t = threadIdx.x;
  __shared__ float B[256][8];
  __shared__ float sg[256];
  for (int i = t; i < 256; i += 128) {
    float x = g[(size_t)bg * 256 + i];
    sg[i] = x / (1.f + expf(-x));
    bspline8(x, grid + (size_t)i * 12, B[i]);
  }
  __syncthreads();
  float acc = 0.f;
  for (int i = 0; i < 256; ++i) {
    acc += sg[i] * bw[(size_t)t * 256 + i];
    const float* swp = sw + ((size_t)t * 256 + i) * 8;
    float sp = 0.f;
#pragma unroll
    for (int k = 0; k < 8; ++k) sp += B[i][k] * swp[k];
    acc += sp * sc[(size_t)t * 256 + i];
  }
  z[(size_t)bg * KH + t] = acc;
}

__global__ __launch_bounds__(128) void kan2(
    const float* __restrict__ z, const float* __restrict__ bw,
    const float* __restrict__ sw, const float* __restrict__ sc,
    const float* __restrict__ grid, float* __restrict__ out) {
  int bg = blockIdx.x, t = threadIdx.x;
  __shared__ float B[128][8];
  __shared__ float sz[128];
  float x = z[(size_t)bg * KH + t];
  sz[t] = x / (1.f + expf(-x));
  bspline8(x, grid + (size_t)t * 12, B[t]);
  __syncthreads();
  if (t < NC) {
    float acc = 0.f;
    for (int i = 0; i < 128; ++i) {
      acc += sz[i] * bw[(size_t)t * 128 + i];
      const float* swp = sw + ((size_t)t * 128 + i) * 8;
      float sp = 0.f;
#pragma unroll
      for (int k = 0; k < 8; ++k) sp += B[i][k] * swp[k];
      acc += sp * sc[(size_t)t * 128 + i];
    }
    out[(size_t)bg * NC + t] = acc;
  }
}

extern "C" void kernel_launch(void* const* d_in, const int* in_sizes, int n_in,
                              void* d_out, int out_size, void* d_ws, size_t ws_size,
                              hipStream_t stream) {
  const float* x       = (const float*)d_in[0];
  const float* eattr   = (const float*)d_in[1];
  const int*   idtok   = (const int*)d_in[2];
  const int*   ei      = (const int*)d_in[3];
  const int*   etype   = (const int*)d_in[4];
  const int*   batch   = (const int*)d_in[5];
  const float* idemb   = (const float*)d_in[6];
  const float* inw     = (const float*)d_in[7];
  const float* inb     = (const float*)d_in[8];
  const float* relemb  = (const float*)d_in[9];
  const float* linlw   = (const float*)d_in[10];
  const float* linlb   = (const float*)d_in[11];
  const float* linrw   = (const float*)d_in[12];
  const float* linrb   = (const float*)d_in[13];
  const float* linew   = (const float*)d_in[14];
  const float* attw    = (const float*)d_in[15];
  const float* convb   = (const float*)d_in[16];
  const float* relgate = (const float*)d_in[17];
  const float* n1w     = (const float*)d_in[18];
  const float* n1b     = (const float*)d_in[19];
  const float* n2w     = (const float*)d_in[20];
  const float* n2b     = (const float*)d_in[21];
  const float* f1w     = (const float*)d_in[22];
  const float* f1bias  = (const float*)d_in[23];
  const float* f2w     = (const float*)d_in[24];
  const float* f2bias  = (const float*)d_in[25];
  const float* rnw     = (const float*)d_in[26];
  const float* rnb     = (const float*)d_in[27];
  const float* bw1     = (const float*)d_in[28];
  const float* sw1     = (const float*)d_in[29];
  const float* sc1     = (const float*)d_in[30];
  const float* grid1   = (const float*)d_in[31];
  const float* bw2     = (const float*)d_in[32];
  const float* sw2     = (const float*)d_in[33];
  const float* sc2     = (const float*)d_in[34];
  const float* grid2   = (const float*)d_in[35];
  float* out = (float*)d_out;
  (void)in_sizes; (void)n_in; (void)out_size;

  // ---- pick heads-per-pass: full-head (4) if workspace allows, else head-pair ----
  auto needed = [](int HP) -> size_t {
    auto al = [](size_t b) { return (b + 255) & ~(size_t)255; };
    size_t o = 0;
    o += al((size_t)NN * HID * 4) * 2;
    o += al((size_t)NN * HID * 2);
    o += al((size_t)NN * 128 * HP * 2) * 2;
    o += al((size_t)NE * HP * 4) * 2;
    o += al((size_t)NN * HP * 8);
    o += al((size_t)NE * 4) + al(64);
    o += al((size_t)NL * NR * 512 * 128 * 2) * 2;
    o += al((size_t)NL * 256 * 128 * 2) * 2;
    o += al((size_t)128 * 96 * 2);
    o += al(NR * 4) + al(HID * 4);
    o += al((size_t)(NG + NG * HID * 2) * 4);
    o += al((size_t)NG * 256 * 4) + al((size_t)NG * KH * 4);
    return o;
  };
  const int HP = (needed(4) <= ws_size) ? 4 : 2;
  const int lghp = (HP == 4) ? 2 : 1;
  const int passes = NH / HP;
  const int stride = HP * 128;

  // ---- workspace carve ----
  char* p = (char*)d_ws;
  auto alloc = [&](size_t bytes) { void* q = (void*)p; p += (bytes + 255) & ~(size_t)255; return q; };
  float* h    = (float*)alloc((size_t)NN * HID * 4);
  float* hmsg = (float*)alloc((size_t)NN * HID * 4);
  unsigned short* hbf = (unsigned short*)alloc((size_t)NN * HID * 2);
  unsigned short* xlb = (unsigned short*)alloc((size_t)NN * 128 * HP * 2);
  unsigned short* xrb = (unsigned short*)alloc((size_t)NN * 128 * HP * 2);
  float* logit = (float*)alloc((size_t)NE * HP * 4);
  float* aexp  = (float*)alloc((size_t)NE * HP * 4);
  unsigned* mkey = (unsigned*)alloc((size_t)NN * HP * 8);
  float* den = (float*)(mkey + (size_t)NN * HP);
  int* elist = (int*)alloc((size_t)NE * 4);
  int* ecnt  = (int*)alloc(64);
  int* ecur  = ecnt + 4;
  int* ebase = ecnt + 8;
  unsigned short* linlwb = (unsigned short*)alloc((size_t)NL * NR * 512 * 128 * 2);
  unsigned short* linrwb = (unsigned short*)alloc((size_t)NL * NR * 512 * 128 * 2);
  unsigned short* f1wb   = (unsigned short*)alloc((size_t)NL * 256 * 128 * 2);
  unsigned short* f2wb   = (unsigned short*)alloc((size_t)NL * 128 * 256 * 2);
  unsigned short* inwb   = (unsigned short*)alloc((size_t)128 * 96 * 2);
  float* gate = (float*)alloc(NR * 4);
  float* cb   = (float*)alloc(HID * 4);
  float* rcnt = (float*)alloc((size_t)(NG + NG * HID * 2) * 4);
  float* rsum = rcnt + NG;
  unsigned* rmaxk = (unsigned*)(rsum + (size_t)NG * HID);
  float* g = (float*)alloc((size_t)NG * 256 * 4);
  float* z = (float*)alloc((size_t)NG * KH * 4);
  unsigned short* xinbf = xlb;
  unsigned short* f1buf = xlb;

  const int NB = (NN + 127) / 128;

  // ---- weight conversions ----
  {
    int n;
    n = NL * NR * 512 * 128 / 4;
    cvt_bf16<<<(n + 255) / 256, 256, 0, stream>>>(linlw, linlwb, n);
    cvt_bf16<<<(n + 255) / 256, 256, 0, stream>>>(linrw, linrwb, n);
    n = NL * 256 * 128 / 4;
    cvt_bf16<<<(n + 255) / 256, 256, 0, stream>>>(f1w, f1wb, n);
    cvt_bf16<<<(n + 255) / 256, 256, 0, stream>>>(f2w, f2wb, n);
    n = 128 * 96 / 4;
    cvt_bf16<<<(n + 255) / 256, 256, 0, stream>>>(inw, inwb, n);
  }

  // ---- edge lists ----
  hipMemsetAsync(ecnt, 0, 8 * 4, stream);
  hist_et<<<(NE + 255) / 256, 256, 0, stream>>>(etype, ecnt);
  scan_et<<<1, 64, 0, stream>>>(ecnt, ebase);
  scatter_et<<<(NE + 255) / 256, 256, 0, stream>>>(etype, ebase, ecur, elist);

  // ---- input projection ----
  build_xin_bf<<<(NN * 96 + 255) / 256, 256, 0, stream>>>(x, idtok, idemb, xinbf);
  gemm_bf16<<<dim3(NB, 1), 256, 0, stream>>>(xinbf, inwb, inb, h, nullptr, NN, 96, 128, 1);

  const int logit_blocks = (((NE + 7) / 8) * HP + 3) / 4;
  for (int l = 0; l < NL; ++l) {
    gate_cb<<<1, 128, 0, stream>>>(relgate + l * NR, convb + (size_t)l * NR * HID, gate, cb);
    hipMemsetAsync(hmsg, 0, (size_t)NN * HID * 4, stream);
    cvt_bf16<<<(NN * HID / 4 + 255) / 256, 256, 0, stream>>>(h, hbf, NN * HID / 4);
    for (int r = 0; r < NR; ++r) {
      int lr = l * NR + r;
      for (int hp = 0; hp < passes; ++hp) {
        int hpBase = hp * HP;
        const unsigned short* wl = linlwb + ((size_t)lr * 512 + hpBase * 128) * 128;
        const unsigned short* wr = linrwb + ((size_t)lr * 512 + hpBase * 128) * 128;
        const float* bl = linlb + (size_t)lr * 512 + hpBase * 128;
        const float* br = linrb + (size_t)lr * 512 + hpBase * 128;
        gemm_dual<<<dim3(NB, 2 * HP), 256, 0, stream>>>(hbf, wl, wr, bl, br, xlb, xrb,
                                                        NN, 128, stride, HP);
        hipMemsetAsync(mkey, 0, (size_t)NN * HP * 8, stream);
        edge_logit_g<<<logit_blocks, 256, 0, stream>>>(
            ei, elist, ebase, eattr, relemb + (size_t)lr * RED,
            linew + ((size_t)lr * 512 + hpBase * 128) * 24,
            attw + (size_t)lr * 512 + hpBase * 128,
            xlb, xrb, logit, mkey, r, HP, lghp, stride);
        edge_exp_g<<<(NE * HP + 255) / 256, 256, 0, stream>>>(
            ei, elist, ebase, logit, mkey, aexp, den, r, HP, lghp);
        edge_aggr_g<<<(NE + 1) / 2, 256, 0, stream>>>(
            ei, elist, ebase, aexp, den, xlb, hmsg, gate, r, HP, stride);
      }
    }
    add_ln<<<(NN + 3) / 4, 256, 0, stream>>>(h, hmsg, cb, n1w + l * HID, n1b + l * HID, NN);
    cvt_bf16<<<(NN * HID / 4 + 255) / 256, 256, 0, stream>>>(h, hbf, NN * HID / 4);
    gemm_bf16<<<dim3(NB, 2), 256, 0, stream>>>(hbf, f1wb + (size_t)l * 256 * 128,
                                               f1bias + (size_t)l * 256, nullptr, f1buf,
                                               NN, 128, 256, 1);
    gemm_bf16<<<dim3(NB, 1), 256, 0, stream>>>(f1buf, f2wb + (size_t)l * 128 * 256,
                                               f2bias + (size_t)l * 128, hmsg, nullptr,
                                               NN, 256, 128, 0);
    add_ln<<<(NN + 3) / 4, 256, 0, stream>>>(h, hmsg, nullptr, n2w + l * HID, n2b + l * HID, NN);
  }

  hipMemsetAsync(rcnt, 0, (size_t)(NG + NG * HID * 2) * 4, stream);
  readout_acc<<<NN, 128, 0, stream>>>(h, batch, rcnt, rsum, rmaxk);
  readout_final<<<NG, 256, 0, stream>>>(rcnt, rsum, rmaxk, rnw, rnb, g);
  kan1<<<NG, 128, 0, stream>>>(g, bw1, sw1, sc1, grid1, z);
  kan2<<<NG, 128, 0, stream>>>(z, bw2, sw2, sc2, grid2, out);
}

// Round 6
// 2864.008 us; speedup vs baseline: 3.7793x; 1.1340x over previous
//
#include <hip/hip_runtime.h>
#include <math.h>

#define NN 50000
#define NE 120000
#define FN 64
#define NEA 16
#define NR 4
#define NH 4
#define HID 128
#define NL 3
#define IDE 32
#define RED 8
#define NG 64
#define NC 10
#define KH 128
#define FFH 256

typedef short bf16x8 __attribute__((ext_vector_type(8)));
typedef float f32x4 __attribute__((ext_vector_type(4)));

// ---- bf16 helpers (RNE) ----
__device__ __forceinline__ unsigned short f2b(float f) {
  unsigned u = __float_as_uint(f);
  unsigned r = (u + 0x7FFFu + ((u >> 16) & 1u)) >> 16;
  return (unsigned short)r;
}
__device__ __forceinline__ float b2f(unsigned short b) {
  return __uint_as_float((unsigned)b << 16);
}

// ---- monotone float<->uint key for atomic max ----
__device__ __forceinline__ unsigned fkey(float f) {
  unsigned u = __float_as_uint(f);
  return (u & 0x80000000u) ? ~u : (u | 0x80000000u);
}
__device__ __forceinline__ float unkey(unsigned k) {
  unsigned u = (k & 0x80000000u) ? (k ^ 0x80000000u) : ~k;
  return __uint_as_float(u);
}

// ---- f32 -> bf16 bulk convert (n multiple of 4) ----
__global__ void cvt_bf16(const float* __restrict__ s, unsigned short* __restrict__ d, int n4) {
  int i = blockIdx.x * blockDim.x + threadIdx.x;
  if (i >= n4) return;
  float4 v = ((const float4*)s)[i];
  ushort4 o;
  o.x = f2b(v.x); o.y = f2b(v.y); o.z = f2b(v.z); o.w = f2b(v.w);
  ((ushort4*)d)[i] = o;
}

// ---- MFMA bf16 GEMM: C[n][m] = A[n][:K].W[m][:K] + bias[m]; opt silu; out f32 or bf16 ----
__global__ __launch_bounds__(256) void gemm_bf16(
    const unsigned short* __restrict__ A, const unsigned short* __restrict__ W,
    const float* __restrict__ bias, float* __restrict__ Cf, unsigned short* __restrict__ Cb,
    int nrows, int K, int mout, int act) {
  __shared__ unsigned short As[128][40];
  __shared__ unsigned short Ws[128][40];
  int t = threadIdx.x;
  int lane = t & 63, w = t >> 6;
  int wm = w >> 1, wn = w & 1;
  int q = lane >> 4, mr = lane & 15;
  int rowBase = blockIdx.x * 128;
  int colBase = blockIdx.y * 128;
  f32x4 acc[4][4] = {};
  for (int k0 = 0; k0 < K; k0 += 32) {
#pragma unroll
    for (int half = 0; half < 2; ++half) {
      int c = t + half * 256;
      int row = c >> 2, c16 = c & 3;
      int gr = rowBase + row;
      bf16x8 av = {0, 0, 0, 0, 0, 0, 0, 0};
      if (gr < nrows) av = *(const bf16x8*)(A + (size_t)gr * K + k0 + c16 * 8);
      *(bf16x8*)&As[row][c16 * 8] = av;
      bf16x8 wv = *(const bf16x8*)(W + (size_t)(colBase + row) * K + k0 + c16 * 8);
      *(bf16x8*)&Ws[row][c16 * 8] = wv;
    }
    __syncthreads();
    bf16x8 af[4], bfr[4];
#pragma unroll
    for (int mt = 0; mt < 4; ++mt) af[mt] = *(const bf16x8*)&As[wm * 64 + mt * 16 + mr][q * 8];
#pragma unroll
    for (int nt = 0; nt < 4; ++nt) bfr[nt] = *(const bf16x8*)&Ws[wn * 64 + nt * 16 + mr][q * 8];
#pragma unroll
    for (int mt = 0; mt < 4; ++mt)
#pragma unroll
      for (int nt = 0; nt < 4; ++nt)
        acc[mt][nt] = __builtin_amdgcn_mfma_f32_16x16x32_bf16(af[mt], bfr[nt], acc[mt][nt], 0, 0, 0);
    __syncthreads();
  }
#pragma unroll
  for (int mt = 0; mt < 4; ++mt)
#pragma unroll
    for (int nt = 0; nt < 4; ++nt)
#pragma unroll
      for (int r = 0; r < 4; ++r) {
        int row = rowBase + wm * 64 + mt * 16 + q * 4 + r;
        int col = colBase + wn * 64 + nt * 16 + mr;
        if (row < nrows) {
          float v = acc[mt][nt][r] + bias[col];
          if (act) v = v / (1.f + expf(-v));
          if (Cb) Cb[(size_t)row * mout + col] = f2b(v);
          else    Cf[(size_t)row * mout + col] = v;
        }
      }
}

// ---- dual-output GEMM: blockIdx.y selects (W1->C1) vs (W2->C2); K=HID ----
__global__ __launch_bounds__(256) void gemm_dual(
    const unsigned short* __restrict__ A,
    const unsigned short* __restrict__ W1, const unsigned short* __restrict__ W2,
    const float* __restrict__ b1, const float* __restrict__ b2,
    unsigned short* __restrict__ C1, unsigned short* __restrict__ C2,
    int nrows, int K, int mout, int HP) {
  int sel = (int)blockIdx.y / HP;
  int cy = (int)blockIdx.y - sel * HP;
  const unsigned short* W = sel ? W2 : W1;
  const float* bias = sel ? b2 : b1;
  unsigned short* Cb = sel ? C2 : C1;
  __shared__ unsigned short As[128][40];
  __shared__ unsigned short Ws[128][40];
  int t = threadIdx.x;
  int lane = t & 63, w = t >> 6;
  int wm = w >> 1, wn = w & 1;
  int q = lane >> 4, mr = lane & 15;
  int rowBase = blockIdx.x * 128;
  int colBase = cy * 128;
  f32x4 acc[4][4] = {};
  for (int k0 = 0; k0 < K; k0 += 32) {
#pragma unroll
    for (int half = 0; half < 2; ++half) {
      int c = t + half * 256;
      int row = c >> 2, c16 = c & 3;
      int gr = rowBase + row;
      bf16x8 av = {0, 0, 0, 0, 0, 0, 0, 0};
      if (gr < nrows) av = *(const bf16x8*)(A + (size_t)gr * K + k0 + c16 * 8);
      *(bf16x8*)&As[row][c16 * 8] = av;
      bf16x8 wv = *(const bf16x8*)(W + (size_t)(colBase + row) * K + k0 + c16 * 8);
      *(bf16x8*)&Ws[row][c16 * 8] = wv;
    }
    __syncthreads();
    bf16x8 af[4], bfr[4];
#pragma unroll
    for (int mt = 0; mt < 4; ++mt) af[mt] = *(const bf16x8*)&As[wm * 64 + mt * 16 + mr][q * 8];
#pragma unroll
    for (int nt = 0; nt < 4; ++nt) bfr[nt] = *(const bf16x8*)&Ws[wn * 64 + nt * 16 + mr][q * 8];
#pragma unroll
    for (int mt = 0; mt < 4; ++mt)
#pragma unroll
      for (int nt = 0; nt < 4; ++nt)
        acc[mt][nt] = __builtin_amdgcn_mfma_f32_16x16x32_bf16(af[mt], bfr[nt], acc[mt][nt], 0, 0, 0);
    __syncthreads();
  }
#pragma unroll
  for (int mt = 0; mt < 4; ++mt)
#pragma unroll
    for (int nt = 0; nt < 4; ++nt)
#pragma unroll
      for (int r = 0; r < 4; ++r) {
        int row = rowBase + wm * 64 + mt * 16 + q * 4 + r;
        int col = colBase + wn * 64 + nt * 16 + mr;
        if (row < nrows) {
          float v = acc[mt][nt][r] + bias[col];
          Cb[(size_t)row * mout + col] = f2b(v);
        }
      }
}

// ---- concat(x, id_emb[tok]) -> bf16 (N,96) ----
__global__ void build_xin_bf(const float* __restrict__ x, const int* __restrict__ idtok,
                             const float* __restrict__ emb, unsigned short* __restrict__ xin) {
  int i = blockIdx.x * blockDim.x + threadIdx.x;
  if (i >= NN * 96) return;
  int n = i / 96, k = i - n * 96;
  float v = (k < FN) ? x[(size_t)n * FN + k] : emb[(size_t)idtok[n] * IDE + (k - FN)];
  xin[i] = f2b(v);
}

// ---- edge lists per relation ----
__global__ void hist_et(const int* __restrict__ et, int* __restrict__ ecnt) {
  int i = blockIdx.x * blockDim.x + threadIdx.x;
  bool valid = i < NE;
  int r = valid ? et[i] : -1;
  int lane = threadIdx.x & 63;
  for (int rr = 0; rr < NR; ++rr) {
    unsigned long long m = __ballot(valid && r == rr);
    if (m != 0ull && lane == __ffsll((unsigned long long)m) - 1)
      atomicAdd(&ecnt[rr], __popcll(m));
  }
}
__global__ void scan_et(const int* __restrict__ ecnt, int* __restrict__ ebase) {
  if (threadIdx.x == 0 && blockIdx.x == 0) {
    int b = 0;
    for (int r = 0; r < NR; ++r) { ebase[r] = b; b += ecnt[r]; }
    ebase[NR] = b;
  }
}
__global__ void scatter_et(const int* __restrict__ et, const int* __restrict__ ebase,
                           int* __restrict__ ecur, int* __restrict__ elist) {
  int i = blockIdx.x * blockDim.x + threadIdx.x;
  bool valid = i < NE;
  int r = valid ? et[i] : -1;
  int lane = threadIdx.x & 63;
  for (int rr = 0; rr < NR; ++rr) {
    unsigned long long m = __ballot(valid && r == rr);
    if (m == 0ull) continue;
    int leader = __ffsll((unsigned long long)m) - 1;
    int base = 0;
    if (lane == leader) base = atomicAdd(&ecur[rr], __popcll(m));
    base = __shfl(base, leader, 64);
    if (valid && r == rr) {
      unsigned long long below = m & ((1ull << lane) - 1ull);
      elist[ebase[rr] + base + __popcll(below)] = i;
    }
  }
}

// ---- per-layer gate + fused conv_bias ----
__global__ void gate_cb(const float* __restrict__ rg, const float* __restrict__ cbias,
                        float* __restrict__ gate, float* __restrict__ cb) {
  __shared__ float g[NR];
  int t = threadIdx.x;
  if (t == 0) {
    float mx = rg[0];
    for (int r = 1; r < NR; ++r) mx = fmaxf(mx, rg[r]);
    float s = 0.f, tmp[NR];
    for (int r = 0; r < NR; ++r) { tmp[r] = expf(rg[r] - mx); s += tmp[r]; }
    for (int r = 0; r < NR; ++r) { g[r] = tmp[r] / s; gate[r] = g[r]; }
  }
  __syncthreads();
  float c = 0.f;
  for (int r = 0; r < NR; ++r) c += g[r] * cbias[r * HID + t];
  cb[t] = c;
}

// ---- pass A: one wave per (edge-group, head); 8 edges/wave ----
__global__ __launch_bounds__(256) void edge_logit_g(
    const int* __restrict__ ei, const int* __restrict__ elist, const int* __restrict__ ebase,
    const float* __restrict__ eattr, const float* __restrict__ relembp,
    const float* __restrict__ wedgep, const float* __restrict__ attwp,
    const unsigned short* __restrict__ xlb, const unsigned short* __restrict__ xrb,
    float* __restrict__ logit, unsigned* __restrict__ mkey,
    int rel, int HP, int lghp, int stride) {
  int s = ebase[rel], cnt = ebase[rel + 1] - s;
  int gw = blockIdx.x * 4 + (threadIdx.x >> 6);
  int eg = gw >> lghp, hh = gw & (HP - 1);
  int e0 = eg * 8;
  if (e0 >= cnt) return;
  int lane = threadIdx.x & 63;
  float wreg[2][24], areg[2], rreg[8];
#pragma unroll
  for (int j = 0; j < 2; ++j) {
    int col = hh * 128 + lane + j * 64;
    const float* wp = wedgep + (size_t)col * 24;
#pragma unroll
    for (int k = 0; k < 24; ++k) wreg[j][k] = wp[k];
    areg[j] = attwp[col];
  }
#pragma unroll
  for (int k = 0; k < 8; ++k) rreg[k] = relembp[k];
  for (int i = 0; i < 8; ++i) {
    int li = e0 + i;
    if (li >= cnt) break;
    int e = elist[s + li];
    int src = ei[e], dst = ei[NE + e];
    const float* eap = eattr + (size_t)e * NEA;
    float er[NEA];
#pragma unroll
    for (int k = 0; k < NEA; ++k) er[k] = eap[k];
    float p = 0.f;
#pragma unroll
    for (int j = 0; j < 2; ++j) {
      int col = hh * 128 + lane + j * 64;
      float eev = 0.f;
#pragma unroll
      for (int k = 0; k < NEA; ++k) eev += er[k] * wreg[j][k];
#pragma unroll
      for (int k = 0; k < 8; ++k) eev += rreg[k] * wreg[j][NEA + k];
      float sv = b2f(xlb[(size_t)src * stride + col]) + b2f(xrb[(size_t)dst * stride + col]) + eev;
      sv = (sv > 0.f) ? sv : 0.2f * sv;
      p += sv * areg[j];
    }
#pragma unroll
    for (int o = 32; o > 0; o >>= 1) p += __shfl_xor(p, o, 64);
    if (lane == 0) {
      logit[(size_t)li * HP + hh] = p;
      atomicMax(mkey + (size_t)dst * HP + hh, fkey(p));
    }
  }
}

// ---- pass B ----
__global__ void edge_exp_g(const int* __restrict__ ei, const int* __restrict__ elist,
                           const int* __restrict__ ebase, const float* __restrict__ logit,
                           const unsigned* __restrict__ mkey, float* __restrict__ aexp,
                           float* __restrict__ den, int rel, int HP, int lghp) {
  int i = blockIdx.x * blockDim.x + threadIdx.x;
  int li = i >> lghp, hh = i & (HP - 1);
  int s = ebase[rel], cnt = ebase[rel + 1] - s;
  if (li >= cnt) return;
  int e = elist[s + li];
  int dst = ei[NE + e];
  float m = unkey(mkey[(size_t)dst * HP + hh]);
  float a = expf(logit[i] - m);
  aexp[i] = a;
  atomicAdd(den + (size_t)dst * HP + hh, a);
}

// ---- pass C ----
__global__ __launch_bounds__(256) void edge_aggr_g(
    const int* __restrict__ ei, const int* __restrict__ elist, const int* __restrict__ ebase,
    const float* __restrict__ aexp, const float* __restrict__ den,
    const unsigned short* __restrict__ xlb, float* __restrict__ hmsg,
    const float* __restrict__ gate, int rel, int HP, int stride) {
  int s = ebase[rel], cnt = ebase[rel + 1] - s;
  int li = blockIdx.x * 2 + (threadIdx.x >> 7);
  int tt = threadIdx.x & 127;
  if (li >= cnt) return;
  int e = elist[s + li];
  int src = ei[e], dst = ei[NE + e];
  float g = gate[rel] * 0.25f;
  float v = 0.f;
  for (int h = 0; h < HP; ++h) {
    float d = den[(size_t)dst * HP + h];
    d = (d == 0.f) ? 1.f : d;
    float w = g * aexp[(size_t)li * HP + h] / d;
    v += w * b2f(xlb[(size_t)src * stride + h * 128 + tt]);
  }
  atomicAdd(hmsg + (size_t)dst * HID + tt, v);
}

// ---- h = layernorm(h + add (+ cb)) ----
__global__ __launch_bounds__(256) void add_ln(
    float* __restrict__ h, const float* __restrict__ add, const float* __restrict__ cb,
    const float* __restrict__ w, const float* __restrict__ b, int nrows) {
  int wave = threadIdx.x >> 6, lane = threadIdx.x & 63;
  int row = blockIdx.x * 4 + wave;
  if (row >= nrows) return;
  size_t base = (size_t)row * HID;
  float x0 = h[base + lane] + add[base + lane];
  float x1 = h[base + 64 + lane] + add[base + 64 + lane];
  if (cb) { x0 += cb[lane]; x1 += cb[64 + lane]; }
  float s = x0 + x1;
#pragma unroll
  for (int o = 32; o > 0; o >>= 1) s += __shfl_xor(s, o, 64);
  float mean = s * (1.f / 128.f);
  float d0 = x0 - mean, d1 = x1 - mean;
  float v = d0 * d0 + d1 * d1;
#pragma unroll
  for (int o = 32; o > 0; o >>= 1) v += __shfl_xor(v, o, 64);
  float inv = 1.f / sqrtf(v * (1.f / 128.f) + 1e-5f);
  h[base + lane] = d0 * inv * w[lane] + b[lane];
  h[base + 64 + lane] = d1 * inv * w[64 + lane] + b[64 + lane];
}

// ---- readout: two-phase. batch is SORTED -> register-accumulate per contiguous
// group run, flush one atomic per (group,dim) per run. 12.8M atomics -> ~116k. ----
__global__ __launch_bounds__(128) void readout_partial(
    const float* __restrict__ h, const int* __restrict__ batch,
    float* __restrict__ cnt, float* __restrict__ sum, unsigned* __restrict__ maxk) {
  int t = threadIdx.x;
  int r0 = blockIdx.x * 128;
  int r1 = min(r0 + 128, NN);
  int curg = batch[r0];
  float acc = 0.f, mx = -3.4e38f;
  int c = 0;
  for (int row = r0; row < r1; ++row) {
    int g = batch[row];
    if (g != curg) {
      atomicAdd(sum + (size_t)curg * HID + t, acc);
      atomicMax(maxk + (size_t)curg * HID + t, fkey(mx));
      if (t == 0) atomicAdd(cnt + curg, (float)c);
      acc = 0.f; mx = -3.4e38f; c = 0; curg = g;
    }
    float v = h[(size_t)row * HID + t];
    acc += v;
    mx = fmaxf(mx, v);
    ++c;
  }
  atomicAdd(sum + (size_t)curg * HID + t, acc);
  atomicMax(maxk + (size_t)curg * HID + t, fkey(mx));
  if (t == 0) atomicAdd(cnt + curg, (float)c);
}

__global__ __launch_bounds__(256) void readout_final(
    const float* __restrict__ cnt, const float* __restrict__ sum,
    const unsigned* __restrict__ maxk, const float* __restrict__ w,
    const float* __restrict__ b, float* __restrict__ g) {
  int bg = blockIdx.x, t = threadIdx.x;
  __shared__ float red[256];
  float c = fmaxf(cnt[bg], 1.f);
  float x = (t < HID) ? sum[(size_t)bg * HID + t] / c
                      : unkey(maxk[(size_t)bg * HID + (t - HID)]);
  red[t] = x;
  __syncthreads();
  for (int s = 128; s > 0; s >>= 1) {
    if (t < s) red[t] += red[t + s];
    __syncthreads();
  }
  float mean = red[0] * (1.f / 256.f);
  __syncthreads();
  float d = x - mean;
  red[t] = d * d;
  __syncthreads();
  for (int s = 128; s > 0; s >>= 1) {
    if (t < s) red[t] += red[t + s];
    __syncthreads();
  }
  float inv = 1.f / sqrtf(red[0] * (1.f / 256.f) + 1e-5f);
  g[(size_t)bg * 256 + t] = d * inv * w[t] + b[t];
}

// ---- B-splines ----
__device__ __forceinline__ void bspline8(float x, const float* __restrict__ t,
                                         float* __restrict__ out) {
  float bs[11];
#pragma unroll
  for (int j = 0; j < 11; ++j) bs[j] = (x >= t[j] && x < t[j + 1]) ? 1.f : 0.f;
#pragma unroll
  for (int k = 1; k <= 3; ++k) {
    for (int j = 0; j < 11 - k; ++j) {
      bs[j] = (x - t[j]) / (t[j + k] - t[j]) * bs[j] +
              (t[j + k + 1] - x) / (t[j + k + 1] - t[j + 1]) * bs[j + 1];
    }
  }
#pragma unroll
  for (int j = 0; j < 8; ++j) out[j] = bs[j];
}

__global__ __launch_bounds__(128) void kan1(
    const float* __restrict__ g, const float* __restrict__ bw,
    const float* __restrict__ sw, const float* __restrict__ sc,
    const float* __restrict__ grid, float* __restrict__ z) {
  int bg = blockIdx.x, t = threadIdx.x;
  __shared__ float B[256][8];
  __shared__ float sg[256];
  for (int i = t; i < 256; i += 128) {
    float x = g[(size_t)bg * 256 + i];
    sg[i] = x / (1.f + expf(-x));
    bspline8(x, grid + (size_t)i * 12, B[i]);
  }
  __syncthreads();
  float acc = 0.f;
  for (int i = 0; i < 256; ++i) {
    acc += sg[i] * bw[(size_t)t * 256 + i];
    const float* swp = sw + ((size_t)t * 256 + i) * 8;
    float sp = 0.f;
#pragma unroll
    for (int k = 0; k < 8; ++k) sp += B[i][k] * swp[k];
    acc += sp * sc[(size_t)t * 256 + i];
  }
  z[(size_t)bg * KH + t] = acc;
}

__global__ __launch_bounds__(128) void kan2(
    const float* __restrict__ z, const float* __restrict__ bw,
    const float* __restrict__ sw, const float* __restrict__ sc,
    const float* __restrict__ grid, float* __restrict__ out) {
  int bg = blockIdx.x, t = threadIdx.x;
  __shared__ float B[128][8];
  __shared__ float sz[128];
  float x = z[(size_t)bg * KH + t];
  sz[t] = x / (1.f + expf(-x));
  bspline8(x, grid + (size_t)t * 12, B[t]);
  __syncthreads();
  if (t < NC) {
    float acc = 0.f;
    for (int i = 0; i < 128; ++i) {
      acc += sz[i] * bw[(size_t)t * 128 + i];
      const float* swp = sw + ((size_t)t * 128 + i) * 8;
      float sp = 0.f;
#pragma unroll
      for (int k = 0; k < 8; ++k) sp += B[i][k] * swp[k];
      acc += sp * sc[(size_t)t * 128 + i];
    }
    out[(size_t)bg * NC + t] = acc;
  }
}

extern "C" void kernel_launch(void* const* d_in, const int* in_sizes, int n_in,
                              void* d_out, int out_size, void* d_ws, size_t ws_size,
                              hipStream_t stream) {
  const float* x       = (const float*)d_in[0];
  const float* eattr   = (const float*)d_in[1];
  const int*   idtok   = (const int*)d_in[2];
  const int*   ei      = (const int*)d_in[3];
  const int*   etype   = (const int*)d_in[4];
  const int*   batch   = (const int*)d_in[5];
  const float* idemb   = (const float*)d_in[6];
  const float* inw     = (const float*)d_in[7];
  const float* inb     = (const float*)d_in[8];
  const float* relemb  = (const float*)d_in[9];
  const float* linlw   = (const float*)d_in[10];
  const float* linlb   = (const float*)d_in[11];
  const float* linrw   = (const float*)d_in[12];
  const float* linrb   = (const float*)d_in[13];
  const float* linew   = (const float*)d_in[14];
  const float* attw    = (const float*)d_in[15];
  const float* convb   = (const float*)d_in[16];
  const float* relgate = (const float*)d_in[17];
  const float* n1w     = (const float*)d_in[18];
  const float* n1b     = (const float*)d_in[19];
  const float* n2w     = (const float*)d_in[20];
  const float* n2b     = (const float*)d_in[21];
  const float* f1w     = (const float*)d_in[22];
  const float* f1bias  = (const float*)d_in[23];
  const float* f2w     = (const float*)d_in[24];
  const float* f2bias  = (const float*)d_in[25];
  const float* rnw     = (const float*)d_in[26];
  const float* rnb     = (const float*)d_in[27];
  const float* bw1     = (const float*)d_in[28];
  const float* sw1     = (const float*)d_in[29];
  const float* sc1     = (const float*)d_in[30];
  const float* grid1   = (const float*)d_in[31];
  const float* bw2     = (const float*)d_in[32];
  const float* sw2     = (const float*)d_in[33];
  const float* sc2     = (const float*)d_in[34];
  const float* grid2   = (const float*)d_in[35];
  float* out = (float*)d_out;
  (void)in_sizes; (void)n_in; (void)out_size;

  // ---- pick heads-per-pass: full-head (4) if workspace allows, else head-pair ----
  auto needed = [](int HP) -> size_t {
    auto al = [](size_t b) { return (b + 255) & ~(size_t)255; };
    size_t o = 0;
    o += al((size_t)NN * HID * 4) * 2;
    o += al((size_t)NN * HID * 2);
    o += al((size_t)NN * 128 * HP * 2) * 2;
    o += al((size_t)NE * HP * 4) * 2;
    o += al((size_t)NN * HP * 8);
    o += al((size_t)NE * 4) + al(64);
    o += al((size_t)NL * NR * 512 * 128 * 2) * 2;
    o += al((size_t)NL * 256 * 128 * 2) * 2;
    o += al((size_t)128 * 96 * 2);
    o += al(NR * 4) + al(HID * 4);
    o += al((size_t)(NG + NG * HID * 2) * 4);
    o += al((size_t)NG * 256 * 4) + al((size_t)NG * KH * 4);
    return o;
  };
  const int HP = (needed(4) <= ws_size) ? 4 : 2;
  const int lghp = (HP == 4) ? 2 : 1;
  const int passes = NH / HP;
  const int stride = HP * 128;

  // ---- workspace carve ----
  char* p = (char*)d_ws;
  auto alloc = [&](size_t bytes) { void* q = (void*)p; p += (bytes + 255) & ~(size_t)255; return q; };
  float* h    = (float*)alloc((size_t)NN * HID * 4);
  float* hmsg = (float*)alloc((size_t)NN * HID * 4);
  unsigned short* hbf = (unsigned short*)alloc((size_t)NN * HID * 2);
  unsigned short* xlb = (unsigned short*)alloc((size_t)NN * 128 * HP * 2);
  unsigned short* xrb = (unsigned short*)alloc((size_t)NN * 128 * HP * 2);
  float* logit = (float*)alloc((size_t)NE * HP * 4);
  float* aexp  = (float*)alloc((size_t)NE * HP * 4);
  unsigned* mkey = (unsigned*)alloc((size_t)NN * HP * 8);
  float* den = (float*)(mkey + (size_t)NN * HP);
  int* elist = (int*)alloc((size_t)NE * 4);
  int* ecnt  = (int*)alloc(64);
  int* ecur  = ecnt + 4;
  int* ebase = ecnt + 8;
  unsigned short* linlwb = (unsigned short*)alloc((size_t)NL * NR * 512 * 128 * 2);
  unsigned short* linrwb = (unsigned short*)alloc((size_t)NL * NR * 512 * 128 * 2);
  unsigned short* f1wb   = (unsigned short*)alloc((size_t)NL * 256 * 128 * 2);
  unsigned short* f2wb   = (unsigned short*)alloc((size_t)NL * 128 * 256 * 2);
  unsigned short* inwb   = (unsigned short*)alloc((size_t)128 * 96 * 2);
  float* gate = (float*)alloc(NR * 4);
  float* cb   = (float*)alloc(HID * 4);
  float* rcnt = (float*)alloc((size_t)(NG + NG * HID * 2) * 4);
  float* rsum = rcnt + NG;
  unsigned* rmaxk = (unsigned*)(rsum + (size_t)NG * HID);
  float* g = (float*)alloc((size_t)NG * 256 * 4);
  float* z = (float*)alloc((size_t)NG * KH * 4);
  unsigned short* xinbf = xlb;
  unsigned short* f1buf = xlb;

  const int NB = (NN + 127) / 128;

  // ---- weight conversions ----
  {
    int n;
    n = NL * NR * 512 * 128 / 4;
    cvt_bf16<<<(n + 255) / 256, 256, 0, stream>>>(linlw, linlwb, n);
    cvt_bf16<<<(n + 255) / 256, 256, 0, stream>>>(linrw, linrwb, n);
    n = NL * 256 * 128 / 4;
    cvt_bf16<<<(n + 255) / 256, 256, 0, stream>>>(f1w, f1wb, n);
    cvt_bf16<<<(n + 255) / 256, 256, 0, stream>>>(f2w, f2wb, n);
    n = 128 * 96 / 4;
    cvt_bf16<<<(n + 255) / 256, 256, 0, stream>>>(inw, inwb, n);
  }

  // ---- edge lists ----
  hipMemsetAsync(ecnt, 0, 8 * 4, stream);
  hist_et<<<(NE + 255) / 256, 256, 0, stream>>>(etype, ecnt);
  scan_et<<<1, 64, 0, stream>>>(ecnt, ebase);
  scatter_et<<<(NE + 255) / 256, 256, 0, stream>>>(etype, ebase, ecur, elist);

  // ---- input projection ----
  build_xin_bf<<<(NN * 96 + 255) / 256, 256, 0, stream>>>(x, idtok, idemb, xinbf);
  gemm_bf16<<<dim3(NB, 1), 256, 0, stream>>>(xinbf, inwb, inb, h, nullptr, NN, 96, 128, 1);

  const int logit_blocks = (((NE + 7) / 8) * HP + 3) / 4;
  for (int l = 0; l < NL; ++l) {
    gate_cb<<<1, 128, 0, stream>>>(relgate + l * NR, convb + (size_t)l * NR * HID, gate, cb);
    hipMemsetAsync(hmsg, 0, (size_t)NN * HID * 4, stream);
    cvt_bf16<<<(NN * HID / 4 + 255) / 256, 256, 0, stream>>>(h, hbf, NN * HID / 4);
    for (int r = 0; r < NR; ++r) {
      int lr = l * NR + r;
      for (int hp = 0; hp < passes; ++hp) {
        int hpBase = hp * HP;
        const unsigned short* wl = linlwb + ((size_t)lr * 512 + hpBase * 128) * 128;
        const unsigned short* wr = linrwb + ((size_t)lr * 512 + hpBase * 128) * 128;
        const float* bl = linlb + (size_t)lr * 512 + hpBase * 128;
        const float* br = linrb + (size_t)lr * 512 + hpBase * 128;
        gemm_dual<<<dim3(NB, 2 * HP), 256, 0, stream>>>(hbf, wl, wr, bl, br, xlb, xrb,
                                                        NN, 128, stride, HP);
        hipMemsetAsync(mkey, 0, (size_t)NN * HP * 8, stream);
        edge_logit_g<<<logit_blocks, 256, 0, stream>>>(
            ei, elist, ebase, eattr, relemb + (size_t)lr * RED,
            linew + ((size_t)lr * 512 + hpBase * 128) * 24,
            attw + (size_t)lr * 512 + hpBase * 128,
            xlb, xrb, logit, mkey, r, HP, lghp, stride);
        edge_exp_g<<<(NE * HP + 255) / 256, 256, 0, stream>>>(
            ei, elist, ebase, logit, mkey, aexp, den, r, HP, lghp);
        edge_aggr_g<<<(NE + 1) / 2, 256, 0, stream>>>(
            ei, elist, ebase, aexp, den, xlb, hmsg, gate, r, HP, stride);
      }
    }
    add_ln<<<(NN + 3) / 4, 256, 0, stream>>>(h, hmsg, cb, n1w + l * HID, n1b + l * HID, NN);
    cvt_bf16<<<(NN * HID / 4 + 255) / 256, 256, 0, stream>>>(h, hbf, NN * HID / 4);
    gemm_bf16<<<dim3(NB, 2), 256, 0, stream>>>(hbf, f1wb + (size_t)l * 256 * 128,
                                               f1bias + (size_t)l * 256, nullptr, f1buf,
                                               NN, 128, 256, 1);
    gemm_bf16<<<dim3(NB, 1), 256, 0, stream>>>(f1buf, f2wb + (size_t)l * 128 * 256,
                                               f2bias + (size_t)l * 128, hmsg, nullptr,
                                               NN, 256, 128, 0);
    add_ln<<<(NN + 3) / 4, 256, 0, stream>>>(h, hmsg, nullptr, n2w + l * HID, n2b + l * HID, NN);
  }

  hipMemsetAsync(rcnt, 0, (size_t)(NG + NG * HID * 2) * 4, stream);
  readout_partial<<<NB, 128, 0, stream>>>(h, batch, rcnt, rsum, rmaxk);
  readout_final<<<NG, 256, 0, stream>>>(rcnt, rsum, rmaxk, rnw, rnb, g);
  kan1<<<NG, 128, 0, stream>>>(g, bw1, sw1, sc1, grid1, z);
  kan2<<<NG, 128, 0, stream>>>(z, bw2, sw2, sc2, grid2, out);
}

// Round 7
// 2532.325 us; speedup vs baseline: 4.2743x; 1.1310x over previous
//
#include <hip/hip_runtime.h>
#include <math.h>

#define NN 50000
#define NE 120000
#define FN 64
#define NEA 16
#define NR 4
#define NH 4
#define HID 128
#define NL 3
#define IDE 32
#define RED 8
#define NG 64
#define NC 10
#define KH 128
#define FFH 256
#define NBIN (NR * NN)        // 200000 CSR bins
#define SCAN_BLK ((NBIN + 1023) / 1024)  // 196

typedef short bf16x8 __attribute__((ext_vector_type(8)));
typedef float f32x4 __attribute__((ext_vector_type(4)));

// ---- bf16 helpers (RNE) ----
__device__ __forceinline__ unsigned short f2b(float f) {
  unsigned u = __float_as_uint(f);
  unsigned r = (u + 0x7FFFu + ((u >> 16) & 1u)) >> 16;
  return (unsigned short)r;
}
__device__ __forceinline__ float b2f(unsigned short b) {
  return __uint_as_float((unsigned)b << 16);
}

// ---- monotone float<->uint key for atomic max ----
__device__ __forceinline__ unsigned fkey(float f) {
  unsigned u = __float_as_uint(f);
  return (u & 0x80000000u) ? ~u : (u | 0x80000000u);
}
__device__ __forceinline__ float unkey(unsigned k) {
  unsigned u = (k & 0x80000000u) ? (k ^ 0x80000000u) : ~k;
  return __uint_as_float(u);
}

// ---- f32 -> bf16 bulk convert (n multiple of 4) ----
__global__ void cvt_bf16(const float* __restrict__ s, unsigned short* __restrict__ d, int n4) {
  int i = blockIdx.x * blockDim.x + threadIdx.x;
  if (i >= n4) return;
  float4 v = ((const float4*)s)[i];
  ushort4 o;
  o.x = f2b(v.x); o.y = f2b(v.y); o.z = f2b(v.z); o.w = f2b(v.w);
  ((ushort4*)d)[i] = o;
}

// ---- MFMA bf16 GEMM ----
__global__ __launch_bounds__(256) void gemm_bf16(
    const unsigned short* __restrict__ A, const unsigned short* __restrict__ W,
    const float* __restrict__ bias, float* __restrict__ Cf, unsigned short* __restrict__ Cb,
    int nrows, int K, int mout, int act) {
  __shared__ unsigned short As[128][40];
  __shared__ unsigned short Ws[128][40];
  int t = threadIdx.x;
  int lane = t & 63, w = t >> 6;
  int wm = w >> 1, wn = w & 1;
  int q = lane >> 4, mr = lane & 15;
  int rowBase = blockIdx.x * 128;
  int colBase = blockIdx.y * 128;
  f32x4 acc[4][4] = {};
  for (int k0 = 0; k0 < K; k0 += 32) {
#pragma unroll
    for (int half = 0; half < 2; ++half) {
      int c = t + half * 256;
      int row = c >> 2, c16 = c & 3;
      int gr = rowBase + row;
      bf16x8 av = {0, 0, 0, 0, 0, 0, 0, 0};
      if (gr < nrows) av = *(const bf16x8*)(A + (size_t)gr * K + k0 + c16 * 8);
      *(bf16x8*)&As[row][c16 * 8] = av;
      bf16x8 wv = *(const bf16x8*)(W + (size_t)(colBase + row) * K + k0 + c16 * 8);
      *(bf16x8*)&Ws[row][c16 * 8] = wv;
    }
    __syncthreads();
    bf16x8 af[4], bfr[4];
#pragma unroll
    for (int mt = 0; mt < 4; ++mt) af[mt] = *(const bf16x8*)&As[wm * 64 + mt * 16 + mr][q * 8];
#pragma unroll
    for (int nt = 0; nt < 4; ++nt) bfr[nt] = *(const bf16x8*)&Ws[wn * 64 + nt * 16 + mr][q * 8];
#pragma unroll
    for (int mt = 0; mt < 4; ++mt)
#pragma unroll
      for (int nt = 0; nt < 4; ++nt)
        acc[mt][nt] = __builtin_amdgcn_mfma_f32_16x16x32_bf16(af[mt], bfr[nt], acc[mt][nt], 0, 0, 0);
    __syncthreads();
  }
#pragma unroll
  for (int mt = 0; mt < 4; ++mt)
#pragma unroll
    for (int nt = 0; nt < 4; ++nt)
#pragma unroll
      for (int r = 0; r < 4; ++r) {
        int row = rowBase + wm * 64 + mt * 16 + q * 4 + r;
        int col = colBase + wn * 64 + nt * 16 + mr;
        if (row < nrows) {
          float v = acc[mt][nt][r] + bias[col];
          if (act) v = v / (1.f + expf(-v));
          if (Cb) Cb[(size_t)row * mout + col] = f2b(v);
          else    Cf[(size_t)row * mout + col] = v;
        }
      }
}

// ---- dual-output GEMM ----
__global__ __launch_bounds__(256) void gemm_dual(
    const unsigned short* __restrict__ A,
    const unsigned short* __restrict__ W1, const unsigned short* __restrict__ W2,
    const float* __restrict__ b1, const float* __restrict__ b2,
    unsigned short* __restrict__ C1, unsigned short* __restrict__ C2,
    int nrows, int K, int mout, int HP) {
  int sel = (int)blockIdx.y / HP;
  int cy = (int)blockIdx.y - sel * HP;
  const unsigned short* W = sel ? W2 : W1;
  const float* bias = sel ? b2 : b1;
  unsigned short* Cb = sel ? C2 : C1;
  __shared__ unsigned short As[128][40];
  __shared__ unsigned short Ws[128][40];
  int t = threadIdx.x;
  int lane = t & 63, w = t >> 6;
  int wm = w >> 1, wn = w & 1;
  int q = lane >> 4, mr = lane & 15;
  int rowBase = blockIdx.x * 128;
  int colBase = cy * 128;
  f32x4 acc[4][4] = {};
  for (int k0 = 0; k0 < K; k0 += 32) {
#pragma unroll
    for (int half = 0; half < 2; ++half) {
      int c = t + half * 256;
      int row = c >> 2, c16 = c & 3;
      int gr = rowBase + row;
      bf16x8 av = {0, 0, 0, 0, 0, 0, 0, 0};
      if (gr < nrows) av = *(const bf16x8*)(A + (size_t)gr * K + k0 + c16 * 8);
      *(bf16x8*)&As[row][c16 * 8] = av;
      bf16x8 wv = *(const bf16x8*)(W + (size_t)(colBase + row) * K + k0 + c16 * 8);
      *(bf16x8*)&Ws[row][c16 * 8] = wv;
    }
    __syncthreads();
    bf16x8 af[4], bfr[4];
#pragma unroll
    for (int mt = 0; mt < 4; ++mt) af[mt] = *(const bf16x8*)&As[wm * 64 + mt * 16 + mr][q * 8];
#pragma unroll
    for (int nt = 0; nt < 4; ++nt) bfr[nt] = *(const bf16x8*)&Ws[wn * 64 + nt * 16 + mr][q * 8];
#pragma unroll
    for (int mt = 0; mt < 4; ++mt)
#pragma unroll
      for (int nt = 0; nt < 4; ++nt)
        acc[mt][nt] = __builtin_amdgcn_mfma_f32_16x16x32_bf16(af[mt], bfr[nt], acc[mt][nt], 0, 0, 0);
    __syncthreads();
  }
#pragma unroll
  for (int mt = 0; mt < 4; ++mt)
#pragma unroll
    for (int nt = 0; nt < 4; ++nt)
#pragma unroll
      for (int r = 0; r < 4; ++r) {
        int row = rowBase + wm * 64 + mt * 16 + q * 4 + r;
        int col = colBase + wn * 64 + nt * 16 + mr;
        if (row < nrows) {
          float v = acc[mt][nt][r] + bias[col];
          Cb[(size_t)row * mout + col] = f2b(v);
        }
      }
}

// ---- concat(x, id_emb[tok]) -> bf16 (N,96) ----
__global__ void build_xin_bf(const float* __restrict__ x, const int* __restrict__ idtok,
                             const float* __restrict__ emb, unsigned short* __restrict__ xin) {
  int i = blockIdx.x * blockDim.x + threadIdx.x;
  if (i >= NN * 96) return;
  int n = i / 96, k = i - n * 96;
  float v = (k < FN) ? x[(size_t)n * FN + k] : emb[(size_t)idtok[n] * IDE + (k - FN)];
  xin[i] = f2b(v);
}

// ---- CSR by (rel, dst): bin = rel*NN + dst ----
__global__ void hist_bin(const int* __restrict__ ei, const int* __restrict__ et,
                         int* __restrict__ bcnt) {
  int e = blockIdx.x * blockDim.x + threadIdx.x;
  if (e >= NE) return;
  atomicAdd(&bcnt[et[e] * NN + ei[NE + e]], 1);  // 200k bins -> low contention
}

// exclusive scan of bcnt[NBIN] -> csroff[NBIN]; block-local pass
__global__ __launch_bounds__(256) void scan1(const int* __restrict__ cnt,
                                             int* __restrict__ csroff, int* __restrict__ bsum) {
  __shared__ int lds[256];
  int b = blockIdx.x, t = threadIdx.x;
  int base = b * 1024 + t * 4;
  int v[4];
#pragma unroll
  for (int j = 0; j < 4; ++j) v[j] = (base + j < NBIN) ? cnt[base + j] : 0;
  int tot = v[0] + v[1] + v[2] + v[3];
  lds[t] = tot;
  __syncthreads();
  for (int off = 1; off < 256; off <<= 1) {
    int x = (t >= off) ? lds[t - off] : 0;
    __syncthreads();
    lds[t] += x;
    __syncthreads();
  }
  if (t == 255) bsum[b] = lds[255];
  int run = lds[t] - tot;
#pragma unroll
  for (int j = 0; j < 4; ++j) {
    if (base + j < NBIN) csroff[base + j] = run;
    run += v[j];
  }
}
// exclusive scan of bsum[SCAN_BLK] in one block
__global__ __launch_bounds__(256) void scan2(int* __restrict__ bsum) {
  __shared__ int lds[256];
  int t = threadIdx.x;
  int v = (t < SCAN_BLK) ? bsum[t] : 0;
  lds[t] = v;
  __syncthreads();
  for (int off = 1; off < 256; off <<= 1) {
    int x = (t >= off) ? lds[t - off] : 0;
    __syncthreads();
    lds[t] += x;
    __syncthreads();
  }
  if (t < SCAN_BLK) bsum[t] = lds[t] - v;
}
__global__ void scan3(int* __restrict__ csroff, const int* __restrict__ bsum) {
  int i = blockIdx.x * blockDim.x + threadIdx.x;
  if (i < NBIN) csroff[i] += bsum[i >> 10];
  if (i == 0) csroff[NBIN] = NE;
}
__global__ void scatter_bin(const int* __restrict__ ei, const int* __restrict__ et,
                            const int* __restrict__ csroff, int* __restrict__ cur,
                            int* __restrict__ elist) {
  int e = blockIdx.x * blockDim.x + threadIdx.x;
  if (e >= NE) return;
  int bin = et[e] * NN + ei[NE + e];
  int p = atomicAdd(&cur[bin], 1);
  elist[csroff[bin] + p] = e;
}

// ---- per-layer gate + fused conv_bias ----
__global__ void gate_cb(const float* __restrict__ rg, const float* __restrict__ cbias,
                        float* __restrict__ gate, float* __restrict__ cb) {
  __shared__ float g[NR];
  int t = threadIdx.x;
  if (t == 0) {
    float mx = rg[0];
    for (int r = 1; r < NR; ++r) mx = fmaxf(mx, rg[r]);
    float s = 0.f, tmp[NR];
    for (int r = 0; r < NR; ++r) { tmp[r] = expf(rg[r] - mx); s += tmp[r]; }
    for (int r = 0; r < NR; ++r) { g[r] = tmp[r] / s; gate[r] = g[r]; }
  }
  __syncthreads();
  float c = 0.f;
  for (int r = 0; r < NR; ++r) c += g[r] * cbias[r * HID + t];
  cb[t] = c;
}

// ---- pass A: logits at absolute CSR positions (no atomics) ----
__global__ __launch_bounds__(256) void edge_logit_g(
    const int* __restrict__ ei, const int* __restrict__ elist, const int* __restrict__ csroff,
    const float* __restrict__ eattr, const float* __restrict__ relembp,
    const float* __restrict__ wedgep, const float* __restrict__ attwp,
    const unsigned short* __restrict__ xlb, const unsigned short* __restrict__ xrb,
    float* __restrict__ logit, int rel, int HP, int lghp, int stride) {
  int s = csroff[rel * NN], cnt = csroff[rel * NN + NN] - s;
  int gw = blockIdx.x * 4 + (threadIdx.x >> 6);
  int eg = gw >> lghp, hh = gw & (HP - 1);
  int e0 = eg * 8;
  if (e0 >= cnt) return;
  int lane = threadIdx.x & 63;
  float wreg[2][24], areg[2], rreg[8];
#pragma unroll
  for (int j = 0; j < 2; ++j) {
    int col = hh * 128 + lane + j * 64;
    const float* wp = wedgep + (size_t)col * 24;
#pragma unroll
    for (int k = 0; k < 24; ++k) wreg[j][k] = wp[k];
    areg[j] = attwp[col];
  }
#pragma unroll
  for (int k = 0; k < 8; ++k) rreg[k] = relembp[k];
  for (int i = 0; i < 8; ++i) {
    int li = e0 + i;
    if (li >= cnt) break;
    int e = elist[s + li];
    int src = ei[e], dst = ei[NE + e];
    const float* eap = eattr + (size_t)e * NEA;
    float er[NEA];
#pragma unroll
    for (int k = 0; k < NEA; ++k) er[k] = eap[k];
    float p = 0.f;
#pragma unroll
    for (int j = 0; j < 2; ++j) {
      int col = hh * 128 + lane + j * 64;
      float eev = 0.f;
#pragma unroll
      for (int k = 0; k < NEA; ++k) eev += er[k] * wreg[j][k];
#pragma unroll
      for (int k = 0; k < 8; ++k) eev += rreg[k] * wreg[j][NEA + k];
      float sv = b2f(xlb[(size_t)src * stride + col]) + b2f(xrb[(size_t)dst * stride + col]) + eev;
      sv = (sv > 0.f) ? sv : 0.2f * sv;
      p += sv * areg[j];
    }
#pragma unroll
    for (int o = 32; o > 0; o >>= 1) p += __shfl_xor(p, o, 64);
    if (lane == 0) logit[(size_t)(s + li) * HP + hh] = p;
  }
}

// ---- pass B: fused softmax + aggregate. One wave per dst; no atomics. ----
__global__ __launch_bounds__(256) void edge_smaggr(
    const int* __restrict__ ei, const int* __restrict__ elist, const int* __restrict__ csroff,
    const float* __restrict__ logit, const unsigned short* __restrict__ xlb,
    float* __restrict__ hmsg, const float* __restrict__ gate,
    int rel, int HP, int stride) {
  int dst = blockIdx.x * 4 + (threadIdx.x >> 6);
  if (dst >= NN) return;
  int s = csroff[rel * NN + dst], e_ = csroff[rel * NN + dst + 1];
  if (s >= e_) return;
  int lane = threadIdx.x & 63;
  float m = -3.4e38f, den = 0.f;
  if (lane < HP) {
    for (int p = s; p < e_; ++p) m = fmaxf(m, logit[(size_t)p * HP + lane]);
    for (int p = s; p < e_; ++p) den += expf(logit[(size_t)p * HP + lane] - m);
  }
  float inv = (lane < HP) ? gate[rel] * 0.25f / den : 0.f;  // den>=1 (has edges)
  float acc0 = 0.f, acc1 = 0.f;
  for (int p = s; p < e_; ++p) {
    int src = ei[elist[p]];
    float w = (lane < HP) ? expf(logit[(size_t)p * HP + lane] - m) * inv : 0.f;
    const unsigned short* xp = xlb + (size_t)src * stride;
    for (int h = 0; h < HP; ++h) {
      float wh = __shfl(w, h, 64);
      acc0 += wh * b2f(xp[h * 128 + lane]);
      acc1 += wh * b2f(xp[h * 128 + 64 + lane]);
    }
  }
  hmsg[(size_t)dst * HID + lane] += acc0;
  hmsg[(size_t)dst * HID + 64 + lane] += acc1;
}

// ---- h = layernorm(h + add (+ cb)) ----
__global__ __launch_bounds__(256) void add_ln(
    float* __restrict__ h, const float* __restrict__ add, const float* __restrict__ cb,
    const float* __restrict__ w, const float* __restrict__ b, int nrows) {
  int wave = threadIdx.x >> 6, lane = threadIdx.x & 63;
  int row = blockIdx.x * 4 + wave;
  if (row >= nrows) return;
  size_t base = (size_t)row * HID;
  float x0 = h[base + lane] + add[base + lane];
  float x1 = h[base + 64 + lane] + add[base + 64 + lane];
  if (cb) { x0 += cb[lane]; x1 += cb[64 + lane]; }
  float s = x0 + x1;
#pragma unroll
  for (int o = 32; o > 0; o >>= 1) s += __shfl_xor(s, o, 64);
  float mean = s * (1.f / 128.f);
  float d0 = x0 - mean, d1 = x1 - mean;
  float v = d0 * d0 + d1 * d1;
#pragma unroll
  for (int o = 32; o > 0; o >>= 1) v += __shfl_xor(v, o, 64);
  float inv = 1.f / sqrtf(v * (1.f / 128.f) + 1e-5f);
  h[base + lane] = d0 * inv * w[lane] + b[lane];
  h[base + 64 + lane] = d1 * inv * w[64 + lane] + b[64 + lane];
}

// ---- readout: batch sorted -> register runs, flush on group change ----
__global__ __launch_bounds__(128) void readout_partial(
    const float* __restrict__ h, const int* __restrict__ batch,
    float* __restrict__ cnt, float* __restrict__ sum, unsigned* __restrict__ maxk) {
  int t = threadIdx.x;
  int r0 = blockIdx.x * 128;
  int r1 = min(r0 + 128, NN);
  int curg = batch[r0];
  float acc = 0.f, mx = -3.4e38f;
  int c = 0;
  for (int row = r0; row < r1; ++row) {
    int g = batch[row];
    if (g != curg) {
      atomicAdd(sum + (size_t)curg * HID + t, acc);
      atomicMax(maxk + (size_t)curg * HID + t, fkey(mx));
      if (t == 0) atomicAdd(cnt + curg, (float)c);
      acc = 0.f; mx = -3.4e38f; c = 0; curg = g;
    }
    float v = h[(size_t)row * HID + t];
    acc += v;
    mx = fmaxf(mx, v);
    ++c;
  }
  atomicAdd(sum + (size_t)curg * HID + t, acc);
  atomicMax(maxk + (size_t)curg * HID + t, fkey(mx));
  if (t == 0) atomicAdd(cnt + curg, (float)c);
}

__global__ __launch_bounds__(256) void readout_final(
    const float* __restrict__ cnt, const float* __restrict__ sum,
    const unsigned* __restrict__ maxk, const float* __restrict__ w,
    const float* __restrict__ b, float* __restrict__ g) {
  int bg = blockIdx.x, t = threadIdx.x;
  __shared__ float red[256];
  float c = fmaxf(cnt[bg], 1.f);
  float x = (t < HID) ? sum[(size_t)bg * HID + t] / c
                      : unkey(maxk[(size_t)bg * HID + (t - HID)]);
  red[t] = x;
  __syncthreads();
  for (int s = 128; s > 0; s >>= 1) {
    if (t < s) red[t] += red[t + s];
    __syncthreads();
  }
  float mean = red[0] * (1.f / 256.f);
  __syncthreads();
  float d = x - mean;
  red[t] = d * d;
  __syncthreads();
  for (int s = 128; s > 0; s >>= 1) {
    if (t < s) red[t] += red[t + s];
    __syncthreads();
  }
  float inv = 1.f / sqrtf(red[0] * (1.f / 256.f) + 1e-5f);
  g[(size_t)bg * 256 + t] = d * inv * w[t] + b[t];
}

// ---- B-splines ----
__device__ __forceinline__ void bspline8(float x, const float* __restrict__ t,
                                         float* __restrict__ out) {
  float bs[11];
#pragma unroll
  for (int j = 0; j < 11; ++j) bs[j] = (x >= t[j] && x < t[j + 1]) ? 1.f : 0.f;
#pragma unroll
  for (int k = 1; k <= 3; ++k) {
    for (int j = 0; j < 11 - k; ++j) {
      bs[j] = (x - t[j]) / (t[j + k] - t[j]) * bs[j] +
              (t[j + k + 1] - x) / (t[j + k + 1] - t[j + 1]) * bs[j + 1];
    }
  }
#pragma unroll
  for (int j = 0; j < 8; ++j) out[j] = bs[j];
}

__global__ __launch_bounds__(128) void kan1(
    const float* __restrict__ g, const float* __restrict__ bw,
    const float* __restrict__ sw, const float* __restrict__ sc,
    const float* __restrict__ grid, float* __restrict__ z) {
  int bg = blockIdx.x, t = threadIdx.x;
  __shared__ float B[256][8];
  __shared__ float sg[256];
  for (int i = t; i < 256; i += 128) {
    float x = g[(size_t)bg * 256 + i];
    sg[i] = x / (1.f + expf(-x));
    bspline8(x, grid + (size_t)i * 12, B[i]);
  }
  __syncthreads();
  float acc = 0.f;
  for (int i = 0; i < 256; ++i) {
    acc += sg[i] * bw[(size_t)t * 256 + i];
    const float* swp = sw + ((size_t)t * 256 + i) * 8;
    float sp = 0.f;
#pragma unroll
    for (int k = 0; k < 8; ++k) sp += B[i][k] * swp[k];
    acc += sp * sc[(size_t)t * 256 + i];
  }
  z[(size_t)bg * KH + t] = acc;
}

__global__ __launch_bounds__(128) void kan2(
    const float* __restrict__ z, const float* __restrict__ bw,
    const float* __restrict__ sw, const float* __restrict__ sc,
    const float* __restrict__ grid, float* __restrict__ out) {
  int bg = blockIdx.x, t = threadIdx.x;
  __shared__ float B[128][8];
  __shared__ float sz[128];
  float x = z[(size_t)bg * KH + t];
  sz[t] = x / (1.f + expf(-x));
  bspline8(x, grid + (size_t)t * 12, B[t]);
  __syncthreads();
  if (t < NC) {
    float acc = 0.f;
    for (int i = 0; i < 128; ++i) {
      acc += sz[i] * bw[(size_t)t * 128 + i];
      const float* swp = sw + ((size_t)t * 128 + i) * 8;
      float sp = 0.f;
#pragma unroll
      for (int k = 0; k < 8; ++k) sp += B[i][k] * swp[k];
      acc += sp * sc[(size_t)t * 128 + i];
    }
    out[(size_t)bg * NC + t] = acc;
  }
}

extern "C" void kernel_launch(void* const* d_in, const int* in_sizes, int n_in,
                              void* d_out, int out_size, void* d_ws, size_t ws_size,
                              hipStream_t stream) {
  const float* x       = (const float*)d_in[0];
  const float* eattr   = (const float*)d_in[1];
  const int*   idtok   = (const int*)d_in[2];
  const int*   ei      = (const int*)d_in[3];
  const int*   etype   = (const int*)d_in[4];
  const int*   batch   = (const int*)d_in[5];
  const float* idemb   = (const float*)d_in[6];
  const float* inw     = (const float*)d_in[7];
  const float* inb     = (const float*)d_in[8];
  const float* relemb  = (const float*)d_in[9];
  const float* linlw   = (const float*)d_in[10];
  const float* linlb   = (const float*)d_in[11];
  const float* linrw   = (const float*)d_in[12];
  const float* linrb   = (const float*)d_in[13];
  const float* linew   = (const float*)d_in[14];
  const float* attw    = (const float*)d_in[15];
  const float* convb   = (const float*)d_in[16];
  const float* relgate = (const float*)d_in[17];
  const float* n1w     = (const float*)d_in[18];
  const float* n1b     = (const float*)d_in[19];
  const float* n2w     = (const float*)d_in[20];
  const float* n2b     = (const float*)d_in[21];
  const float* f1w     = (const float*)d_in[22];
  const float* f1bias  = (const float*)d_in[23];
  const float* f2w     = (const float*)d_in[24];
  const float* f2bias  = (const float*)d_in[25];
  const float* rnw     = (const float*)d_in[26];
  const float* rnb     = (const float*)d_in[27];
  const float* bw1     = (const float*)d_in[28];
  const float* sw1     = (const float*)d_in[29];
  const float* sc1     = (const float*)d_in[30];
  const float* grid1   = (const float*)d_in[31];
  const float* bw2     = (const float*)d_in[32];
  const float* sw2     = (const float*)d_in[33];
  const float* sc2     = (const float*)d_in[34];
  const float* grid2   = (const float*)d_in[35];
  float* out = (float*)d_out;
  (void)in_sizes; (void)n_in; (void)out_size;

  // ---- pick heads-per-pass ----
  auto needed = [](int HP) -> size_t {
    auto al = [](size_t b) { return (b + 255) & ~(size_t)255; };
    size_t o = 0;
    o += al((size_t)NN * HID * 4) * 2;            // h, hmsg
    o += al((size_t)NN * HID * 2);                // hbf
    o += al((size_t)NN * 128 * HP * 2) * 2;       // xlb, xrb
    o += al((size_t)NE * HP * 4);                 // logit
    o += al((size_t)NE * 4);                      // elist
    o += al((size_t)NBIN * 8 + 8);                // bcnt+cur
    o += al((size_t)(NBIN + 1) * 4);              // csroff
    o += al((size_t)SCAN_BLK * 4);                // bsum
    o += al((size_t)NL * NR * 512 * 128 * 2) * 2; // linlwb, linrwb
    o += al((size_t)NL * 256 * 128 * 2) * 2;      // f1wb, f2wb
    o += al((size_t)128 * 96 * 2);                // inwb
    o += al(NR * 4) + al(HID * 4);
    o += al((size_t)(NG + NG * HID * 2) * 4);
    o += al((size_t)NG * 256 * 4) + al((size_t)NG * KH * 4);
    return o;
  };
  const int HP = (needed(4) <= ws_size) ? 4 : 2;
  const int lghp = (HP == 4) ? 2 : 1;
  const int passes = NH / HP;
  const int stride = HP * 128;

  // ---- workspace carve ----
  char* p = (char*)d_ws;
  auto alloc = [&](size_t bytes) { void* q = (void*)p; p += (bytes + 255) & ~(size_t)255; return q; };
  float* h    = (float*)alloc((size_t)NN * HID * 4);
  float* hmsg = (float*)alloc((size_t)NN * HID * 4);
  unsigned short* hbf = (unsigned short*)alloc((size_t)NN * HID * 2);
  unsigned short* xlb = (unsigned short*)alloc((size_t)NN * 128 * HP * 2);
  unsigned short* xrb = (unsigned short*)alloc((size_t)NN * 128 * HP * 2);
  float* logit = (float*)alloc((size_t)NE * HP * 4);
  int* elist = (int*)alloc((size_t)NE * 4);
  int* bcnt  = (int*)alloc((size_t)NBIN * 8 + 8);   // bcnt[NBIN] + cur[NBIN]
  int* cur   = bcnt + NBIN;
  int* csroff = (int*)alloc((size_t)(NBIN + 1) * 4);
  int* bsum  = (int*)alloc((size_t)SCAN_BLK * 4);
  unsigned short* linlwb = (unsigned short*)alloc((size_t)NL * NR * 512 * 128 * 2);
  unsigned short* linrwb = (unsigned short*)alloc((size_t)NL * NR * 512 * 128 * 2);
  unsigned short* f1wb   = (unsigned short*)alloc((size_t)NL * 256 * 128 * 2);
  unsigned short* f2wb   = (unsigned short*)alloc((size_t)NL * 128 * 256 * 2);
  unsigned short* inwb   = (unsigned short*)alloc((size_t)128 * 96 * 2);
  float* gate = (float*)alloc(NR * 4);
  float* cb   = (float*)alloc(HID * 4);
  float* rcnt = (float*)alloc((size_t)(NG + NG * HID * 2) * 4);
  float* rsum = rcnt + NG;
  unsigned* rmaxk = (unsigned*)(rsum + (size_t)NG * HID);
  float* g = (float*)alloc((size_t)NG * 256 * 4);
  float* z = (float*)alloc((size_t)NG * KH * 4);
  unsigned short* xinbf = xlb;
  unsigned short* f1buf = xlb;

  const int NB = (NN + 127) / 128;

  // ---- weight conversions ----
  {
    int n;
    n = NL * NR * 512 * 128 / 4;
    cvt_bf16<<<(n + 255) / 256, 256, 0, stream>>>(linlw, linlwb, n);
    cvt_bf16<<<(n + 255) / 256, 256, 0, stream>>>(linrw, linrwb, n);
    n = NL * 256 * 128 / 4;
    cvt_bf16<<<(n + 255) / 256, 256, 0, stream>>>(f1w, f1wb, n);
    cvt_bf16<<<(n + 255) / 256, 256, 0, stream>>>(f2w, f2wb, n);
    n = 128 * 96 / 4;
    cvt_bf16<<<(n + 255) / 256, 256, 0, stream>>>(inw, inwb, n);
  }

  // ---- CSR build: (rel,dst) bins ----
  hipMemsetAsync(bcnt, 0, (size_t)NBIN * 8 + 8, stream);  // bcnt + cur
  hist_bin<<<(NE + 255) / 256, 256, 0, stream>>>(ei, etype, bcnt);
  scan1<<<SCAN_BLK, 256, 0, stream>>>(bcnt, csroff, bsum);
  scan2<<<1, 256, 0, stream>>>(bsum);
  scan3<<<(NBIN + 256) / 256, 256, 0, stream>>>(csroff, bsum);
  scatter_bin<<<(NE + 255) / 256, 256, 0, stream>>>(ei, etype, csroff, cur, elist);

  // ---- input projection ----
  build_xin_bf<<<(NN * 96 + 255) / 256, 256, 0, stream>>>(x, idtok, idemb, xinbf);
  gemm_bf16<<<dim3(NB, 1), 256, 0, stream>>>(xinbf, inwb, inb, h, nullptr, NN, 96, 128, 1);

  const int logit_blocks = (((NE + 7) / 8) * HP + 3) / 4;
  for (int l = 0; l < NL; ++l) {
    gate_cb<<<1, 128, 0, stream>>>(relgate + l * NR, convb + (size_t)l * NR * HID, gate, cb);
    hipMemsetAsync(hmsg, 0, (size_t)NN * HID * 4, stream);
    cvt_bf16<<<(NN * HID / 4 + 255) / 256, 256, 0, stream>>>(h, hbf, NN * HID / 4);
    for (int r = 0; r < NR; ++r) {
      int lr = l * NR + r;
      for (int hp = 0; hp < passes; ++hp) {
        int hpBase = hp * HP;
        const unsigned short* wl = linlwb + ((size_t)lr * 512 + hpBase * 128) * 128;
        const unsigned short* wr = linrwb + ((size_t)lr * 512 + hpBase * 128) * 128;
        const float* bl = linlb + (size_t)lr * 512 + hpBase * 128;
        const float* br = linrb + (size_t)lr * 512 + hpBase * 128;
        gemm_dual<<<dim3(NB, 2 * HP), 256, 0, stream>>>(hbf, wl, wr, bl, br, xlb, xrb,
                                                        NN, 128, stride, HP);
        edge_logit_g<<<logit_blocks, 256, 0, stream>>>(
            ei, elist, csroff, eattr, relemb + (size_t)lr * RED,
            linew + ((size_t)lr * 512 + hpBase * 128) * 24,
            attw + (size_t)lr * 512 + hpBase * 128,
            xlb, xrb, logit, r, HP, lghp, stride);
        edge_smaggr<<<(NN + 3) / 4, 256, 0, stream>>>(
            ei, elist, csroff, logit, xlb, hmsg, gate, r, HP, stride);
      }
    }
    add_ln<<<(NN + 3) / 4, 256, 0, stream>>>(h, hmsg, cb, n1w + l * HID, n1b + l * HID, NN);
    cvt_bf16<<<(NN * HID / 4 + 255) / 256, 256, 0, stream>>>(h, hbf, NN * HID / 4);
    gemm_bf16<<<dim3(NB, 2), 256, 0, stream>>>(hbf, f1wb + (size_t)l * 256 * 128,
                                               f1bias + (size_t)l * 256, nullptr, f1buf,
                                               NN, 128, 256, 1);
    gemm_bf16<<<dim3(NB, 1), 256, 0, stream>>>(f1buf, f2wb + (size_t)l * 128 * 256,
                                               f2bias + (size_t)l * 128, hmsg, nullptr,
                                               NN, 256, 128, 0);
    add_ln<<<(NN + 3) / 4, 256, 0, stream>>>(h, hmsg, nullptr, n2w + l * HID, n2b + l * HID, NN);
  }

  hipMemsetAsync(rcnt, 0, (size_t)(NG + NG * HID * 2) * 4, stream);
  readout_partial<<<NB, 128, 0, stream>>>(h, batch, rcnt, rsum, rmaxk);
  readout_final<<<NG, 256, 0, stream>>>(rcnt, rsum, rmaxk, rnw, rnb, g);
  kan1<<<NG, 128, 0, stream>>>(g, bw1, sw1, sc1, grid1, z);
  kan2<<<NG, 128, 0, stream>>>(z, bw2, sw2, sc2, grid2, out);
}

// Round 8
// 2414.263 us; speedup vs baseline: 4.4834x; 1.0489x over previous
//
#include <hip/hip_runtime.h>
#include <math.h>

#define NN 50000
#define NE 120000
#define FN 64
#define NEA 16
#define NR 4
#define NH 4
#define HID 128
#define NL 3
#define IDE 32
#define RED 8
#define NG 64
#define NC 10
#define KH 128
#define FFH 256
#define NBIN (NR * NN)
#define SCAN_BLK ((NBIN + 1023) / 1024)

typedef short bf16x8 __attribute__((ext_vector_type(8)));
typedef float f32x4 __attribute__((ext_vector_type(4)));

__device__ __forceinline__ unsigned short f2b(float f) {
  unsigned u = __float_as_uint(f);
  unsigned r = (u + 0x7FFFu + ((u >> 16) & 1u)) >> 16;
  return (unsigned short)r;
}
__device__ __forceinline__ float b2f(unsigned short b) {
  return __uint_as_float((unsigned)b << 16);
}
__device__ __forceinline__ unsigned fkey(float f) {
  unsigned u = __float_as_uint(f);
  return (u & 0x80000000u) ? ~u : (u | 0x80000000u);
}
__device__ __forceinline__ float unkey(unsigned k) {
  unsigned u = (k & 0x80000000u) ? (k ^ 0x80000000u) : ~k;
  return __uint_as_float(u);
}

__global__ void cvt_bf16(const float* __restrict__ s, unsigned short* __restrict__ d, int n4) {
  int i = blockIdx.x * blockDim.x + threadIdx.x;
  if (i >= n4) return;
  float4 v = ((const float4*)s)[i];
  ushort4 o;
  o.x = f2b(v.x); o.y = f2b(v.y); o.z = f2b(v.z); o.w = f2b(v.w);
  ((ushort4*)d)[i] = o;
}

// ---- GEMM core: 128x128 tile, row-panel-major 1D grid, LDS-staged bf16 epilogue ----
// smem layout: K-loop: As[128][40] @0, Ws[128][40] @10240; epilogue: Es[64][136] @0.
__device__ __forceinline__ void gemm_core(
    char* smem, const unsigned short* __restrict__ A, const unsigned short* __restrict__ W,
    const float* __restrict__ bias, float* __restrict__ Cf, unsigned short* __restrict__ Cb,
    int nrows, int K, int mout, int act, int rowBase, int colBase) {
  unsigned short (*As)[40] = (unsigned short (*)[40])smem;
  unsigned short (*Ws)[40] = (unsigned short (*)[40])(smem + 10240);
  int t = threadIdx.x;
  int lane = t & 63, w = t >> 6;
  int wm = w >> 1, wn = w & 1;
  int q = lane >> 4, mr = lane & 15;
  f32x4 acc[4][4] = {};
  for (int k0 = 0; k0 < K; k0 += 32) {
#pragma unroll
    for (int half = 0; half < 2; ++half) {
      int c = t + half * 256;
      int row = c >> 2, c16 = c & 3;
      int gr = rowBase + row;
      bf16x8 av = {0, 0, 0, 0, 0, 0, 0, 0};
      if (gr < nrows) av = *(const bf16x8*)(A + (size_t)gr * K + k0 + c16 * 8);
      *(bf16x8*)&As[row][c16 * 8] = av;
      bf16x8 wv = *(const bf16x8*)(W + (size_t)(colBase + row) * K + k0 + c16 * 8);
      *(bf16x8*)&Ws[row][c16 * 8] = wv;
    }
    __syncthreads();
    bf16x8 af[4], bfr[4];
#pragma unroll
    for (int mt = 0; mt < 4; ++mt) af[mt] = *(const bf16x8*)&As[wm * 64 + mt * 16 + mr][q * 8];
#pragma unroll
    for (int nt = 0; nt < 4; ++nt) bfr[nt] = *(const bf16x8*)&Ws[wn * 64 + nt * 16 + mr][q * 8];
#pragma unroll
    for (int mt = 0; mt < 4; ++mt)
#pragma unroll
      for (int nt = 0; nt < 4; ++nt)
        acc[mt][nt] = __builtin_amdgcn_mfma_f32_16x16x32_bf16(af[mt], bfr[nt], acc[mt][nt], 0, 0, 0);
    __syncthreads();
  }
  if (Cb) {
    // LDS-staged epilogue: two 64-row phases; coalesced dwordx4 stores
    unsigned short (*Es)[136] = (unsigned short (*)[136])smem;
#pragma unroll
    for (int ph = 0; ph < 2; ++ph) {
      if (wm == ph) {
#pragma unroll
        for (int mt = 0; mt < 4; ++mt)
#pragma unroll
          for (int nt = 0; nt < 4; ++nt)
#pragma unroll
            for (int r = 0; r < 4; ++r) {
              float v = acc[mt][nt][r] + bias[colBase + wn * 64 + nt * 16 + mr];
              if (act) v = v / (1.f + expf(-v));
              Es[mt * 16 + q * 4 + r][wn * 64 + nt * 16 + mr] = f2b(v);
            }
      }
      __syncthreads();
      int rl = t >> 2, co = (t & 3) * 32;
      int grow = rowBase + ph * 64 + rl;
      if (grow < nrows) {
        unsigned short* dst = Cb + (size_t)grow * mout + colBase + co;
#pragma unroll
        for (int j = 0; j < 4; ++j)
          *(bf16x8*)(dst + j * 8) = *(const bf16x8*)&Es[rl][co + j * 8];
      }
      __syncthreads();
    }
  } else {
#pragma unroll
    for (int mt = 0; mt < 4; ++mt)
#pragma unroll
      for (int nt = 0; nt < 4; ++nt)
#pragma unroll
        for (int r = 0; r < 4; ++r) {
          int row = rowBase + wm * 64 + mt * 16 + q * 4 + r;
          int col = colBase + wn * 64 + nt * 16 + mr;
          if (row < nrows) {
            float v = acc[mt][nt][r] + bias[col];
            if (act) v = v / (1.f + expf(-v));
            Cf[(size_t)row * mout + col] = v;
          }
        }
  }
}

__global__ __launch_bounds__(256) void gemm_bf16(
    const unsigned short* __restrict__ A, const unsigned short* __restrict__ W,
    const float* __restrict__ bias, float* __restrict__ Cf, unsigned short* __restrict__ Cb,
    int nrows, int K, int mout, int act, int ncol) {
  __shared__ char smem[20480];
  int bid = blockIdx.x;
  int rowT = bid / ncol, cy = bid - rowT * ncol;
  gemm_core(smem, A, W, bias, Cf, Cb, nrows, K, mout, act, rowT * 128, cy * 128);
}

__global__ __launch_bounds__(256) void gemm_dual(
    const unsigned short* __restrict__ A,
    const unsigned short* __restrict__ W1, const unsigned short* __restrict__ W2,
    const float* __restrict__ b1, const float* __restrict__ b2,
    unsigned short* __restrict__ C1, unsigned short* __restrict__ C2,
    int nrows, int K, int mout, int HP) {
  __shared__ char smem[20480];
  int bid = blockIdx.x;
  int rowT = bid / (2 * HP), rem = bid - rowT * 2 * HP;
  int sel = rem / HP, cy = rem - sel * HP;
  gemm_core(smem, A, sel ? W2 : W1, sel ? b2 : b1, nullptr, sel ? C2 : C1,
            nrows, K, mout, 0, rowT * 128, cy * 128);
}

__global__ void build_xin_bf(const float* __restrict__ x, const int* __restrict__ idtok,
                             const float* __restrict__ emb, unsigned short* __restrict__ xin) {
  int i = blockIdx.x * blockDim.x + threadIdx.x;
  if (i >= NN * 96) return;
  int n = i / 96, k = i - n * 96;
  float v = (k < FN) ? x[(size_t)n * FN + k] : emb[(size_t)idtok[n] * IDE + (k - FN)];
  xin[i] = f2b(v);
}

// ---- CSR by (rel, dst) ----
__global__ void hist_bin(const int* __restrict__ ei, const int* __restrict__ et,
                         int* __restrict__ bcnt) {
  int e = blockIdx.x * blockDim.x + threadIdx.x;
  if (e >= NE) return;
  atomicAdd(&bcnt[et[e] * NN + ei[NE + e]], 1);
}
__global__ __launch_bounds__(256) void scan1(const int* __restrict__ cnt,
                                             int* __restrict__ csroff, int* __restrict__ bsum) {
  __shared__ int lds[256];
  int b = blockIdx.x, t = threadIdx.x;
  int base = b * 1024 + t * 4;
  int v[4];
#pragma unroll
  for (int j = 0; j < 4; ++j) v[j] = (base + j < NBIN) ? cnt[base + j] : 0;
  int tot = v[0] + v[1] + v[2] + v[3];
  lds[t] = tot;
  __syncthreads();
  for (int off = 1; off < 256; off <<= 1) {
    int x = (t >= off) ? lds[t - off] : 0;
    __syncthreads();
    lds[t] += x;
    __syncthreads();
  }
  if (t == 255) bsum[b] = lds[255];
  int run = lds[t] - tot;
#pragma unroll
  for (int j = 0; j < 4; ++j) {
    if (base + j < NBIN) csroff[base + j] = run;
    run += v[j];
  }
}
__global__ __launch_bounds__(256) void scan2(int* __restrict__ bsum) {
  __shared__ int lds[256];
  int t = threadIdx.x;
  int v = (t < SCAN_BLK) ? bsum[t] : 0;
  lds[t] = v;
  __syncthreads();
  for (int off = 1; off < 256; off <<= 1) {
    int x = (t >= off) ? lds[t - off] : 0;
    __syncthreads();
    lds[t] += x;
    __syncthreads();
  }
  if (t < SCAN_BLK) bsum[t] = lds[t] - v;
}
__global__ void scan3(int* __restrict__ csroff, const int* __restrict__ bsum) {
  int i = blockIdx.x * blockDim.x + threadIdx.x;
  if (i < NBIN) csroff[i] += bsum[i >> 10];
  if (i == 0) csroff[NBIN] = NE;
}
__global__ void scatter_bin(const int* __restrict__ ei, const int* __restrict__ et,
                            const int* __restrict__ csroff, int* __restrict__ cur,
                            int* __restrict__ elist) {
  int e = blockIdx.x * blockDim.x + threadIdx.x;
  if (e >= NE) return;
  int bin = et[e] * NN + ei[NE + e];
  int p = atomicAdd(&cur[bin], 1);
  elist[csroff[bin] + p] = e;
}

__global__ void gate_cb(const float* __restrict__ rg, const float* __restrict__ cbias,
                        float* __restrict__ gate, float* __restrict__ cb) {
  __shared__ float g[NR];
  int t = threadIdx.x;
  if (t == 0) {
    float mx = rg[0];
    for (int r = 1; r < NR; ++r) mx = fmaxf(mx, rg[r]);
    float s = 0.f, tmp[NR];
    for (int r = 0; r < NR; ++r) { tmp[r] = expf(rg[r] - mx); s += tmp[r]; }
    for (int r = 0; r < NR; ++r) { g[r] = tmp[r] / s; gate[r] = g[r]; }
  }
  __syncthreads();
  float c = 0.f;
  for (int r = 0; r < NR; ++r) c += g[r] * cbias[r * HID + t];
  cb[t] = c;
}

// ---- pass A: one wave per (edge-group, head); 16 edges/wave ----
__global__ __launch_bounds__(256) void edge_logit_g(
    const int* __restrict__ ei, const int* __restrict__ elist, const int* __restrict__ csroff,
    const float* __restrict__ eattr, const float* __restrict__ relembp,
    const float* __restrict__ wedgep, const float* __restrict__ attwp,
    const unsigned short* __restrict__ xlb, const unsigned short* __restrict__ xrb,
    float* __restrict__ logit, int rel, int HP, int lghp, int stride) {
  int s = csroff[rel * NN], cnt = csroff[rel * NN + NN] - s;
  int gw = blockIdx.x * 4 + (threadIdx.x >> 6);
  int eg = gw >> lghp, hh = gw & (HP - 1);
  int e0 = eg * 16;
  if (e0 >= cnt) return;
  int lane = threadIdx.x & 63;
  float wreg[2][24], areg[2], rreg[8];
#pragma unroll
  for (int j = 0; j < 2; ++j) {
    int col = hh * 128 + lane + j * 64;
    const float* wp = wedgep + (size_t)col * 24;
#pragma unroll
    for (int k = 0; k < 24; ++k) wreg[j][k] = wp[k];
    areg[j] = attwp[col];
  }
#pragma unroll
  for (int k = 0; k < 8; ++k) rreg[k] = relembp[k];
  for (int i = 0; i < 16; ++i) {
    int li = e0 + i;
    if (li >= cnt) break;
    int e = elist[s + li];
    int src = ei[e], dst = ei[NE + e];
    const float* eap = eattr + (size_t)e * NEA;
    float er[NEA];
#pragma unroll
    for (int k = 0; k < NEA; ++k) er[k] = eap[k];
    float p = 0.f;
#pragma unroll
    for (int j = 0; j < 2; ++j) {
      int col = hh * 128 + lane + j * 64;
      float eev = 0.f;
#pragma unroll
      for (int k = 0; k < NEA; ++k) eev += er[k] * wreg[j][k];
#pragma unroll
      for (int k = 0; k < 8; ++k) eev += rreg[k] * wreg[j][NEA + k];
      float sv = b2f(xlb[(size_t)src * stride + col]) + b2f(xrb[(size_t)dst * stride + col]) + eev;
      sv = (sv > 0.f) ? sv : 0.2f * sv;
      p += sv * areg[j];
    }
#pragma unroll
    for (int o = 32; o > 0; o >>= 1) p += __shfl_xor(p, o, 64);
    if (lane == 0) logit[(size_t)(s + li) * HP + hh] = p;
  }
}

// ---- pass B: fused softmax + aggregate, one wave per dst ----
__global__ __launch_bounds__(256) void edge_smaggr(
    const int* __restrict__ ei, const int* __restrict__ elist, const int* __restrict__ csroff,
    const float* __restrict__ logit, const unsigned short* __restrict__ xlb,
    float* __restrict__ hmsg, const float* __restrict__ gate,
    int rel, int HP, int stride) {
  int dst = blockIdx.x * 4 + (threadIdx.x >> 6);
  if (dst >= NN) return;
  int s = csroff[rel * NN + dst], e_ = csroff[rel * NN + dst + 1];
  if (s >= e_) return;
  int lane = threadIdx.x & 63;
  float m = -3.4e38f, den = 0.f;
  if (lane < HP) {
    for (int p = s; p < e_; ++p) m = fmaxf(m, logit[(size_t)p * HP + lane]);
    for (int p = s; p < e_; ++p) den += expf(logit[(size_t)p * HP + lane] - m);
  }
  float inv = (lane < HP) ? gate[rel] * 0.25f / den : 0.f;
  float acc0 = 0.f, acc1 = 0.f;
  for (int p = s; p < e_; ++p) {
    int src = ei[elist[p]];
    float w = (lane < HP) ? expf(logit[(size_t)p * HP + lane] - m) * inv : 0.f;
    const unsigned short* xp = xlb + (size_t)src * stride;
    for (int h = 0; h < HP; ++h) {
      float wh = __shfl(w, h, 64);
      acc0 += wh * b2f(xp[h * 128 + lane]);
      acc1 += wh * b2f(xp[h * 128 + 64 + lane]);
    }
  }
  hmsg[(size_t)dst * HID + lane] += acc0;
  hmsg[(size_t)dst * HID + 64 + lane] += acc1;
}

// ---- h = layernorm(h + add (+ cb)); also emits bf16 copy ----
__global__ __launch_bounds__(256) void add_ln(
    float* __restrict__ h, const float* __restrict__ add, const float* __restrict__ cb,
    const float* __restrict__ w, const float* __restrict__ b,
    unsigned short* __restrict__ hbf, int nrows) {
  int wave = threadIdx.x >> 6, lane = threadIdx.x & 63;
  int row = blockIdx.x * 4 + wave;
  if (row >= nrows) return;
  size_t base = (size_t)row * HID;
  float x0 = h[base + lane] + add[base + lane];
  float x1 = h[base + 64 + lane] + add[base + 64 + lane];
  if (cb) { x0 += cb[lane]; x1 += cb[64 + lane]; }
  float s = x0 + x1;
#pragma unroll
  for (int o = 32; o > 0; o >>= 1) s += __shfl_xor(s, o, 64);
  float mean = s * (1.f / 128.f);
  float d0 = x0 - mean, d1 = x1 - mean;
  float v = d0 * d0 + d1 * d1;
#pragma unroll
  for (int o = 32; o > 0; o >>= 1) v += __shfl_xor(v, o, 64);
  float inv = 1.f / sqrtf(v * (1.f / 128.f) + 1e-5f);
  float y0 = d0 * inv * w[lane] + b[lane];
  float y1 = d1 * inv * w[64 + lane] + b[64 + lane];
  h[base + lane] = y0;
  h[base + 64 + lane] = y1;
  hbf[base + lane] = f2b(y0);
  hbf[base + 64 + lane] = f2b(y1);
}

// ---- readout ----
__global__ __launch_bounds__(128) void readout_partial(
    const float* __restrict__ h, const int* __restrict__ batch,
    float* __restrict__ cnt, float* __restrict__ sum, unsigned* __restrict__ maxk) {
  int t = threadIdx.x;
  int r0 = blockIdx.x * 128;
  int r1 = min(r0 + 128, NN);
  int curg = batch[r0];
  float acc = 0.f, mx = -3.4e38f;
  int c = 0;
  for (int row = r0; row < r1; ++row) {
    int g = batch[row];
    if (g != curg) {
      atomicAdd(sum + (size_t)curg * HID + t, acc);
      atomicMax(maxk + (size_t)curg * HID + t, fkey(mx));
      if (t == 0) atomicAdd(cnt + curg, (float)c);
      acc = 0.f; mx = -3.4e38f; c = 0; curg = g;
    }
    float v = h[(size_t)row * HID + t];
    acc += v;
    mx = fmaxf(mx, v);
    ++c;
  }
  atomicAdd(sum + (size_t)curg * HID + t, acc);
  atomicMax(maxk + (size_t)curg * HID + t, fkey(mx));
  if (t == 0) atomicAdd(cnt + curg, (float)c);
}

__global__ __launch_bounds__(256) void readout_final(
    const float* __restrict__ cnt, const float* __restrict__ sum,
    const unsigned* __restrict__ maxk, const float* __restrict__ w,
    const float* __restrict__ b, float* __restrict__ g) {
  int bg = blockIdx.x, t = threadIdx.x;
  __shared__ float red[256];
  float c = fmaxf(cnt[bg], 1.f);
  float x = (t < HID) ? sum[(size_t)bg * HID + t] / c
                      : unkey(maxk[(size_t)bg * HID + (t - HID)]);
  red[t] = x;
  __syncthreads();
  for (int s = 128; s > 0; s >>= 1) {
    if (t < s) red[t] += red[t + s];
    __syncthreads();
  }
  float mean = red[0] * (1.f / 256.f);
  __syncthreads();
  float d = x - mean;
  red[t] = d * d;
  __syncthreads();
  for (int s = 128; s > 0; s >>= 1) {
    if (t < s) red[t] += red[t + s];
    __syncthreads();
  }
  float inv = 1.f / sqrtf(red[0] * (1.f / 256.f) + 1e-5f);
  g[(size_t)bg * 256 + t] = d * inv * w[t] + b[t];
}

__device__ __forceinline__ void bspline8(float x, const float* __restrict__ t,
                                         float* __restrict__ out) {
  float bs[11];
#pragma unroll
  for (int j = 0; j < 11; ++j) bs[j] = (x >= t[j] && x < t[j + 1]) ? 1.f : 0.f;
#pragma unroll
  for (int k = 1; k <= 3; ++k) {
    for (int j = 0; j < 11 - k; ++j) {
      bs[j] = (x - t[j]) / (t[j + k] - t[j]) * bs[j] +
              (t[j + k + 1] - x) / (t[j + k + 1] - t[j + 1]) * bs[j + 1];
    }
  }
#pragma unroll
  for (int j = 0; j < 8; ++j) out[j] = bs[j];
}

__global__ __launch_bounds__(128) void kan1(
    const float* __restrict__ g, const float* __restrict__ bw,
    const float* __restrict__ sw, const float* __restrict__ sc,
    const float* __restrict__ grid, float* __restrict__ z) {
  int bg = blockIdx.x, t = threadIdx.x;
  __shared__ float B[256][8];
  __shared__ float sg[256];
  for (int i = t; i < 256; i += 128) {
    float x = g[(size_t)bg * 256 + i];
    sg[i] = x / (1.f + expf(-x));
    bspline8(x, grid + (size_t)i * 12, B[i]);
  }
  __syncthreads();
  float acc = 0.f;
  for (int i = 0; i < 256; ++i) {
    acc += sg[i] * bw[(size_t)t * 256 + i];
    const float* swp = sw + ((size_t)t * 256 + i) * 8;
    float sp = 0.f;
#pragma unroll
    for (int k = 0; k < 8; ++k) sp += B[i][k] * swp[k];
    acc += sp * sc[(size_t)t * 256 + i];
  }
  z[(size_t)bg * KH + t] = acc;
}

__global__ __launch_bounds__(128) void kan2(
    const float* __restrict__ z, const float* __restrict__ bw,
    const float* __restrict__ sw, const float* __restrict__ sc,
    const float* __restrict__ grid, float* __restrict__ out) {
  int bg = blockIdx.x, t = threadIdx.x;
  __shared__ float B[128][8];
  __shared__ float sz[128];
  float x = z[(size_t)bg * KH + t];
  sz[t] = x / (1.f + expf(-x));
  bspline8(x, grid + (size_t)t * 12, B[t]);
  __syncthreads();
  if (t < NC) {
    float acc = 0.f;
    for (int i = 0; i < 128; ++i) {
      acc += sz[i] * bw[(size_t)t * 128 + i];
      const float* swp = sw + ((size_t)t * 128 + i) * 8;
      float sp = 0.f;
#pragma unroll
      for (int k = 0; k < 8; ++k) sp += B[i][k] * swp[k];
      acc += sp * sc[(size_t)t * 128 + i];
    }
    out[(size_t)bg * NC + t] = acc;
  }
}

extern "C" void kernel_launch(void* const* d_in, const int* in_sizes, int n_in,
                              void* d_out, int out_size, void* d_ws, size_t ws_size,
                              hipStream_t stream) {
  const float* x       = (const float*)d_in[0];
  const float* eattr   = (const float*)d_in[1];
  const int*   idtok   = (const int*)d_in[2];
  const int*   ei      = (const int*)d_in[3];
  const int*   etype   = (const int*)d_in[4];
  const int*   batch   = (const int*)d_in[5];
  const float* idemb   = (const float*)d_in[6];
  const float* inw     = (const float*)d_in[7];
  const float* inb     = (const float*)d_in[8];
  const float* relemb  = (const float*)d_in[9];
  const float* linlw   = (const float*)d_in[10];
  const float* linlb   = (const float*)d_in[11];
  const float* linrw   = (const float*)d_in[12];
  const float* linrb   = (const float*)d_in[13];
  const float* linew   = (const float*)d_in[14];
  const float* attw    = (const float*)d_in[15];
  const float* convb   = (const float*)d_in[16];
  const float* relgate = (const float*)d_in[17];
  const float* n1w     = (const float*)d_in[18];
  const float* n1b     = (const float*)d_in[19];
  const float* n2w     = (const float*)d_in[20];
  const float* n2b     = (const float*)d_in[21];
  const float* f1w     = (const float*)d_in[22];
  const float* f1bias  = (const float*)d_in[23];
  const float* f2w     = (const float*)d_in[24];
  const float* f2bias  = (const float*)d_in[25];
  const float* rnw     = (const float*)d_in[26];
  const float* rnb     = (const float*)d_in[27];
  const float* bw1     = (const float*)d_in[28];
  const float* sw1     = (const float*)d_in[29];
  const float* sc1     = (const float*)d_in[30];
  const float* grid1   = (const float*)d_in[31];
  const float* bw2     = (const float*)d_in[32];
  const float* sw2     = (const float*)d_in[33];
  const float* sc2     = (const float*)d_in[34];
  const float* grid2   = (const float*)d_in[35];
  float* out = (float*)d_out;
  (void)in_sizes; (void)n_in; (void)out_size;

  auto needed = [](int HP) -> size_t {
    auto al = [](size_t b) { return (b + 255) & ~(size_t)255; };
    size_t o = 0;
    o += al((size_t)NN * HID * 4) * 2;
    o += al((size_t)NN * HID * 2);
    o += al((size_t)NN * 128 * HP * 2) * 2;
    o += al((size_t)NE * HP * 4);
    o += al((size_t)NE * 4);
    o += al((size_t)NBIN * 8 + 8);
    o += al((size_t)(NBIN + 1) * 4);
    o += al((size_t)SCAN_BLK * 4);
    o += al((size_t)NL * NR * 512 * 128 * 2) * 2;
    o += al((size_t)NL * 256 * 128 * 2) * 2;
    o += al((size_t)128 * 96 * 2);
    o += al(NR * 4) + al(HID * 4);
    o += al((size_t)(NG + NG * HID * 2) * 4);
    o += al((size_t)NG * 256 * 4) + al((size_t)NG * KH * 4);
    return o;
  };
  const int HP = (needed(4) <= ws_size) ? 4 : 2;
  const int lghp = (HP == 4) ? 2 : 1;
  const int passes = NH / HP;
  const int stride = HP * 128;

  char* p = (char*)d_ws;
  auto alloc = [&](size_t bytes) { void* q = (void*)p; p += (bytes + 255) & ~(size_t)255; return q; };
  float* h    = (float*)alloc((size_t)NN * HID * 4);
  float* hmsg = (float*)alloc((size_t)NN * HID * 4);
  unsigned short* hbf = (unsigned short*)alloc((size_t)NN * HID * 2);
  unsigned short* xlb = (unsigned short*)alloc((size_t)NN * 128 * HP * 2);
  unsigned short* xrb = (unsigned short*)alloc((size_t)NN * 128 * HP * 2);
  float* logit = (float*)alloc((size_t)NE * HP * 4);
  int* elist = (int*)alloc((size_t)NE * 4);
  int* bcnt  = (int*)alloc((size_t)NBIN * 8 + 8);
  int* cur   = bcnt + NBIN;
  int* csroff = (int*)alloc((size_t)(NBIN + 1) * 4);
  int* bsum  = (int*)alloc((size_t)SCAN_BLK * 4);
  unsigned short* linlwb = (unsigned short*)alloc((size_t)NL * NR * 512 * 128 * 2);
  unsigned short* linrwb = (unsigned short*)alloc((size_t)NL * NR * 512 * 128 * 2);
  unsigned short* f1wb   = (unsigned short*)alloc((size_t)NL * 256 * 128 * 2);
  unsigned short* f2wb   = (unsigned short*)alloc((size_t)NL * 128 * 256 * 2);
  unsigned short* inwb   = (unsigned short*)alloc((size_t)128 * 96 * 2);
  float* gate = (float*)alloc(NR * 4);
  float* cb   = (float*)alloc(HID * 4);
  float* rcnt = (float*)alloc((size_t)(NG + NG * HID * 2) * 4);
  float* rsum = rcnt + NG;
  unsigned* rmaxk = (unsigned*)(rsum + (size_t)NG * HID);
  float* g = (float*)alloc((size_t)NG * 256 * 4);
  float* z = (float*)alloc((size_t)NG * KH * 4);
  unsigned short* xinbf = xlb;
  unsigned short* f1buf = xlb;

  const int NB = (NN + 127) / 128;

  {
    int n;
    n = NL * NR * 512 * 128 / 4;
    cvt_bf16<<<(n + 255) / 256, 256, 0, stream>>>(linlw, linlwb, n);
    cvt_bf16<<<(n + 255) / 256, 256, 0, stream>>>(linrw, linrwb, n);
    n = NL * 256 * 128 / 4;
    cvt_bf16<<<(n + 255) / 256, 256, 0, stream>>>(f1w, f1wb, n);
    cvt_bf16<<<(n + 255) / 256, 256, 0, stream>>>(f2w, f2wb, n);
    n = 128 * 96 / 4;
    cvt_bf16<<<(n + 255) / 256, 256, 0, stream>>>(inw, inwb, n);
  }

  hipMemsetAsync(bcnt, 0, (size_t)NBIN * 8 + 8, stream);
  hist_bin<<<(NE + 255) / 256, 256, 0, stream>>>(ei, etype, bcnt);
  scan1<<<SCAN_BLK, 256, 0, stream>>>(bcnt, csroff, bsum);
  scan2<<<1, 256, 0, stream>>>(bsum);
  scan3<<<(NBIN + 256) / 256, 256, 0, stream>>>(csroff, bsum);
  scatter_bin<<<(NE + 255) / 256, 256, 0, stream>>>(ei, etype, csroff, cur, elist);

  build_xin_bf<<<(NN * 96 + 255) / 256, 256, 0, stream>>>(x, idtok, idemb, xinbf);
  gemm_bf16<<<NB, 256, 0, stream>>>(xinbf, inwb, inb, h, nullptr, NN, 96, 128, 1, 1);
  cvt_bf16<<<(NN * HID / 4 + 255) / 256, 256, 0, stream>>>(h, hbf, NN * HID / 4);

  const int logit_blocks = (((NE + 15) / 16) * HP + 3) / 4;
  for (int l = 0; l < NL; ++l) {
    gate_cb<<<1, 128, 0, stream>>>(relgate + l * NR, convb + (size_t)l * NR * HID, gate, cb);
    hipMemsetAsync(hmsg, 0, (size_t)NN * HID * 4, stream);
    for (int r = 0; r < NR; ++r) {
      int lr = l * NR + r;
      for (int hp = 0; hp < passes; ++hp) {
        int hpBase = hp * HP;
        const unsigned short* wl = linlwb + ((size_t)lr * 512 + hpBase * 128) * 128;
        const unsigned short* wr = linrwb + ((size_t)lr * 512 + hpBase * 128) * 128;
        const float* bl = linlb + (size_t)lr * 512 + hpBase * 128;
        const float* br = linrb + (size_t)lr * 512 + hpBase * 128;
        gemm_dual<<<NB * 2 * HP, 256, 0, stream>>>(hbf, wl, wr, bl, br, xlb, xrb,
                                                   NN, 128, stride, HP);
        edge_logit_g<<<logit_blocks, 256, 0, stream>>>(
            ei, elist, csroff, eattr, relemb + (size_t)lr * RED,
            linew + ((size_t)lr * 512 + hpBase * 128) * 24,
            attw + (size_t)lr * 512 + hpBase * 128,
            xlb, xrb, logit, r, HP, lghp, stride);
        edge_smaggr<<<(NN + 3) / 4, 256, 0, stream>>>(
            ei, elist, csroff, logit, xlb, hmsg, gate, r, HP, stride);
      }
    }
    add_ln<<<(NN + 3) / 4, 256, 0, stream>>>(h, hmsg, cb, n1w + l * HID, n1b + l * HID, hbf, NN);
    gemm_bf16<<<NB * 2, 256, 0, stream>>>(hbf, f1wb + (size_t)l * 256 * 128,
                                          f1bias + (size_t)l * 256, nullptr, f1buf,
                                          NN, 128, 256, 1, 2);
    gemm_bf16<<<NB, 256, 0, stream>>>(f1buf, f2wb + (size_t)l * 128 * 256,
                                      f2bias + (size_t)l * 128, hmsg, nullptr,
                                      NN, 256, 128, 0, 1);
    add_ln<<<(NN + 3) / 4, 256, 0, stream>>>(h, hmsg, nullptr, n2w + l * HID, n2b + l * HID, hbf, NN);
  }

  hipMemsetAsync(rcnt, 0, (size_t)(NG + NG * HID * 2) * 4, stream);
  readout_partial<<<NB, 128, 0, stream>>>(h, batch, rcnt, rsum, rmaxk);
  readout_final<<<NG, 256, 0, stream>>>(rcnt, rsum, rmaxk, rnw, rnb, g);
  kan1<<<NG, 128, 0, stream>>>(g, bw1, sw1, sc1, grid1, z);
  kan2<<<NG, 128, 0, stream>>>(z, bw2, sw2, sc2, grid2, out);
}

// Round 9
// 2179.522 us; speedup vs baseline: 4.9662x; 1.1077x over previous
//
#include <hip/hip_runtime.h>
#include <math.h>

#define NN 50000
#define NE 120000
#define FN 64
#define NEA 16
#define NR 4
#define NH 4
#define HID 128
#define NL 3
#define IDE 32
#define RED 8
#define NG 64
#define NC 10
#define KH 128
#define FFH 256
#define NBIN (NR * NN)
#define SCAN_BLK ((NBIN + 1023) / 1024)

typedef short bf16x8 __attribute__((ext_vector_type(8)));
typedef float f32x4 __attribute__((ext_vector_type(4)));

__device__ __forceinline__ unsigned short f2b(float f) {
  unsigned u = __float_as_uint(f);
  unsigned r = (u + 0x7FFFu + ((u >> 16) & 1u)) >> 16;
  return (unsigned short)r;
}
__device__ __forceinline__ float b2f(unsigned short b) {
  return __uint_as_float((unsigned)b << 16);
}
__device__ __forceinline__ unsigned fkey(float f) {
  unsigned u = __float_as_uint(f);
  return (u & 0x80000000u) ? ~u : (u | 0x80000000u);
}
__device__ __forceinline__ float unkey(unsigned k) {
  unsigned u = (k & 0x80000000u) ? (k ^ 0x80000000u) : ~k;
  return __uint_as_float(u);
}

__global__ void cvt_bf16(const float* __restrict__ s, unsigned short* __restrict__ d, int n4) {
  int i = blockIdx.x * blockDim.x + threadIdx.x;
  if (i >= n4) return;
  float4 v = ((const float4*)s)[i];
  ushort4 o;
  o.x = f2b(v.x); o.y = f2b(v.y); o.z = f2b(v.z); o.w = f2b(v.w);
  ((ushort4*)d)[i] = o;
}

// ---- GEMM core: 128x128 tile, LDS-staged bf16 epilogue ----
__device__ __forceinline__ void gemm_core(
    char* smem, const unsigned short* __restrict__ A, const unsigned short* __restrict__ W,
    const float* __restrict__ bias, float* __restrict__ Cf, unsigned short* __restrict__ Cb,
    int nrows, int K, int mout, int act, int rowBase, int colBase) {
  unsigned short (*As)[40] = (unsigned short (*)[40])smem;
  unsigned short (*Ws)[40] = (unsigned short (*)[40])(smem + 10240);
  int t = threadIdx.x;
  int lane = t & 63, w = t >> 6;
  int wm = w >> 1, wn = w & 1;
  int q = lane >> 4, mr = lane & 15;
  f32x4 acc[4][4] = {};
  for (int k0 = 0; k0 < K; k0 += 32) {
#pragma unroll
    for (int half = 0; half < 2; ++half) {
      int c = t + half * 256;
      int row = c >> 2, c16 = c & 3;
      int gr = rowBase + row;
      bf16x8 av = {0, 0, 0, 0, 0, 0, 0, 0};
      if (gr < nrows) av = *(const bf16x8*)(A + (size_t)gr * K + k0 + c16 * 8);
      *(bf16x8*)&As[row][c16 * 8] = av;
      bf16x8 wv = *(const bf16x8*)(W + (size_t)(colBase + row) * K + k0 + c16 * 8);
      *(bf16x8*)&Ws[row][c16 * 8] = wv;
    }
    __syncthreads();
    bf16x8 af[4], bfr[4];
#pragma unroll
    for (int mt = 0; mt < 4; ++mt) af[mt] = *(const bf16x8*)&As[wm * 64 + mt * 16 + mr][q * 8];
#pragma unroll
    for (int nt = 0; nt < 4; ++nt) bfr[nt] = *(const bf16x8*)&Ws[wn * 64 + nt * 16 + mr][q * 8];
#pragma unroll
    for (int mt = 0; mt < 4; ++mt)
#pragma unroll
      for (int nt = 0; nt < 4; ++nt)
        acc[mt][nt] = __builtin_amdgcn_mfma_f32_16x16x32_bf16(af[mt], bfr[nt], acc[mt][nt], 0, 0, 0);
    __syncthreads();
  }
  if (Cb) {
    unsigned short (*Es)[136] = (unsigned short (*)[136])smem;
#pragma unroll
    for (int ph = 0; ph < 2; ++ph) {
      if (wm == ph) {
#pragma unroll
        for (int mt = 0; mt < 4; ++mt)
#pragma unroll
          for (int nt = 0; nt < 4; ++nt)
#pragma unroll
            for (int r = 0; r < 4; ++r) {
              float v = acc[mt][nt][r] + bias[colBase + wn * 64 + nt * 16 + mr];
              if (act) v = v / (1.f + expf(-v));
              Es[mt * 16 + q * 4 + r][wn * 64 + nt * 16 + mr] = f2b(v);
            }
      }
      __syncthreads();
      int rl = t >> 2, co = (t & 3) * 32;
      int grow = rowBase + ph * 64 + rl;
      if (grow < nrows) {
        unsigned short* dst = Cb + (size_t)grow * mout + colBase + co;
#pragma unroll
        for (int j = 0; j < 4; ++j)
          *(bf16x8*)(dst + j * 8) = *(const bf16x8*)&Es[rl][co + j * 8];
      }
      __syncthreads();
    }
  } else {
#pragma unroll
    for (int mt = 0; mt < 4; ++mt)
#pragma unroll
      for (int nt = 0; nt < 4; ++nt)
#pragma unroll
        for (int r = 0; r < 4; ++r) {
          int row = rowBase + wm * 64 + mt * 16 + q * 4 + r;
          int col = colBase + wn * 64 + nt * 16 + mr;
          if (row < nrows) {
            float v = acc[mt][nt][r] + bias[col];
            if (act) v = v / (1.f + expf(-v));
            Cf[(size_t)row * mout + col] = v;
          }
        }
  }
}

// XCD-aware: xcd = bid&7 (round-robin dispatch); each xcd owns a contiguous
// range of row panels, col-variants consecutive within the xcd -> A panel
// fetched into exactly one per-XCD L2.
__global__ __launch_bounds__(256) void gemm_bf16(
    const unsigned short* __restrict__ A, const unsigned short* __restrict__ W,
    const float* __restrict__ bias, float* __restrict__ Cf, unsigned short* __restrict__ Cb,
    int nrows, int K, int mout, int act, int ncol) {
  __shared__ char smem[20480];
  int nbr = (nrows + 127) >> 7;
  int rpx = (nbr + 7) >> 3;
  int xcd = blockIdx.x & 7, j = blockIdx.x >> 3;
  int rowT = xcd * rpx + j / ncol;
  int cy = j - (j / ncol) * ncol;
  if (rowT >= nbr) return;
  gemm_core(smem, A, W, bias, Cf, Cb, nrows, K, mout, act, rowT * 128, cy * 128);
}

__global__ __launch_bounds__(256) void gemm_dual(
    const unsigned short* __restrict__ A,
    const unsigned short* __restrict__ W1, const unsigned short* __restrict__ W2,
    const float* __restrict__ b1, const float* __restrict__ b2,
    unsigned short* __restrict__ C1, unsigned short* __restrict__ C2,
    int nrows, int K, int mout, int HP) {
  __shared__ char smem[20480];
  int nbr = (nrows + 127) >> 7;
  int rpx = (nbr + 7) >> 3;
  int ncv = 2 * HP;
  int xcd = blockIdx.x & 7, j = blockIdx.x >> 3;
  int rowT = xcd * rpx + j / ncv;
  int rem = j - (j / ncv) * ncv;
  int sel = rem / HP, cy = rem - sel * HP;
  if (rowT >= nbr) return;
  gemm_core(smem, A, sel ? W2 : W1, sel ? b2 : b1, nullptr, sel ? C2 : C1,
            nrows, K, mout, 0, rowT * 128, cy * 128);
}

__global__ void build_xin_bf(const float* __restrict__ x, const int* __restrict__ idtok,
                             const float* __restrict__ emb, unsigned short* __restrict__ xin) {
  int i = blockIdx.x * blockDim.x + threadIdx.x;
  if (i >= NN * 96) return;
  int n = i / 96, k = i - n * 96;
  float v = (k < FN) ? x[(size_t)n * FN + k] : emb[(size_t)idtok[n] * IDE + (k - FN)];
  xin[i] = f2b(v);
}

// ---- CSR by (rel, dst) ----
__global__ void hist_bin(const int* __restrict__ ei, const int* __restrict__ et,
                         int* __restrict__ bcnt) {
  int e = blockIdx.x * blockDim.x + threadIdx.x;
  if (e >= NE) return;
  atomicAdd(&bcnt[et[e] * NN + ei[NE + e]], 1);
}
__global__ __launch_bounds__(256) void scan1(const int* __restrict__ cnt,
                                             int* __restrict__ csroff, int* __restrict__ bsum) {
  __shared__ int lds[256];
  int b = blockIdx.x, t = threadIdx.x;
  int base = b * 1024 + t * 4;
  int v[4];
#pragma unroll
  for (int j = 0; j < 4; ++j) v[j] = (base + j < NBIN) ? cnt[base + j] : 0;
  int tot = v[0] + v[1] + v[2] + v[3];
  lds[t] = tot;
  __syncthreads();
  for (int off = 1; off < 256; off <<= 1) {
    int x = (t >= off) ? lds[t - off] : 0;
    __syncthreads();
    lds[t] += x;
    __syncthreads();
  }
  if (t == 255) bsum[b] = lds[255];
  int run = lds[t] - tot;
#pragma unroll
  for (int j = 0; j < 4; ++j) {
    if (base + j < NBIN) csroff[base + j] = run;
    run += v[j];
  }
}
__global__ __launch_bounds__(256) void scan2(int* __restrict__ bsum) {
  __shared__ int lds[256];
  int t = threadIdx.x;
  int v = (t < SCAN_BLK) ? bsum[t] : 0;
  lds[t] = v;
  __syncthreads();
  for (int off = 1; off < 256; off <<= 1) {
    int x = (t >= off) ? lds[t - off] : 0;
    __syncthreads();
    lds[t] += x;
    __syncthreads();
  }
  if (t < SCAN_BLK) bsum[t] = lds[t] - v;
}
__global__ void scan3(int* __restrict__ csroff, const int* __restrict__ bsum) {
  int i = blockIdx.x * blockDim.x + threadIdx.x;
  if (i < NBIN) csroff[i] += bsum[i >> 10];
  if (i == 0) csroff[NBIN] = NE;
}
__global__ void scatter_bin(const int* __restrict__ ei, const int* __restrict__ et,
                            const int* __restrict__ csroff, int* __restrict__ cur,
                            int* __restrict__ elist) {
  int e = blockIdx.x * blockDim.x + threadIdx.x;
  if (e >= NE) return;
  int bin = et[e] * NN + ei[NE + e];
  int p = atomicAdd(&cur[bin], 1);
  elist[csroff[bin] + p] = e;
}
// once per call: CSR-ordered src + edge_attr (coalesced reads thereafter)
__global__ void gather_edge(const int* __restrict__ ei, const int* __restrict__ elist,
                            const float* __restrict__ eattr,
                            int* __restrict__ rsrc, float* __restrict__ eacsr) {
  int p = blockIdx.x * blockDim.x + threadIdx.x;
  if (p >= NE) return;
  int e = elist[p];
  rsrc[p] = ei[e];
  const float4* s = (const float4*)(eattr + (size_t)e * NEA);
  float4* d = (float4*)(eacsr + (size_t)p * NEA);
#pragma unroll
  for (int j = 0; j < 4; ++j) d[j] = s[j];
}

__global__ void gate_cb(const float* __restrict__ rg, const float* __restrict__ cbias,
                        float* __restrict__ gate, float* __restrict__ cb) {
  __shared__ float g[NR];
  int t = threadIdx.x;
  if (t == 0) {
    float mx = rg[0];
    for (int r = 1; r < NR; ++r) mx = fmaxf(mx, rg[r]);
    float s = 0.f, tmp[NR];
    for (int r = 0; r < NR; ++r) { tmp[r] = expf(rg[r] - mx); s += tmp[r]; }
    for (int r = 0; r < NR; ++r) { g[r] = tmp[r] / s; gate[r] = g[r]; }
  }
  __syncthreads();
  float c = 0.f;
  for (int r = 0; r < NR; ++r) c += g[r] * cbias[r * HID + t];
  cb[t] = c;
}

// ---- fused edge pass: one block per dst (grid-stride), wave = head.
// Per edge: eev from VGPR weights, logit, flash-style online softmax with
// rescaled accumulator. Cross-head sum via LDS; plain += (block owns dst). ----
__global__ __launch_bounds__(256) void edge_fused(
    const int* __restrict__ csroff, const int* __restrict__ rsrc,
    const float* __restrict__ eacsr, const float* __restrict__ relembp,
    const float* __restrict__ wedgep, const float* __restrict__ attwp,
    const unsigned short* __restrict__ xlb, const unsigned short* __restrict__ xrb,
    float* __restrict__ hmsg, const float* __restrict__ gate,
    int rel, int HP, int stride) {
  __shared__ float lds[4][128];
  int wave = threadIdx.x >> 6, lane = threadIdx.x & 63;
  bool act = wave < HP;
  int hh = act ? wave : 0;
  float wreg[2][24], areg[2], rreg[8];
#pragma unroll
  for (int j = 0; j < 2; ++j) {
    int col = hh * 128 + j * 64 + lane;
    const float* wp = wedgep + (size_t)col * 24;
#pragma unroll
    for (int k = 0; k < 24; ++k) wreg[j][k] = wp[k];
    areg[j] = attwp[col];
  }
#pragma unroll
  for (int k = 0; k < 8; ++k) rreg[k] = relembp[k];
  float g4 = gate[rel] * 0.25f;
  for (int dst = blockIdx.x; dst < NN; dst += gridDim.x) {
    int s = csroff[rel * NN + dst], e = csroff[rel * NN + dst + 1];
    if (s >= e) continue;  // block-uniform
    float m = -3.4e38f, den = 0.f, acc0 = 0.f, acc1 = 0.f;
    float xr0 = 0.f, xr1 = 0.f;
    if (act) {
      xr0 = b2f(xrb[(size_t)dst * stride + hh * 128 + lane]);
      xr1 = b2f(xrb[(size_t)dst * stride + hh * 128 + 64 + lane]);
    }
    for (int p = s; p < e; ++p) {
      if (act) {
        int src = rsrc[p];
        const float* eap = eacsr + (size_t)p * NEA;
        float er[NEA];
#pragma unroll
        for (int k = 0; k < NEA; ++k) er[k] = eap[k];
        float eev0 = 0.f, eev1 = 0.f;
#pragma unroll
        for (int k = 0; k < NEA; ++k) { eev0 += er[k] * wreg[0][k]; eev1 += er[k] * wreg[1][k]; }
#pragma unroll
        for (int k = 0; k < 8; ++k) { eev0 += rreg[k] * wreg[0][NEA + k]; eev1 += rreg[k] * wreg[1][NEA + k]; }
        float xl0 = b2f(xlb[(size_t)src * stride + hh * 128 + lane]);
        float xl1 = b2f(xlb[(size_t)src * stride + hh * 128 + 64 + lane]);
        float s0 = xl0 + xr0 + eev0; s0 = (s0 > 0.f) ? s0 : 0.2f * s0;
        float s1 = xl1 + xr1 + eev1; s1 = (s1 > 0.f) ? s1 : 0.2f * s1;
        float lg = s0 * areg[0] + s1 * areg[1];
#pragma unroll
        for (int o = 32; o > 0; o >>= 1) lg += __shfl_xor(lg, o, 64);
        float mn = fmaxf(m, lg);
        float sc = expf(m - mn);
        float ex = expf(lg - mn);
        den = den * sc + ex;
        acc0 = acc0 * sc + ex * xl0;
        acc1 = acc1 * sc + ex * xl1;
        m = mn;
      }
    }
    if (act) {
      float w = g4 / den;
      lds[wave][lane] = acc0 * w;
      lds[wave][64 + lane] = acc1 * w;
    }
    __syncthreads();
    if (wave < 2) {
      int d = wave * 64 + lane;
      float v = 0.f;
      for (int h = 0; h < HP; ++h) v += lds[h][d];
      hmsg[(size_t)dst * HID + d] += v;
    }
    __syncthreads();
  }
}

// ---- h = layernorm(h + add (+ cb)); also emits bf16 copy ----
__global__ __launch_bounds__(256) void add_ln(
    float* __restrict__ h, const float* __restrict__ add, const float* __restrict__ cb,
    const float* __restrict__ w, const float* __restrict__ b,
    unsigned short* __restrict__ hbf, int nrows) {
  int wave = threadIdx.x >> 6, lane = threadIdx.x & 63;
  int row = blockIdx.x * 4 + wave;
  if (row >= nrows) return;
  size_t base = (size_t)row * HID;
  float x0 = h[base + lane] + add[base + lane];
  float x1 = h[base + 64 + lane] + add[base + 64 + lane];
  if (cb) { x0 += cb[lane]; x1 += cb[64 + lane]; }
  float s = x0 + x1;
#pragma unroll
  for (int o = 32; o > 0; o >>= 1) s += __shfl_xor(s, o, 64);
  float mean = s * (1.f / 128.f);
  float d0 = x0 - mean, d1 = x1 - mean;
  float v = d0 * d0 + d1 * d1;
#pragma unroll
  for (int o = 32; o > 0; o >>= 1) v += __shfl_xor(v, o, 64);
  float inv = 1.f / sqrtf(v * (1.f / 128.f) + 1e-5f);
  float y0 = d0 * inv * w[lane] + b[lane];
  float y1 = d1 * inv * w[64 + lane] + b[64 + lane];
  h[base + lane] = y0;
  h[base + 64 + lane] = y1;
  hbf[base + lane] = f2b(y0);
  hbf[base + 64 + lane] = f2b(y1);
}

// ---- readout ----
__global__ __launch_bounds__(128) void readout_partial(
    const float* __restrict__ h, const int* __restrict__ batch,
    float* __restrict__ cnt, float* __restrict__ sum, unsigned* __restrict__ maxk) {
  int t = threadIdx.x;
  int r0 = blockIdx.x * 128;
  int r1 = min(r0 + 128, NN);
  int curg = batch[r0];
  float acc = 0.f, mx = -3.4e38f;
  int c = 0;
  for (int row = r0; row < r1; ++row) {
    int g = batch[row];
    if (g != curg) {
      atomicAdd(sum + (size_t)curg * HID + t, acc);
      atomicMax(maxk + (size_t)curg * HID + t, fkey(mx));
      if (t == 0) atomicAdd(cnt + curg, (float)c);
      acc = 0.f; mx = -3.4e38f; c = 0; curg = g;
    }
    float v = h[(size_t)row * HID + t];
    acc += v;
    mx = fmaxf(mx, v);
    ++c;
  }
  atomicAdd(sum + (size_t)curg * HID + t, acc);
  atomicMax(maxk + (size_t)curg * HID + t, fkey(mx));
  if (t == 0) atomicAdd(cnt + curg, (float)c);
}

__global__ __launch_bounds__(256) void readout_final(
    const float* __restrict__ cnt, const float* __restrict__ sum,
    const unsigned* __restrict__ maxk, const float* __restrict__ w,
    const float* __restrict__ b, float* __restrict__ g) {
  int bg = blockIdx.x, t = threadIdx.x;
  __shared__ float red[256];
  float c = fmaxf(cnt[bg], 1.f);
  float x = (t < HID) ? sum[(size_t)bg * HID + t] / c
                      : unkey(maxk[(size_t)bg * HID + (t - HID)]);
  red[t] = x;
  __syncthreads();
  for (int s = 128; s > 0; s >>= 1) {
    if (t < s) red[t] += red[t + s];
    __syncthreads();
  }
  float mean = red[0] * (1.f / 256.f);
  __syncthreads();
  float d = x - mean;
  red[t] = d * d;
  __syncthreads();
  for (int s = 128; s > 0; s >>= 1) {
    if (t < s) red[t] += red[t + s];
    __syncthreads();
  }
  float inv = 1.f / sqrtf(red[0] * (1.f / 256.f) + 1e-5f);
  g[(size_t)bg * 256 + t] = d * inv * w[t] + b[t];
}

__device__ __forceinline__ void bspline8(float x, const float* __restrict__ t,
                                         float* __restrict__ out) {
  float bs[11];
#pragma unroll
  for (int j = 0; j < 11; ++j) bs[j] = (x >= t[j] && x < t[j + 1]) ? 1.f : 0.f;
#pragma unroll
  for (int k = 1; k <= 3; ++k) {
    for (int j = 0; j < 11 - k; ++j) {
      bs[j] = (x - t[j]) / (t[j + k] - t[j]) * bs[j] +
              (t[j + k + 1] - x) / (t[j + k + 1] - t[j + 1]) * bs[j + 1];
    }
  }
#pragma unroll
  for (int j = 0; j < 8; ++j) out[j] = bs[j];
}

__global__ __launch_bounds__(128) void kan1(
    const float* __restrict__ g, const float* __restrict__ bw,
    const float* __restrict__ sw, const float* __restrict__ sc,
    const float* __restrict__ grid, float* __restrict__ z) {
  int bg = blockIdx.x, t = threadIdx.x;
  __shared__ float B[256][8];
  __shared__ float sg[256];
  for (int i = t; i < 256; i += 128) {
    float x = g[(size_t)bg * 256 + i];
    sg[i] = x / (1.f + expf(-x));
    bspline8(x, grid + (size_t)i * 12, B[i]);
  }
  __syncthreads();
  float acc = 0.f;
  for (int i = 0; i < 256; ++i) {
    acc += sg[i] * bw[(size_t)t * 256 + i];
    const float* swp = sw + ((size_t)t * 256 + i) * 8;
    float sp = 0.f;
#pragma unroll
    for (int k = 0; k < 8; ++k) sp += B[i][k] * swp[k];
    acc += sp * sc[(size_t)t * 256 + i];
  }
  z[(size_t)bg * KH + t] = acc;
}

__global__ __launch_bounds__(128) void kan2(
    const float* __restrict__ z, const float* __restrict__ bw,
    const float* __restrict__ sw, const float* __restrict__ sc,
    const float* __restrict__ grid, float* __restrict__ out) {
  int bg = blockIdx.x, t = threadIdx.x;
  __shared__ float B[128][8];
  __shared__ float sz[128];
  float x = z[(size_t)bg * KH + t];
  sz[t] = x / (1.f + expf(-x));
  bspline8(x, grid + (size_t)t * 12, B[t]);
  __syncthreads();
  if (t < NC) {
    float acc = 0.f;
    for (int i = 0; i < 128; ++i) {
      acc += sz[i] * bw[(size_t)t * 128 + i];
      const float* swp = sw + ((size_t)t * 128 + i) * 8;
      float sp = 0.f;
#pragma unroll
      for (int k = 0; k < 8; ++k) sp += B[i][k] * swp[k];
      acc += sp * sc[(size_t)t * 128 + i];
    }
    out[(size_t)bg * NC + t] = acc;
  }
}

extern "C" void kernel_launch(void* const* d_in, const int* in_sizes, int n_in,
                              void* d_out, int out_size, void* d_ws, size_t ws_size,
                              hipStream_t stream) {
  const float* x       = (const float*)d_in[0];
  const float* eattr   = (const float*)d_in[1];
  const int*   idtok   = (const int*)d_in[2];
  const int*   ei      = (const int*)d_in[3];
  const int*   etype   = (const int*)d_in[4];
  const int*   batch   = (const int*)d_in[5];
  const float* idemb   = (const float*)d_in[6];
  const float* inw     = (const float*)d_in[7];
  const float* inb     = (const float*)d_in[8];
  const float* relemb  = (const float*)d_in[9];
  const float* linlw   = (const float*)d_in[10];
  const float* linlb   = (const float*)d_in[11];
  const float* linrw   = (const float*)d_in[12];
  const float* linrb   = (const float*)d_in[13];
  const float* linew   = (const float*)d_in[14];
  const float* attw    = (const float*)d_in[15];
  const float* convb   = (const float*)d_in[16];
  const float* relgate = (const float*)d_in[17];
  const float* n1w     = (const float*)d_in[18];
  const float* n1b     = (const float*)d_in[19];
  const float* n2w     = (const float*)d_in[20];
  const float* n2b     = (const float*)d_in[21];
  const float* f1w     = (const float*)d_in[22];
  const float* f1bias  = (const float*)d_in[23];
  const float* f2w     = (const float*)d_in[24];
  const float* f2bias  = (const float*)d_in[25];
  const float* rnw     = (const float*)d_in[26];
  const float* rnb     = (const float*)d_in[27];
  const float* bw1     = (const float*)d_in[28];
  const float* sw1     = (const float*)d_in[29];
  const float* sc1     = (const float*)d_in[30];
  const float* grid1   = (const float*)d_in[31];
  const float* bw2     = (const float*)d_in[32];
  const float* sw2     = (const float*)d_in[33];
  const float* sc2     = (const float*)d_in[34];
  const float* grid2   = (const float*)d_in[35];
  float* out = (float*)d_out;
  (void)in_sizes; (void)n_in; (void)out_size;

  auto needed = [](int HP) -> size_t {
    auto al = [](size_t b) { return (b + 255) & ~(size_t)255; };
    size_t o = 0;
    o += al((size_t)NN * HID * 4) * 2;            // h, hmsg
    o += al((size_t)NN * HID * 2);                // hbf
    o += al((size_t)NN * 128 * HP * 2) * 2;       // xlb, xrb
    o += al((size_t)NE * 4);                      // elist
    o += al((size_t)NE * 4);                      // rsrc
    o += al((size_t)NE * NEA * 4);                // eacsr
    o += al((size_t)NBIN * 8 + 8);                // bcnt+cur
    o += al((size_t)(NBIN + 1) * 4);              // csroff
    o += al((size_t)SCAN_BLK * 4);                // bsum
    o += al((size_t)NL * NR * 512 * 128 * 2) * 2; // linlwb, linrwb
    o += al((size_t)NL * 256 * 128 * 2) * 2;      // f1wb, f2wb
    o += al((size_t)128 * 96 * 2);                // inwb
    o += al(NR * 4) + al(HID * 4);
    o += al((size_t)(NG + NG * HID * 2) * 4);
    o += al((size_t)NG * 256 * 4) + al((size_t)NG * KH * 4);
    return o;
  };
  const int HP = (needed(4) <= ws_size) ? 4 : 2;
  const int passes = NH / HP;
  const int stride = HP * 128;

  char* p = (char*)d_ws;
  auto alloc = [&](size_t bytes) { void* q = (void*)p; p += (bytes + 255) & ~(size_t)255; return q; };
  float* h    = (float*)alloc((size_t)NN * HID * 4);
  float* hmsg = (float*)alloc((size_t)NN * HID * 4);
  unsigned short* hbf = (unsigned short*)alloc((size_t)NN * HID * 2);
  unsigned short* xlb = (unsigned short*)alloc((size_t)NN * 128 * HP * 2);
  unsigned short* xrb = (unsigned short*)alloc((size_t)NN * 128 * HP * 2);
  int* elist = (int*)alloc((size_t)NE * 4);
  int* rsrc  = (int*)alloc((size_t)NE * 4);
  float* eacsr = (float*)alloc((size_t)NE * NEA * 4);
  int* bcnt  = (int*)alloc((size_t)NBIN * 8 + 8);
  int* cur   = bcnt + NBIN;
  int* csroff = (int*)alloc((size_t)(NBIN + 1) * 4);
  int* bsum  = (int*)alloc((size_t)SCAN_BLK * 4);
  unsigned short* linlwb = (unsigned short*)alloc((size_t)NL * NR * 512 * 128 * 2);
  unsigned short* linrwb = (unsigned short*)alloc((size_t)NL * NR * 512 * 128 * 2);
  unsigned short* f1wb   = (unsigned short*)alloc((size_t)NL * 256 * 128 * 2);
  unsigned short* f2wb   = (unsigned short*)alloc((size_t)NL * 128 * 256 * 2);
  unsigned short* inwb   = (unsigned short*)alloc((size_t)128 * 96 * 2);
  float* gate = (float*)alloc(NR * 4);
  float* cb   = (float*)alloc(HID * 4);
  float* rcnt = (float*)alloc((size_t)(NG + NG * HID * 2) * 4);
  float* rsum = rcnt + NG;
  unsigned* rmaxk = (unsigned*)(rsum + (size_t)NG * HID);
  float* g = (float*)alloc((size_t)NG * 256 * 4);
  float* z = (float*)alloc((size_t)NG * KH * 4);
  unsigned short* xinbf = xlb;
  unsigned short* f1buf = xlb;

  const int NB = (NN + 127) / 128;        // 391 row panels
  const int RPX = (NB + 7) / 8;           // 49 per xcd

  {
    int n;
    n = NL * NR * 512 * 128 / 4;
    cvt_bf16<<<(n + 255) / 256, 256, 0, stream>>>(linlw, linlwb, n);
    cvt_bf16<<<(n + 255) / 256, 256, 0, stream>>>(linrw, linrwb, n);
    n = NL * 256 * 128 / 4;
    cvt_bf16<<<(n + 255) / 256, 256, 0, stream>>>(f1w, f1wb, n);
    cvt_bf16<<<(n + 255) / 256, 256, 0, stream>>>(f2w, f2wb, n);
    n = 128 * 96 / 4;
    cvt_bf16<<<(n + 255) / 256, 256, 0, stream>>>(inw, inwb, n);
  }

  hipMemsetAsync(bcnt, 0, (size_t)NBIN * 8 + 8, stream);
  hist_bin<<<(NE + 255) / 256, 256, 0, stream>>>(ei, etype, bcnt);
  scan1<<<SCAN_BLK, 256, 0, stream>>>(bcnt, csroff, bsum);
  scan2<<<1, 256, 0, stream>>>(bsum);
  scan3<<<(NBIN + 256) / 256, 256, 0, stream>>>(csroff, bsum);
  scatter_bin<<<(NE + 255) / 256, 256, 0, stream>>>(ei, etype, csroff, cur, elist);
  gather_edge<<<(NE + 255) / 256, 256, 0, stream>>>(ei, elist, eattr, rsrc, eacsr);

  build_xin_bf<<<(NN * 96 + 255) / 256, 256, 0, stream>>>(x, idtok, idemb, xinbf);
  gemm_bf16<<<8 * RPX, 256, 0, stream>>>(xinbf, inwb, inb, h, nullptr, NN, 96, 128, 1, 1);
  cvt_bf16<<<(NN * HID / 4 + 255) / 256, 256, 0, stream>>>(h, hbf, NN * HID / 4);

  for (int l = 0; l < NL; ++l) {
    gate_cb<<<1, 128, 0, stream>>>(relgate + l * NR, convb + (size_t)l * NR * HID, gate, cb);
    hipMemsetAsync(hmsg, 0, (size_t)NN * HID * 4, stream);
    for (int r = 0; r < NR; ++r) {
      int lr = l * NR + r;
      for (int hp = 0; hp < passes; ++hp) {
        int hpBase = hp * HP;
        const unsigned short* wl = linlwb + ((size_t)lr * 512 + hpBase * 128) * 128;
        const unsigned short* wr = linrwb + ((size_t)lr * 512 + hpBase * 128) * 128;
        const float* bl = linlb + (size_t)lr * 512 + hpBase * 128;
        const float* br = linrb + (size_t)lr * 512 + hpBase * 128;
        gemm_dual<<<8 * RPX * 2 * HP, 256, 0, stream>>>(hbf, wl, wr, bl, br, xlb, xrb,
                                                        NN, 128, stride, HP);
        edge_fused<<<8192, 256, 0, stream>>>(
            csroff, rsrc, eacsr, relemb + (size_t)lr * RED,
            linew + ((size_t)lr * 512 + hpBase * 128) * 24,
            attw + (size_t)lr * 512 + hpBase * 128,
            xlb, xrb, hmsg, gate, r, HP, stride);
      }
    }
    add_ln<<<(NN + 3) / 4, 256, 0, stream>>>(h, hmsg, cb, n1w + l * HID, n1b + l * HID, hbf, NN);
    gemm_bf16<<<8 * RPX * 2, 256, 0, stream>>>(hbf, f1wb + (size_t)l * 256 * 128,
                                               f1bias + (size_t)l * 256, nullptr, f1buf,
                                               NN, 128, 256, 1, 2);
    gemm_bf16<<<8 * RPX, 256, 0, stream>>>(f1buf, f2wb + (size_t)l * 128 * 256,
                                           f2bias + (size_t)l * 128, hmsg, nullptr,
                                           NN, 256, 128, 0, 1);
    add_ln<<<(NN + 3) / 4, 256, 0, stream>>>(h, hmsg, nullptr, n2w + l * HID, n2b + l * HID, hbf, NN);
  }

  hipMemsetAsync(rcnt, 0, (size_t)(NG + NG * HID * 2) * 4, stream);
  readout_partial<<<NB, 128, 0, stream>>>(h, batch, rcnt, rsum, rmaxk);
  readout_final<<<NG, 256, 0, stream>>>(rcnt, rsum, rmaxk, rnw, rnb, g);
  kan1<<<NG, 128, 0, stream>>>(g, bw1, sw1, sc1, grid1, z);
  kan2<<<NG, 128, 0, stream>>>(z, bw2, sw2, sc2, grid2, out);
}

// Round 10
// 1930.598 us; speedup vs baseline: 5.6065x; 1.1289x over previous
//
#include <hip/hip_runtime.h>
#include <math.h>

#define NN 50000
#define NE 120000
#define FN 64
#define NEA 16
#define NR 4
#define NH 4
#define HID 128
#define NL 3
#define IDE 32
#define RED 8
#define NG 64
#define NC 10
#define KH 128
#define FFH 256
#define NBIN (NR * NN)
#define SCAN_BLK ((NBIN + 1023) / 1024)

typedef short bf16x8 __attribute__((ext_vector_type(8)));
typedef float f32x4 __attribute__((ext_vector_type(4)));

__device__ __forceinline__ unsigned short f2b(float f) {
  unsigned u = __float_as_uint(f);
  unsigned r = (u + 0x7FFFu + ((u >> 16) & 1u)) >> 16;
  return (unsigned short)r;
}
__device__ __forceinline__ float b2f(unsigned short b) {
  return __uint_as_float((unsigned)b << 16);
}
__device__ __forceinline__ unsigned fkey(float f) {
  unsigned u = __float_as_uint(f);
  return (u & 0x80000000u) ? ~u : (u | 0x80000000u);
}
__device__ __forceinline__ float unkey(unsigned k) {
  unsigned u = (k & 0x80000000u) ? (k ^ 0x80000000u) : ~k;
  return __uint_as_float(u);
}

__global__ void cvt_bf16(const float* __restrict__ s, unsigned short* __restrict__ d, int n4) {
  int i = blockIdx.x * blockDim.x + threadIdx.x;
  if (i >= n4) return;
  float4 v = ((const float4*)s)[i];
  ushort4 o;
  o.x = f2b(v.x); o.y = f2b(v.y); o.z = f2b(v.z); o.w = f2b(v.w);
  ((ushort4*)d)[i] = o;
}

// ---- GEMM core: 128x128 tile, optional A-row gather, LDS-staged bf16 epilogue ----
__device__ __forceinline__ void gemm_core(
    char* smem, const unsigned short* __restrict__ A, const int* __restrict__ rowlist,
    const unsigned short* __restrict__ W,
    const float* __restrict__ bias, float* __restrict__ Cf, unsigned short* __restrict__ Cb,
    int nrows, int K, int mout, int act, int rowBase, int colBase) {
  unsigned short (*As)[40] = (unsigned short (*)[40])smem;
  unsigned short (*Ws)[40] = (unsigned short (*)[40])(smem + 10240);
  int t = threadIdx.x;
  int lane = t & 63, w = t >> 6;
  int wm = w >> 1, wn = w & 1;
  int q = lane >> 4, mr = lane & 15;
  f32x4 acc[4][4] = {};
  for (int k0 = 0; k0 < K; k0 += 32) {
#pragma unroll
    for (int half = 0; half < 2; ++half) {
      int c = t + half * 256;
      int row = c >> 2, c16 = c & 3;
      int gr = rowBase + row;
      bf16x8 av = {0, 0, 0, 0, 0, 0, 0, 0};
      if (gr < nrows) {
        int ar = rowlist ? rowlist[gr] : gr;
        av = *(const bf16x8*)(A + (size_t)ar * K + k0 + c16 * 8);
      }
      *(bf16x8*)&As[row][c16 * 8] = av;
      bf16x8 wv = *(const bf16x8*)(W + (size_t)(colBase + row) * K + k0 + c16 * 8);
      *(bf16x8*)&Ws[row][c16 * 8] = wv;
    }
    __syncthreads();
    bf16x8 af[4], bfr[4];
#pragma unroll
    for (int mt = 0; mt < 4; ++mt) af[mt] = *(const bf16x8*)&As[wm * 64 + mt * 16 + mr][q * 8];
#pragma unroll
    for (int nt = 0; nt < 4; ++nt) bfr[nt] = *(const bf16x8*)&Ws[wn * 64 + nt * 16 + mr][q * 8];
#pragma unroll
    for (int mt = 0; mt < 4; ++mt)
#pragma unroll
      for (int nt = 0; nt < 4; ++nt)
        acc[mt][nt] = __builtin_amdgcn_mfma_f32_16x16x32_bf16(af[mt], bfr[nt], acc[mt][nt], 0, 0, 0);
    __syncthreads();
  }
  if (Cb) {
    unsigned short (*Es)[136] = (unsigned short (*)[136])smem;
#pragma unroll
    for (int ph = 0; ph < 2; ++ph) {
      if (wm == ph) {
#pragma unroll
        for (int mt = 0; mt < 4; ++mt)
#pragma unroll
          for (int nt = 0; nt < 4; ++nt)
#pragma unroll
            for (int r = 0; r < 4; ++r) {
              float v = acc[mt][nt][r] + bias[colBase + wn * 64 + nt * 16 + mr];
              if (act) v = v / (1.f + expf(-v));
              Es[mt * 16 + q * 4 + r][wn * 64 + nt * 16 + mr] = f2b(v);
            }
      }
      __syncthreads();
      int rl = t >> 2, co = (t & 3) * 32;
      int grow = rowBase + ph * 64 + rl;
      if (grow < nrows) {
        unsigned short* dst = Cb + (size_t)grow * mout + colBase + co;
#pragma unroll
        for (int j = 0; j < 4; ++j)
          *(bf16x8*)(dst + j * 8) = *(const bf16x8*)&Es[rl][co + j * 8];
      }
      __syncthreads();
    }
  } else {
#pragma unroll
    for (int mt = 0; mt < 4; ++mt)
#pragma unroll
      for (int nt = 0; nt < 4; ++nt)
#pragma unroll
        for (int r = 0; r < 4; ++r) {
          int row = rowBase + wm * 64 + mt * 16 + q * 4 + r;
          int col = colBase + wn * 64 + nt * 16 + mr;
          if (row < nrows) {
            float v = acc[mt][nt][r] + bias[col];
            if (act) v = v / (1.f + expf(-v));
            Cf[(size_t)row * mout + col] = v;
          }
        }
  }
}

// XCD-aware full GEMM (dispatch is round-robin over 8 XCDs: bid&7 = XCD)
__global__ __launch_bounds__(256) void gemm_bf16(
    const unsigned short* __restrict__ A, const unsigned short* __restrict__ W,
    const float* __restrict__ bias, float* __restrict__ Cf, unsigned short* __restrict__ Cb,
    int nrows, int K, int mout, int act, int ncol) {
  __shared__ char smem[20480];
  int nbr = (nrows + 127) >> 7;
  int rpx = (nbr + 7) >> 3;
  int xcd = blockIdx.x & 7, j = blockIdx.x >> 3;
  int rowT = xcd * rpx + j / ncol;
  int cy = j - (j / ncol) * ncol;
  if (rowT >= nbr) return;
  gemm_core(smem, A, nullptr, W, bias, Cf, Cb, nrows, K, mout, act, rowT * 128, cy * 128);
}

// row-gather GEMM over device-side row count (xr for deg>=2 dsts only)
__global__ __launch_bounds__(256) void gemm_rows(
    const unsigned short* __restrict__ A, const int* __restrict__ rowlist,
    const int* __restrict__ nrowsp, const unsigned short* __restrict__ W,
    const float* __restrict__ bias, unsigned short* __restrict__ Cb,
    int K, int mout, int ncol) {
  __shared__ char smem[20480];
  int nrows = *nrowsp;
  int bid = blockIdx.x;
  int rowT = bid / ncol, cy = bid - rowT * ncol;
  if (rowT * 128 >= nrows) return;
  gemm_core(smem, A, rowlist, W, bias, nullptr, Cb, nrows, K, mout, 0, rowT * 128, cy * 128);
}

__global__ void build_xin_bf(const float* __restrict__ x, const int* __restrict__ idtok,
                             const float* __restrict__ emb, unsigned short* __restrict__ xin) {
  int i = blockIdx.x * blockDim.x + threadIdx.x;
  if (i >= NN * 96) return;
  int n = i / 96, k = i - n * 96;
  float v = (k < FN) ? x[(size_t)n * FN + k] : emb[(size_t)idtok[n] * IDE + (k - FN)];
  xin[i] = f2b(v);
}

// ---- CSR by (rel, dst) ----
__global__ void hist_bin(const int* __restrict__ ei, const int* __restrict__ et,
                         int* __restrict__ bcnt) {
  int e = blockIdx.x * blockDim.x + threadIdx.x;
  if (e >= NE) return;
  atomicAdd(&bcnt[et[e] * NN + ei[NE + e]], 1);
}
__global__ __launch_bounds__(256) void scan1(const int* __restrict__ cnt,
                                             int* __restrict__ csroff, int* __restrict__ bsum) {
  __shared__ int lds[256];
  int b = blockIdx.x, t = threadIdx.x;
  int base = b * 1024 + t * 4;
  int v[4];
#pragma unroll
  for (int j = 0; j < 4; ++j) v[j] = (base + j < NBIN) ? cnt[base + j] : 0;
  int tot = v[0] + v[1] + v[2] + v[3];
  lds[t] = tot;
  __syncthreads();
  for (int off = 1; off < 256; off <<= 1) {
    int x = (t >= off) ? lds[t - off] : 0;
    __syncthreads();
    lds[t] += x;
    __syncthreads();
  }
  if (t == 255) bsum[b] = lds[255];
  int run = lds[t] - tot;
#pragma unroll
  for (int j = 0; j < 4; ++j) {
    if (base + j < NBIN) csroff[base + j] = run;
    run += v[j];
  }
}
__global__ __launch_bounds__(256) void scan2(int* __restrict__ bsum) {
  __shared__ int lds[256];
  int t = threadIdx.x;
  int v = (t < SCAN_BLK) ? bsum[t] : 0;
  lds[t] = v;
  __syncthreads();
  for (int off = 1; off < 256; off <<= 1) {
    int x = (t >= off) ? lds[t - off] : 0;
    __syncthreads();
    lds[t] += x;
    __syncthreads();
  }
  if (t < SCAN_BLK) bsum[t] = lds[t] - v;
}
__global__ void scan3(int* __restrict__ csroff, const int* __restrict__ bsum) {
  int i = blockIdx.x * blockDim.x + threadIdx.x;
  if (i < NBIN) csroff[i] += bsum[i >> 10];
  if (i == 0) csroff[NBIN] = NE;
}
__global__ void scatter_bin(const int* __restrict__ ei, const int* __restrict__ et,
                            const int* __restrict__ csroff, int* __restrict__ cur,
                            int* __restrict__ elist) {
  int e = blockIdx.x * blockDim.x + threadIdx.x;
  if (e >= NE) return;
  int bin = et[e] * NN + ei[NE + e];
  int p = atomicAdd(&cur[bin], 1);
  elist[csroff[bin] + p] = e;
}
__global__ void gather_edge(const int* __restrict__ ei, const int* __restrict__ elist,
                            const float* __restrict__ eattr,
                            int* __restrict__ rsrc, float* __restrict__ eacsr) {
  int p = blockIdx.x * blockDim.x + threadIdx.x;
  if (p >= NE) return;
  int e = elist[p];
  rsrc[p] = ei[e];
  const float4* s = (const float4*)(eattr + (size_t)e * NEA);
  float4* d = (float4*)(eacsr + (size_t)p * NEA);
#pragma unroll
  for (int j = 0; j < 4; ++j) d[j] = s[j];
}
// hot dsts (deg>=2) per rel; ballot-aggregated (returning atomics serialize!)
__global__ void build_hot(const int* __restrict__ csroff, int* __restrict__ nhot,
                          int* __restrict__ hotlist, int* __restrict__ hotidx) {
  int b = blockIdx.x * blockDim.x + threadIdx.x;
  bool valid = b < NBIN;
  int cnt = 0, rel = -1;
  if (valid) { cnt = csroff[b + 1] - csroff[b]; rel = b / NN; }
  bool hot = valid && cnt >= 2;
  int lane = threadIdx.x & 63;
  int idx = -1;
  for (int rr = 0; rr < NR; ++rr) {
    unsigned long long m = __ballot(hot && rel == rr);
    if (m == 0ull) continue;
    int leader = __ffsll((unsigned long long)m) - 1;
    int base = 0;
    if (lane == leader) base = atomicAdd(&nhot[rr], __popcll(m));
    base = __shfl(base, leader, 64);
    if (hot && rel == rr) {
      unsigned long long below = m & ((1ull << lane) - 1ull);
      int pos = base + __popcll(below);
      hotlist[rr * NN + pos] = b - rr * NN;
      idx = pos;
    }
  }
  if (valid) hotidx[b] = idx;
}

__global__ void gate_cb(const float* __restrict__ rg, const float* __restrict__ cbias,
                        float* __restrict__ gate, float* __restrict__ cb) {
  __shared__ float g[NR];
  int t = threadIdx.x;
  if (t == 0) {
    float mx = rg[0];
    for (int r = 1; r < NR; ++r) mx = fmaxf(mx, rg[r]);
    float s = 0.f, tmp[NR];
    for (int r = 0; r < NR; ++r) { tmp[r] = expf(rg[r] - mx); s += tmp[r]; }
    for (int r = 0; r < NR; ++r) { g[r] = tmp[r] / s; gate[r] = g[r]; }
  }
  __syncthreads();
  float c = 0.f;
  for (int r = 0; r < NR; ++r) c += g[r] * cbias[r * HID + t];
  cb[t] = c;
}

// ---- fused edge pass. deg-1 dsts (majority): softmax weight == 1 exactly ->
// pure gather-scale, no xr/eev/exp. deg>=2: online softmax, xr from hot buffer. ----
__global__ __launch_bounds__(256) void edge_fused(
    const int* __restrict__ csroff, const int* __restrict__ rsrc,
    const float* __restrict__ eacsr, const float* __restrict__ relembp,
    const float* __restrict__ wedgep, const float* __restrict__ attwp,
    const unsigned short* __restrict__ xlb, const unsigned short* __restrict__ xrh,
    const int* __restrict__ hotidx, float* __restrict__ hmsg,
    const float* __restrict__ gate, int rel, int HP, int stride) {
  __shared__ float lds[4][128];
  int wave = threadIdx.x >> 6, lane = threadIdx.x & 63;
  bool act = wave < HP;
  int hh = act ? wave : 0;
  float wreg[2][24], areg[2];
#pragma unroll
  for (int j = 0; j < 2; ++j) {
    int col = hh * 128 + j * 64 + lane;
    const float* wp = wedgep + (size_t)col * 24;
#pragma unroll
    for (int k = 0; k < 24; ++k) wreg[j][k] = wp[k];
    areg[j] = attwp[col];
  }
  float evr0 = 0.f, evr1 = 0.f;  // relemb part of eev (edge-independent)
#pragma unroll
  for (int k = 0; k < 8; ++k) {
    float rk = relembp[k];
    evr0 += rk * wreg[0][NEA + k];
    evr1 += rk * wreg[1][NEA + k];
  }
  float g4 = gate[rel] * 0.25f;
  for (int dst = blockIdx.x; dst < NN; dst += gridDim.x) {
    int s = csroff[rel * NN + dst], e = csroff[rel * NN + dst + 1];
    int cnt = e - s;
    if (cnt == 0) continue;
    float o0 = 0.f, o1 = 0.f;
    if (cnt == 1) {
      if (act) {
        int src = rsrc[s];
        o0 = g4 * b2f(xlb[(size_t)src * stride + hh * 128 + lane]);
        o1 = g4 * b2f(xlb[(size_t)src * stride + hh * 128 + 64 + lane]);
      }
    } else if (act) {
      int hi = hotidx[rel * NN + dst];
      const unsigned short* xrp = xrh + (size_t)hi * stride;
      float xr0 = b2f(xrp[hh * 128 + lane]);
      float xr1 = b2f(xrp[hh * 128 + 64 + lane]);
      float m = -3.4e38f, den = 0.f, acc0 = 0.f, acc1 = 0.f;
      for (int p = s; p < e; ++p) {
        int src = rsrc[p];
        const float* eap = eacsr + (size_t)p * NEA;
        float er[NEA];
#pragma unroll
        for (int k = 0; k < NEA; ++k) er[k] = eap[k];
        float eev0 = evr0, eev1 = evr1;
#pragma unroll
        for (int k = 0; k < NEA; ++k) { eev0 += er[k] * wreg[0][k]; eev1 += er[k] * wreg[1][k]; }
        float xl0 = b2f(xlb[(size_t)src * stride + hh * 128 + lane]);
        float xl1 = b2f(xlb[(size_t)src * stride + hh * 128 + 64 + lane]);
        float s0 = xl0 + xr0 + eev0; s0 = (s0 > 0.f) ? s0 : 0.2f * s0;
        float s1 = xl1 + xr1 + eev1; s1 = (s1 > 0.f) ? s1 : 0.2f * s1;
        float lg = s0 * areg[0] + s1 * areg[1];
#pragma unroll
        for (int o = 32; o > 0; o >>= 1) lg += __shfl_xor(lg, o, 64);
        float mn = fmaxf(m, lg);
        float sc = expf(m - mn);
        float ex = expf(lg - mn);
        den = den * sc + ex;
        acc0 = acc0 * sc + ex * xl0;
        acc1 = acc1 * sc + ex * xl1;
        m = mn;
      }
      float w = g4 / den;
      o0 = acc0 * w;
      o1 = acc1 * w;
    }
    if (act) {
      lds[wave][lane] = o0;
      lds[wave][64 + lane] = o1;
    }
    __syncthreads();
    if (wave < 2) {
      int d = wave * 64 + lane;
      float v = 0.f;
      for (int h = 0; h < HP; ++h) v += lds[h][d];
      hmsg[(size_t)dst * HID + d] += v;
    }
    __syncthreads();
  }
}

// ---- h = layernorm(h + add (+ cb)); also emits bf16 copy ----
__global__ __launch_bounds__(256) void add_ln(
    float* __restrict__ h, const float* __restrict__ add, const float* __restrict__ cb,
    const float* __restrict__ w, const float* __restrict__ b,
    unsigned short* __restrict__ hbf, int nrows) {
  int wave = threadIdx.x >> 6, lane = threadIdx.x & 63;
  int row = blockIdx.x * 4 + wave;
  if (row >= nrows) return;
  size_t base = (size_t)row * HID;
  float x0 = h[base + lane] + add[base + lane];
  float x1 = h[base + 64 + lane] + add[base + 64 + lane];
  if (cb) { x0 += cb[lane]; x1 += cb[64 + lane]; }
  float s = x0 + x1;
#pragma unroll
  for (int o = 32; o > 0; o >>= 1) s += __shfl_xor(s, o, 64);
  float mean = s * (1.f / 128.f);
  float d0 = x0 - mean, d1 = x1 - mean;
  float v = d0 * d0 + d1 * d1;
#pragma unroll
  for (int o = 32; o > 0; o >>= 1) v += __shfl_xor(v, o, 64);
  float inv = 1.f / sqrtf(v * (1.f / 128.f) + 1e-5f);
  float y0 = d0 * inv * w[lane] + b[lane];
  float y1 = d1 * inv * w[64 + lane] + b[64 + lane];
  h[base + lane] = y0;
  h[base + 64 + lane] = y1;
  hbf[base + lane] = f2b(y0);
  hbf[base + 64 + lane] = f2b(y1);
}

// ---- readout ----
__global__ __launch_bounds__(128) void readout_partial(
    const float* __restrict__ h, const int* __restrict__ batch,
    float* __restrict__ cnt, float* __restrict__ sum, unsigned* __restrict__ maxk) {
  int t = threadIdx.x;
  int r0 = blockIdx.x * 128;
  int r1 = min(r0 + 128, NN);
  int curg = batch[r0];
  float acc = 0.f, mx = -3.4e38f;
  int c = 0;
  for (int row = r0; row < r1; ++row) {
    int g = batch[row];
    if (g != curg) {
      atomicAdd(sum + (size_t)curg * HID + t, acc);
      atomicMax(maxk + (size_t)curg * HID + t, fkey(mx));
      if (t == 0) atomicAdd(cnt + curg, (float)c);
      acc = 0.f; mx = -3.4e38f; c = 0; curg = g;
    }
    float v = h[(size_t)row * HID + t];
    acc += v;
    mx = fmaxf(mx, v);
    ++c;
  }
  atomicAdd(sum + (size_t)curg * HID + t, acc);
  atomicMax(maxk + (size_t)curg * HID + t, fkey(mx));
  if (t == 0) atomicAdd(cnt + curg, (float)c);
}

__global__ __launch_bounds__(256) void readout_final(
    const float* __restrict__ cnt, const float* __restrict__ sum,
    const unsigned* __restrict__ maxk, const float* __restrict__ w,
    const float* __restrict__ b, float* __restrict__ g) {
  int bg = blockIdx.x, t = threadIdx.x;
  __shared__ float red[256];
  float c = fmaxf(cnt[bg], 1.f);
  float x = (t < HID) ? sum[(size_t)bg * HID + t] / c
                      : unkey(maxk[(size_t)bg * HID + (t - HID)]);
  red[t] = x;
  __syncthreads();
  for (int s = 128; s > 0; s >>= 1) {
    if (t < s) red[t] += red[t + s];
    __syncthreads();
  }
  float mean = red[0] * (1.f / 256.f);
  __syncthreads();
  float d = x - mean;
  red[t] = d * d;
  __syncthreads();
  for (int s = 128; s > 0; s >>= 1) {
    if (t < s) red[t] += red[t + s];
    __syncthreads();
  }
  float inv = 1.f / sqrtf(red[0] * (1.f / 256.f) + 1e-5f);
  g[(size_t)bg * 256 + t] = d * inv * w[t] + b[t];
}

__device__ __forceinline__ void bspline8(float x, const float* __restrict__ t,
                                         float* __restrict__ out) {
  float bs[11];
#pragma unroll
  for (int j = 0; j < 11; ++j) bs[j] = (x >= t[j] && x < t[j + 1]) ? 1.f : 0.f;
#pragma unroll
  for (int k = 1; k <= 3; ++k) {
    for (int j = 0; j < 11 - k; ++j) {
      bs[j] = (x - t[j]) / (t[j + k] - t[j]) * bs[j] +
              (t[j + k + 1] - x) / (t[j + k + 1] - t[j + 1]) * bs[j + 1];
    }
  }
#pragma unroll
  for (int j = 0; j < 8; ++j) out[j] = bs[j];
}

__global__ __launch_bounds__(128) void kan1(
    const float* __restrict__ g, const float* __restrict__ bw,
    const float* __restrict__ sw, const float* __restrict__ sc,
    const float* __restrict__ grid, float* __restrict__ z) {
  int bg = blockIdx.x, t = threadIdx.x;
  __shared__ float B[256][8];
  __shared__ float sg[256];
  for (int i = t; i < 256; i += 128) {
    float x = g[(size_t)bg * 256 + i];
    sg[i] = x / (1.f + expf(-x));
    bspline8(x, grid + (size_t)i * 12, B[i]);
  }
  __syncthreads();
  float acc = 0.f;
  for (int i = 0; i < 256; ++i) {
    acc += sg[i] * bw[(size_t)t * 256 + i];
    const float* swp = sw + ((size_t)t * 256 + i) * 8;
    float sp = 0.f;
#pragma unroll
    for (int k = 0; k < 8; ++k) sp += B[i][k] * swp[k];
    acc += sp * sc[(size_t)t * 256 + i];
  }
  z[(size_t)bg * KH + t] = acc;
}

__global__ __launch_bounds__(128) void kan2(
    const float* __restrict__ z, const float* __restrict__ bw,
    const float* __restrict__ sw, const float* __restrict__ sc,
    const float* __restrict__ grid, float* __restrict__ out) {
  int bg = blockIdx.x, t = threadIdx.x;
  __shared__ float B[128][8];
  __shared__ float sz[128];
  float x = z[(size_t)bg * KH + t];
  sz[t] = x / (1.f + expf(-x));
  bspline8(x, grid + (size_t)t * 12, B[t]);
  __syncthreads();
  if (t < NC) {
    float acc = 0.f;
    for (int i = 0; i < 128; ++i) {
      acc += sz[i] * bw[(size_t)t * 128 + i];
      const float* swp = sw + ((size_t)t * 128 + i) * 8;
      float sp = 0.f;
#pragma unroll
      for (int k = 0; k < 8; ++k) sp += B[i][k] * swp[k];
      acc += sp * sc[(size_t)t * 128 + i];
    }
    out[(size_t)bg * NC + t] = acc;
  }
}

extern "C" void kernel_launch(void* const* d_in, const int* in_sizes, int n_in,
                              void* d_out, int out_size, void* d_ws, size_t ws_size,
                              hipStream_t stream) {
  const float* x       = (const float*)d_in[0];
  const float* eattr   = (const float*)d_in[1];
  const int*   idtok   = (const int*)d_in[2];
  const int*   ei      = (const int*)d_in[3];
  const int*   etype   = (const int*)d_in[4];
  const int*   batch   = (const int*)d_in[5];
  const float* idemb   = (const float*)d_in[6];
  const float* inw     = (const float*)d_in[7];
  const float* inb     = (const float*)d_in[8];
  const float* relemb  = (const float*)d_in[9];
  const float* linlw   = (const float*)d_in[10];
  const float* linlb   = (const float*)d_in[11];
  const float* linrw   = (const float*)d_in[12];
  const float* linrb   = (const float*)d_in[13];
  const float* linew   = (const float*)d_in[14];
  const float* attw    = (const float*)d_in[15];
  const float* convb   = (const float*)d_in[16];
  const float* relgate = (const float*)d_in[17];
  const float* n1w     = (const float*)d_in[18];
  const float* n1b     = (const float*)d_in[19];
  const float* n2w     = (const float*)d_in[20];
  const float* n2b     = (const float*)d_in[21];
  const float* f1w     = (const float*)d_in[22];
  const float* f1bias  = (const float*)d_in[23];
  const float* f2w     = (const float*)d_in[24];
  const float* f2bias  = (const float*)d_in[25];
  const float* rnw     = (const float*)d_in[26];
  const float* rnb     = (const float*)d_in[27];
  const float* bw1     = (const float*)d_in[28];
  const float* sw1     = (const float*)d_in[29];
  const float* sc1     = (const float*)d_in[30];
  const float* grid1   = (const float*)d_in[31];
  const float* bw2     = (const float*)d_in[32];
  const float* sw2     = (const float*)d_in[33];
  const float* sc2     = (const float*)d_in[34];
  const float* grid2   = (const float*)d_in[35];
  float* out = (float*)d_out;
  (void)in_sizes; (void)n_in; (void)out_size;

  auto needed = [](int HP) -> size_t {
    auto al = [](size_t b) { return (b + 255) & ~(size_t)255; };
    size_t o = 0;
    o += al((size_t)NN * HID * 4) * 2;            // h, hmsg
    o += al((size_t)NN * HID * 2);                // hbf
    o += al((size_t)NN * 128 * HP * 2) * 2;       // xlb, xrh
    o += al((size_t)NE * 4) * 2;                  // elist, rsrc
    o += al((size_t)NE * NEA * 4);                // eacsr
    o += al((size_t)NBIN * 8 + 8);                // bcnt+cur
    o += al((size_t)(NBIN + 1) * 4);              // csroff
    o += al((size_t)SCAN_BLK * 4);                // bsum
    o += al((size_t)NR * NN * 4);                 // hotlist
    o += al((size_t)NBIN * 4);                    // hotidx
    o += al(64);                                  // nhot
    o += al((size_t)NL * NR * 512 * 128 * 2) * 2; // linlwb, linrwb
    o += al((size_t)NL * 256 * 128 * 2) * 2;      // f1wb, f2wb
    o += al((size_t)128 * 96 * 2);                // inwb
    o += al(NR * 4) + al(HID * 4);
    o += al((size_t)(NG + NG * HID * 2) * 4);
    o += al((size_t)NG * 256 * 4) + al((size_t)NG * KH * 4);
    return o;
  };
  const int HP = (needed(4) <= ws_size) ? 4 : 2;
  const int passes = NH / HP;
  const int stride = HP * 128;

  char* p = (char*)d_ws;
  auto alloc = [&](size_t bytes) { void* q = (void*)p; p += (bytes + 255) & ~(size_t)255; return q; };
  float* h    = (float*)alloc((size_t)NN * HID * 4);
  float* hmsg = (float*)alloc((size_t)NN * HID * 4);
  unsigned short* hbf = (unsigned short*)alloc((size_t)NN * HID * 2);
  unsigned short* xlb = (unsigned short*)alloc((size_t)NN * 128 * HP * 2);
  unsigned short* xrh = (unsigned short*)alloc((size_t)NN * 128 * HP * 2);
  int* elist = (int*)alloc((size_t)NE * 4);
  int* rsrc  = (int*)alloc((size_t)NE * 4);
  float* eacsr = (float*)alloc((size_t)NE * NEA * 4);
  int* bcnt  = (int*)alloc((size_t)NBIN * 8 + 8);
  int* cur   = bcnt + NBIN;
  int* csroff = (int*)alloc((size_t)(NBIN + 1) * 4);
  int* bsum  = (int*)alloc((size_t)SCAN_BLK * 4);
  int* hotlist = (int*)alloc((size_t)NR * NN * 4);
  int* hotidx  = (int*)alloc((size_t)NBIN * 4);
  int* nhot    = (int*)alloc(64);
  unsigned short* linlwb = (unsigned short*)alloc((size_t)NL * NR * 512 * 128 * 2);
  unsigned short* linrwb = (unsigned short*)alloc((size_t)NL * NR * 512 * 128 * 2);
  unsigned short* f1wb   = (unsigned short*)alloc((size_t)NL * 256 * 128 * 2);
  unsigned short* f2wb   = (unsigned short*)alloc((size_t)NL * 128 * 256 * 2);
  unsigned short* inwb   = (unsigned short*)alloc((size_t)128 * 96 * 2);
  float* gate = (float*)alloc(NR * 4);
  float* cb   = (float*)alloc(HID * 4);
  float* rcnt = (float*)alloc((size_t)(NG + NG * HID * 2) * 4);
  float* rsum = rcnt + NG;
  unsigned* rmaxk = (unsigned*)(rsum + (size_t)NG * HID);
  float* g = (float*)alloc((size_t)NG * 256 * 4);
  float* z = (float*)alloc((size_t)NG * KH * 4);
  unsigned short* xinbf = xlb;
  unsigned short* f1buf = xlb;

  const int NB = (NN + 127) / 128;        // 391 row panels
  const int RPX = (NB + 7) / 8;           // per xcd

  {
    int n;
    n = NL * NR * 512 * 128 / 4;
    cvt_bf16<<<(n + 255) / 256, 256, 0, stream>>>(linlw, linlwb, n);
    cvt_bf16<<<(n + 255) / 256, 256, 0, stream>>>(linrw, linrwb, n);
    n = NL * 256 * 128 / 4;
    cvt_bf16<<<(n + 255) / 256, 256, 0, stream>>>(f1w, f1wb, n);
    cvt_bf16<<<(n + 255) / 256, 256, 0, stream>>>(f2w, f2wb, n);
    n = 128 * 96 / 4;
    cvt_bf16<<<(n + 255) / 256, 256, 0, stream>>>(inw, inwb, n);
  }

  hipMemsetAsync(bcnt, 0, (size_t)NBIN * 8 + 8, stream);
  hipMemsetAsync(nhot, 0, 64, stream);
  hist_bin<<<(NE + 255) / 256, 256, 0, stream>>>(ei, etype, bcnt);
  scan1<<<SCAN_BLK, 256, 0, stream>>>(bcnt, csroff, bsum);
  scan2<<<1, 256, 0, stream>>>(bsum);
  scan3<<<(NBIN + 256) / 256, 256, 0, stream>>>(csroff, bsum);
  scatter_bin<<<(NE + 255) / 256, 256, 0, stream>>>(ei, etype, csroff, cur, elist);
  gather_edge<<<(NE + 255) / 256, 256, 0, stream>>>(ei, elist, eattr, rsrc, eacsr);
  build_hot<<<(NBIN + 255) / 256, 256, 0, stream>>>(csroff, nhot, hotlist, hotidx);

  build_xin_bf<<<(NN * 96 + 255) / 256, 256, 0, stream>>>(x, idtok, idemb, xinbf);
  gemm_bf16<<<8 * RPX, 256, 0, stream>>>(xinbf, inwb, inb, h, nullptr, NN, 96, 128, 1, 1);
  cvt_bf16<<<(NN * HID / 4 + 255) / 256, 256, 0, stream>>>(h, hbf, NN * HID / 4);

  for (int l = 0; l < NL; ++l) {
    gate_cb<<<1, 128, 0, stream>>>(relgate + l * NR, convb + (size_t)l * NR * HID, gate, cb);
    hipMemsetAsync(hmsg, 0, (size_t)NN * HID * 4, stream);
    for (int r = 0; r < NR; ++r) {
      int lr = l * NR + r;
      for (int hp = 0; hp < passes; ++hp) {
        int hpBase = hp * HP;
        const unsigned short* wl = linlwb + ((size_t)lr * 512 + hpBase * 128) * 128;
        const unsigned short* wr = linrwb + ((size_t)lr * 512 + hpBase * 128) * 128;
        const float* bl = linlb + (size_t)lr * 512 + hpBase * 128;
        const float* br = linrb + (size_t)lr * 512 + hpBase * 128;
        gemm_bf16<<<8 * RPX * HP, 256, 0, stream>>>(hbf, wl, bl, nullptr, xlb,
                                                    NN, 128, stride, 0, HP);
        gemm_rows<<<NB * HP, 256, 0, stream>>>(hbf, hotlist + (size_t)r * NN, nhot + r,
                                               wr, br, xrh, 128, stride, HP);
        edge_fused<<<8192, 256, 0, stream>>>(
            csroff, rsrc, eacsr, relemb + (size_t)lr * RED,
            linew + ((size_t)lr * 512 + hpBase * 128) * 24,
            attw + (size_t)lr * 512 + hpBase * 128,
            xlb, xrh, hotidx, hmsg, gate, r, HP, stride);
      }
    }
    add_ln<<<(NN + 3) / 4, 256, 0, stream>>>(h, hmsg, cb, n1w + l * HID, n1b + l * HID, hbf, NN);
    gemm_bf16<<<8 * RPX * 2, 256, 0, stream>>>(hbf, f1wb + (size_t)l * 256 * 128,
                                               f1bias + (size_t)l * 256, nullptr, f1buf,
                                               NN, 128, 256, 1, 2);
    gemm_bf16<<<8 * RPX, 256, 0, stream>>>(f1buf, f2wb + (size_t)l * 128 * 256,
                                           f2bias + (size_t)l * 128, hmsg, nullptr,
                                           NN, 256, 128, 0, 1);
    add_ln<<<(NN + 3) / 4, 256, 0, stream>>>(h, hmsg, nullptr, n2w + l * HID, n2b + l * HID, hbf, NN);
  }

  hipMemsetAsync(rcnt, 0, (size_t)(NG + NG * HID * 2) * 4, stream);
  readout_partial<<<NB, 128, 0, stream>>>(h, batch, rcnt, rsum, rmaxk);
  readout_final<<<NG, 256, 0, stream>>>(rcnt, rsum, rmaxk, rnw, rnb, g);
  kan1<<<NG, 128, 0, stream>>>(g, bw1, sw1, sc1, grid1, z);
  kan2<<<NG, 128, 0, stream>>>(z, bw2, sw2, sc2, grid2, out);
}

// Round 11
// 1878.313 us; speedup vs baseline: 5.7626x; 1.0278x over previous
//
#include <hip/hip_runtime.h>
#include <math.h>

#define NN 50000
#define NE 120000
#define FN 64
#define NEA 16
#define NR 4
#define NH 4
#define HID 128
#define NL 3
#define IDE 32
#define RED 8
#define NG 64
#define NC 10
#define KH 128
#define FFH 256
#define NBIN (NR * NN)
#define SCAN_BLK ((NBIN + 1023) / 1024)

typedef short bf16x8 __attribute__((ext_vector_type(8)));
typedef float f32x4 __attribute__((ext_vector_type(4)));

__device__ __forceinline__ unsigned short f2b(float f) {
  unsigned u = __float_as_uint(f);
  unsigned r = (u + 0x7FFFu + ((u >> 16) & 1u)) >> 16;
  return (unsigned short)r;
}
__device__ __forceinline__ float b2f(unsigned short b) {
  return __uint_as_float((unsigned)b << 16);
}
__device__ __forceinline__ unsigned fkey(float f) {
  unsigned u = __float_as_uint(f);
  return (u & 0x80000000u) ? ~u : (u | 0x80000000u);
}
__device__ __forceinline__ float unkey(unsigned k) {
  unsigned u = (k & 0x80000000u) ? (k ^ 0x80000000u) : ~k;
  return __uint_as_float(u);
}

__global__ void cvt_bf16(const float* __restrict__ s, unsigned short* __restrict__ d, int n4) {
  int i = blockIdx.x * blockDim.x + threadIdx.x;
  if (i >= n4) return;
  float4 v = ((const float4*)s)[i];
  ushort4 o;
  o.x = f2b(v.x); o.y = f2b(v.y); o.z = f2b(v.z); o.w = f2b(v.w);
  ((ushort4*)d)[i] = o;
}

// ---- GEMM core: 128x128 tile, optional A-row gather, LDS-staged bf16 epilogue ----
__device__ __forceinline__ void gemm_core(
    char* smem, const unsigned short* __restrict__ A, const int* __restrict__ rowlist,
    const unsigned short* __restrict__ W,
    const float* __restrict__ bias, float* __restrict__ Cf, unsigned short* __restrict__ Cb,
    int nrows, int K, int mout, int act, int rowBase, int colBase) {
  unsigned short (*As)[40] = (unsigned short (*)[40])smem;
  unsigned short (*Ws)[40] = (unsigned short (*)[40])(smem + 10240);
  int t = threadIdx.x;
  int lane = t & 63, w = t >> 6;
  int wm = w >> 1, wn = w & 1;
  int q = lane >> 4, mr = lane & 15;
  f32x4 acc[4][4] = {};
  for (int k0 = 0; k0 < K; k0 += 32) {
#pragma unroll
    for (int half = 0; half < 2; ++half) {
      int c = t + half * 256;
      int row = c >> 2, c16 = c & 3;
      int gr = rowBase + row;
      bf16x8 av = {0, 0, 0, 0, 0, 0, 0, 0};
      if (gr < nrows) {
        int ar = rowlist ? rowlist[gr] : gr;
        av = *(const bf16x8*)(A + (size_t)ar * K + k0 + c16 * 8);
      }
      *(bf16x8*)&As[row][c16 * 8] = av;
      bf16x8 wv = *(const bf16x8*)(W + (size_t)(colBase + row) * K + k0 + c16 * 8);
      *(bf16x8*)&Ws[row][c16 * 8] = wv;
    }
    __syncthreads();
    bf16x8 af[4], bfr[4];
#pragma unroll
    for (int mt = 0; mt < 4; ++mt) af[mt] = *(const bf16x8*)&As[wm * 64 + mt * 16 + mr][q * 8];
#pragma unroll
    for (int nt = 0; nt < 4; ++nt) bfr[nt] = *(const bf16x8*)&Ws[wn * 64 + nt * 16 + mr][q * 8];
#pragma unroll
    for (int mt = 0; mt < 4; ++mt)
#pragma unroll
      for (int nt = 0; nt < 4; ++nt)
        acc[mt][nt] = __builtin_amdgcn_mfma_f32_16x16x32_bf16(af[mt], bfr[nt], acc[mt][nt], 0, 0, 0);
    __syncthreads();
  }
  if (Cb) {
    unsigned short (*Es)[136] = (unsigned short (*)[136])smem;
#pragma unroll
    for (int ph = 0; ph < 2; ++ph) {
      if (wm == ph) {
#pragma unroll
        for (int mt = 0; mt < 4; ++mt)
#pragma unroll
          for (int nt = 0; nt < 4; ++nt)
#pragma unroll
            for (int r = 0; r < 4; ++r) {
              float v = acc[mt][nt][r] + bias[colBase + wn * 64 + nt * 16 + mr];
              if (act) v = v / (1.f + expf(-v));
              Es[mt * 16 + q * 4 + r][wn * 64 + nt * 16 + mr] = f2b(v);
            }
      }
      __syncthreads();
      int rl = t >> 2, co = (t & 3) * 32;
      int grow = rowBase + ph * 64 + rl;
      if (grow < nrows) {
        unsigned short* dst = Cb + (size_t)grow * mout + colBase + co;
#pragma unroll
        for (int j = 0; j < 4; ++j)
          *(bf16x8*)(dst + j * 8) = *(const bf16x8*)&Es[rl][co + j * 8];
      }
      __syncthreads();
    }
  } else {
#pragma unroll
    for (int mt = 0; mt < 4; ++mt)
#pragma unroll
      for (int nt = 0; nt < 4; ++nt)
#pragma unroll
        for (int r = 0; r < 4; ++r) {
          int row = rowBase + wm * 64 + mt * 16 + q * 4 + r;
          int col = colBase + wn * 64 + nt * 16 + mr;
          if (row < nrows) {
            float v = acc[mt][nt][r] + bias[col];
            if (act) v = v / (1.f + expf(-v));
            Cf[(size_t)row * mout + col] = v;
          }
        }
  }
}

// XCD-aware full GEMM (dispatch is round-robin over 8 XCDs: bid&7 = XCD)
__global__ __launch_bounds__(256) void gemm_bf16(
    const unsigned short* __restrict__ A, const unsigned short* __restrict__ W,
    const float* __restrict__ bias, float* __restrict__ Cf, unsigned short* __restrict__ Cb,
    int nrows, int K, int mout, int act, int ncol) {
  __shared__ char smem[20480];
  int nbr = (nrows + 127) >> 7;
  int rpx = (nbr + 7) >> 3;
  int xcd = blockIdx.x & 7, j = blockIdx.x >> 3;
  int rowT = xcd * rpx + j / ncol;
  int cy = j - (j / ncol) * ncol;
  if (rowT >= nbr) return;
  gemm_core(smem, A, nullptr, W, bias, Cf, Cb, nrows, K, mout, act, rowT * 128, cy * 128);
}

// row-gather GEMM over device-side row count (xr for deg>=2 dsts only)
__global__ __launch_bounds__(256) void gemm_rows(
    const unsigned short* __restrict__ A, const int* __restrict__ rowlist,
    const int* __restrict__ nrowsp, const unsigned short* __restrict__ W,
    const float* __restrict__ bias, unsigned short* __restrict__ Cb,
    int K, int mout, int ncol) {
  __shared__ char smem[20480];
  int nrows = *nrowsp;
  int bid = blockIdx.x;
  int rowT = bid / ncol, cy = bid - rowT * ncol;
  if (rowT * 128 >= nrows) return;
  gemm_core(smem, A, rowlist, W, bias, nullptr, Cb, nrows, K, mout, 0, rowT * 128, cy * 128);
}

__global__ void build_xin_bf(const float* __restrict__ x, const int* __restrict__ idtok,
                             const float* __restrict__ emb, unsigned short* __restrict__ xin) {
  int i = blockIdx.x * blockDim.x + threadIdx.x;
  if (i >= NN * 96) return;
  int n = i / 96, k = i - n * 96;
  float v = (k < FN) ? x[(size_t)n * FN + k] : emb[(size_t)idtok[n] * IDE + (k - FN)];
  xin[i] = f2b(v);
}

// ---- CSR by (rel, dst) ----
__global__ void hist_bin(const int* __restrict__ ei, const int* __restrict__ et,
                         int* __restrict__ bcnt) {
  int e = blockIdx.x * blockDim.x + threadIdx.x;
  if (e >= NE) return;
  atomicAdd(&bcnt[et[e] * NN + ei[NE + e]], 1);
}
__global__ __launch_bounds__(256) void scan1(const int* __restrict__ cnt,
                                             int* __restrict__ csroff, int* __restrict__ bsum) {
  __shared__ int lds[256];
  int b = blockIdx.x, t = threadIdx.x;
  int base = b * 1024 + t * 4;
  int v[4];
#pragma unroll
  for (int j = 0; j < 4; ++j) v[j] = (base + j < NBIN) ? cnt[base + j] : 0;
  int tot = v[0] + v[1] + v[2] + v[3];
  lds[t] = tot;
  __syncthreads();
  for (int off = 1; off < 256; off <<= 1) {
    int x = (t >= off) ? lds[t - off] : 0;
    __syncthreads();
    lds[t] += x;
    __syncthreads();
  }
  if (t == 255) bsum[b] = lds[255];
  int run = lds[t] - tot;
#pragma unroll
  for (int j = 0; j < 4; ++j) {
    if (base + j < NBIN) csroff[base + j] = run;
    run += v[j];
  }
}
__global__ __launch_bounds__(256) void scan2(int* __restrict__ bsum) {
  __shared__ int lds[256];
  int t = threadIdx.x;
  int v = (t < SCAN_BLK) ? bsum[t] : 0;
  lds[t] = v;
  __syncthreads();
  for (int off = 1; off < 256; off <<= 1) {
    int x = (t >= off) ? lds[t - off] : 0;
    __syncthreads();
    lds[t] += x;
    __syncthreads();
  }
  if (t < SCAN_BLK) bsum[t] = lds[t] - v;
}
__global__ void scan3(int* __restrict__ csroff, const int* __restrict__ bsum) {
  int i = blockIdx.x * blockDim.x + threadIdx.x;
  if (i < NBIN) csroff[i] += bsum[i >> 10];
  if (i == 0) csroff[NBIN] = NE;
}
__global__ void scatter_bin(const int* __restrict__ ei, const int* __restrict__ et,
                            const int* __restrict__ csroff, int* __restrict__ cur,
                            int* __restrict__ elist) {
  int e = blockIdx.x * blockDim.x + threadIdx.x;
  if (e >= NE) return;
  int bin = et[e] * NN + ei[NE + e];
  int p = atomicAdd(&cur[bin], 1);
  elist[csroff[bin] + p] = e;
}
__global__ void gather_edge(const int* __restrict__ ei, const int* __restrict__ elist,
                            const float* __restrict__ eattr,
                            int* __restrict__ rsrc, float* __restrict__ eacsr) {
  int p = blockIdx.x * blockDim.x + threadIdx.x;
  if (p >= NE) return;
  int e = elist[p];
  rsrc[p] = ei[e];
  const float4* s = (const float4*)(eattr + (size_t)e * NEA);
  float4* d = (float4*)(eacsr + (size_t)p * NEA);
#pragma unroll
  for (int j = 0; j < 4; ++j) d[j] = s[j];
}
// per rel: worklist (deg>=1 dsts), hotlist (deg>=2 dsts for xr gemm), hotidx.
// ballot-aggregated (returning atomics serialize!)
__global__ void build_hot(const int* __restrict__ csroff, int* __restrict__ nhot,
                          int* __restrict__ nwork, int* __restrict__ hotlist,
                          int* __restrict__ hotidx, int* __restrict__ worklist) {
  int b = blockIdx.x * blockDim.x + threadIdx.x;
  bool valid = b < NBIN;
  int cnt = 0, rel = -1;
  if (valid) { cnt = csroff[b + 1] - csroff[b]; rel = b / NN; }
  bool ne = valid && cnt >= 1;
  bool hot = valid && cnt >= 2;
  int lane = threadIdx.x & 63;
  int idx = -1;
  for (int rr = 0; rr < NR; ++rr) {
    unsigned long long mw = __ballot(ne && rel == rr);
    if (mw != 0ull) {
      int leader = __ffsll((unsigned long long)mw) - 1;
      int base = 0;
      if (lane == leader) base = atomicAdd(&nwork[rr], __popcll(mw));
      base = __shfl(base, leader, 64);
      if (ne && rel == rr) {
        unsigned long long below = mw & ((1ull << lane) - 1ull);
        worklist[rr * NN + base + __popcll(below)] = b - rr * NN;
      }
    }
    unsigned long long mh = __ballot(hot && rel == rr);
    if (mh != 0ull) {
      int leader = __ffsll((unsigned long long)mh) - 1;
      int base = 0;
      if (lane == leader) base = atomicAdd(&nhot[rr], __popcll(mh));
      base = __shfl(base, leader, 64);
      if (hot && rel == rr) {
        unsigned long long below = mh & ((1ull << lane) - 1ull);
        int pos = base + __popcll(below);
        hotlist[rr * NN + pos] = b - rr * NN;
        idx = pos;
      }
    }
  }
  if (valid) hotidx[b] = idx;
}

__global__ void gate_cb(const float* __restrict__ rg, const float* __restrict__ cbias,
                        float* __restrict__ gate, float* __restrict__ cb) {
  __shared__ float g[NR];
  int t = threadIdx.x;
  if (t == 0) {
    float mx = rg[0];
    for (int r = 1; r < NR; ++r) mx = fmaxf(mx, rg[r]);
    float s = 0.f, tmp[NR];
    for (int r = 0; r < NR; ++r) { tmp[r] = expf(rg[r] - mx); s += tmp[r]; }
    for (int r = 0; r < NR; ++r) { g[r] = tmp[r] / s; gate[r] = g[r]; }
  }
  __syncthreads();
  float c = 0.f;
  for (int r = 0; r < NR; ++r) c += g[r] * cbias[r * HID + t];
  cb[t] = c;
}

// ---- fused edge pass over non-empty worklist. deg-1 (majority): weight==1
// exactly -> direct gather-sum, no LDS/sync. deg>=2: online softmax. ----
__global__ __launch_bounds__(256) void edge_fused(
    const int* __restrict__ csroff, const int* __restrict__ rsrc,
    const float* __restrict__ eacsr, const float* __restrict__ relembp,
    const float* __restrict__ wedgep, const float* __restrict__ attwp,
    const unsigned short* __restrict__ xlb, const unsigned short* __restrict__ xrh,
    const int* __restrict__ hotidx, const int* __restrict__ worklist,
    const int* __restrict__ nwork, float* __restrict__ hmsg,
    const float* __restrict__ gate, int rel, int HP, int stride) {
  __shared__ float lds[4][128];
  int wave = threadIdx.x >> 6, lane = threadIdx.x & 63;
  bool act = wave < HP;
  int hh = act ? wave : 0;
  float wreg[2][24], areg[2];
#pragma unroll
  for (int j = 0; j < 2; ++j) {
    int col = hh * 128 + j * 64 + lane;
    const float* wp = wedgep + (size_t)col * 24;
#pragma unroll
    for (int k = 0; k < 24; ++k) wreg[j][k] = wp[k];
    areg[j] = attwp[col];
  }
  float evr0 = 0.f, evr1 = 0.f;
#pragma unroll
  for (int k = 0; k < 8; ++k) {
    float rk = relembp[k];
    evr0 += rk * wreg[0][NEA + k];
    evr1 += rk * wreg[1][NEA + k];
  }
  float g4 = gate[rel] * 0.25f;
  int nw = nwork[rel];
  for (int wi = blockIdx.x; wi < nw; wi += gridDim.x) {
    int dst = worklist[rel * NN + wi];
    int s = csroff[rel * NN + dst], e = csroff[rel * NN + dst + 1];
    int cnt = e - s;
    if (cnt == 1) {
      // waves 0,1 handle the 128 dims directly; no LDS, no barriers
      if (wave < 2) {
        int src = rsrc[s];
        int d = wave * 64 + lane;
        const unsigned short* xp = xlb + (size_t)src * stride;
        float v = 0.f;
        for (int h = 0; h < HP; ++h) v += b2f(xp[h * 128 + d]);
        hmsg[(size_t)dst * HID + d] += g4 * v;
      }
    } else {
      float o0 = 0.f, o1 = 0.f;
      if (act) {
        int hi = hotidx[rel * NN + dst];
        const unsigned short* xrp = xrh + (size_t)hi * stride;
        float xr0 = b2f(xrp[hh * 128 + lane]);
        float xr1 = b2f(xrp[hh * 128 + 64 + lane]);
        float m = -3.4e38f, den = 0.f, acc0 = 0.f, acc1 = 0.f;
        for (int p = s; p < e; ++p) {
          int src = rsrc[p];
          const float* eap = eacsr + (size_t)p * NEA;
          float er[NEA];
#pragma unroll
          for (int k = 0; k < NEA; ++k) er[k] = eap[k];
          float eev0 = evr0, eev1 = evr1;
#pragma unroll
          for (int k = 0; k < NEA; ++k) { eev0 += er[k] * wreg[0][k]; eev1 += er[k] * wreg[1][k]; }
          float xl0 = b2f(xlb[(size_t)src * stride + hh * 128 + lane]);
          float xl1 = b2f(xlb[(size_t)src * stride + hh * 128 + 64 + lane]);
          float s0 = xl0 + xr0 + eev0; s0 = (s0 > 0.f) ? s0 : 0.2f * s0;
          float s1 = xl1 + xr1 + eev1; s1 = (s1 > 0.f) ? s1 : 0.2f * s1;
          float lg = s0 * areg[0] + s1 * areg[1];
#pragma unroll
          for (int o = 32; o > 0; o >>= 1) lg += __shfl_xor(lg, o, 64);
          float mn = fmaxf(m, lg);
          float sc = expf(m - mn);
          float ex = expf(lg - mn);
          den = den * sc + ex;
          acc0 = acc0 * sc + ex * xl0;
          acc1 = acc1 * sc + ex * xl1;
          m = mn;
        }
        float w = g4 / den;
        o0 = acc0 * w;
        o1 = acc1 * w;
        lds[wave][lane] = o0;
        lds[wave][64 + lane] = o1;
      }
      __syncthreads();
      if (wave < 2) {
        int d = wave * 64 + lane;
        float v = 0.f;
        for (int h = 0; h < HP; ++h) v += lds[h][d];
        hmsg[(size_t)dst * HID + d] += v;
      }
      __syncthreads();
    }
  }
}

// ---- h = layernorm(h + add (+ cb)); also emits bf16 copy ----
__global__ __launch_bounds__(256) void add_ln(
    float* __restrict__ h, const float* __restrict__ add, const float* __restrict__ cb,
    const float* __restrict__ w, const float* __restrict__ b,
    unsigned short* __restrict__ hbf, int nrows) {
  int wave = threadIdx.x >> 6, lane = threadIdx.x & 63;
  int row = blockIdx.x * 4 + wave;
  if (row >= nrows) return;
  size_t base = (size_t)row * HID;
  float x0 = h[base + lane] + add[base + lane];
  float x1 = h[base + 64 + lane] + add[base + 64 + lane];
  if (cb) { x0 += cb[lane]; x1 += cb[64 + lane]; }
  float s = x0 + x1;
#pragma unroll
  for (int o = 32; o > 0; o >>= 1) s += __shfl_xor(s, o, 64);
  float mean = s * (1.f / 128.f);
  float d0 = x0 - mean, d1 = x1 - mean;
  float v = d0 * d0 + d1 * d1;
#pragma unroll
  for (int o = 32; o > 0; o >>= 1) v += __shfl_xor(v, o, 64);
  float inv = 1.f / sqrtf(v * (1.f / 128.f) + 1e-5f);
  float y0 = d0 * inv * w[lane] + b[lane];
  float y1 = d1 * inv * w[64 + lane] + b[64 + lane];
  h[base + lane] = y0;
  h[base + 64 + lane] = y1;
  hbf[base + lane] = f2b(y0);
  hbf[base + 64 + lane] = f2b(y1);
}

// ---- readout ----
__global__ __launch_bounds__(128) void readout_partial(
    const float* __restrict__ h, const int* __restrict__ batch,
    float* __restrict__ cnt, float* __restrict__ sum, unsigned* __restrict__ maxk) {
  int t = threadIdx.x;
  int r0 = blockIdx.x * 128;
  int r1 = min(r0 + 128, NN);
  int curg = batch[r0];
  float acc = 0.f, mx = -3.4e38f;
  int c = 0;
  for (int row = r0; row < r1; ++row) {
    int g = batch[row];
    if (g != curg) {
      atomicAdd(sum + (size_t)curg * HID + t, acc);
      atomicMax(maxk + (size_t)curg * HID + t, fkey(mx));
      if (t == 0) atomicAdd(cnt + curg, (float)c);
      acc = 0.f; mx = -3.4e38f; c = 0; curg = g;
    }
    float v = h[(size_t)row * HID + t];
    acc += v;
    mx = fmaxf(mx, v);
    ++c;
  }
  atomicAdd(sum + (size_t)curg * HID + t, acc);
  atomicMax(maxk + (size_t)curg * HID + t, fkey(mx));
  if (t == 0) atomicAdd(cnt + curg, (float)c);
}

__global__ __launch_bounds__(256) void readout_final(
    const float* __restrict__ cnt, const float* __restrict__ sum,
    const unsigned* __restrict__ maxk, const float* __restrict__ w,
    const float* __restrict__ b, float* __restrict__ g) {
  int bg = blockIdx.x, t = threadIdx.x;
  __shared__ float red[256];
  float c = fmaxf(cnt[bg], 1.f);
  float x = (t < HID) ? sum[(size_t)bg * HID + t] / c
                      : unkey(maxk[(size_t)bg * HID + (t - HID)]);
  red[t] = x;
  __syncthreads();
  for (int s = 128; s > 0; s >>= 1) {
    if (t < s) red[t] += red[t + s];
    __syncthreads();
  }
  float mean = red[0] * (1.f / 256.f);
  __syncthreads();
  float d = x - mean;
  red[t] = d * d;
  __syncthreads();
  for (int s = 128; s > 0; s >>= 1) {
    if (t < s) red[t] += red[t + s];
    __syncthreads();
  }
  float inv = 1.f / sqrtf(red[0] * (1.f / 256.f) + 1e-5f);
  g[(size_t)bg * 256 + t] = d * inv * w[t] + b[t];
}

__device__ __forceinline__ void bspline8(float x, const float* __restrict__ t,
                                         float* __restrict__ out) {
  float bs[11];
#pragma unroll
  for (int j = 0; j < 11; ++j) bs[j] = (x >= t[j] && x < t[j + 1]) ? 1.f : 0.f;
#pragma unroll
  for (int k = 1; k <= 3; ++k) {
    for (int j = 0; j < 11 - k; ++j) {
      bs[j] = (x - t[j]) / (t[j + k] - t[j]) * bs[j] +
              (t[j + k + 1] - x) / (t[j + k + 1] - t[j + 1]) * bs[j + 1];
    }
  }
#pragma unroll
  for (int j = 0; j < 8; ++j) out[j] = bs[j];
}

// ---- KAN1, K-chunked: grid (64 groups, 8 chunks of 32 inputs). z must be 0. ----
__global__ __launch_bounds__(128) void kan1_part(
    const float* __restrict__ g, const float* __restrict__ bw,
    const float* __restrict__ sw, const float* __restrict__ sc,
    const float* __restrict__ grid, float* __restrict__ z) {
  int bg = blockIdx.x, ch = blockIdx.y, t = threadIdx.x;
  int base = ch * 32;
  __shared__ float B[32][8];
  __shared__ float sg[32];
  if (t < 32) {
    float x = g[(size_t)bg * 256 + base + t];
    sg[t] = x / (1.f + expf(-x));
    bspline8(x, grid + (size_t)(base + t) * 12, B[t]);
  }
  __syncthreads();
  float acc = 0.f;
  for (int i = 0; i < 32; ++i) {
    int col = base + i;
    acc += sg[i] * bw[(size_t)t * 256 + col];
    const float* swp = sw + ((size_t)t * 256 + col) * 8;
    float sp = 0.f;
#pragma unroll
    for (int k = 0; k < 8; ++k) sp += B[i][k] * swp[k];
    acc += sp * sc[(size_t)t * 256 + col];
  }
  atomicAdd(z + (size_t)bg * KH + t, acc);
}

__global__ __launch_bounds__(128) void kan2(
    const float* __restrict__ z, const float* __restrict__ bw,
    const float* __restrict__ sw, const float* __restrict__ sc,
    const float* __restrict__ grid, float* __restrict__ out) {
  int bg = blockIdx.x, t = threadIdx.x;
  __shared__ float B[128][8];
  __shared__ float sz[128];
  float x = z[(size_t)bg * KH + t];
  sz[t] = x / (1.f + expf(-x));
  bspline8(x, grid + (size_t)t * 12, B[t]);
  __syncthreads();
  if (t < NC) {
    float acc = 0.f;
    for (int i = 0; i < 128; ++i) {
      acc += sz[i] * bw[(size_t)t * 128 + i];
      const float* swp = sw + ((size_t)t * 128 + i) * 8;
      float sp = 0.f;
#pragma unroll
      for (int k = 0; k < 8; ++k) sp += B[i][k] * swp[k];
      acc += sp * sc[(size_t)t * 128 + i];
    }
    out[(size_t)bg * NC + t] = acc;
  }
}

extern "C" void kernel_launch(void* const* d_in, const int* in_sizes, int n_in,
                              void* d_out, int out_size, void* d_ws, size_t ws_size,
                              hipStream_t stream) {
  const float* x       = (const float*)d_in[0];
  const float* eattr   = (const float*)d_in[1];
  const int*   idtok   = (const int*)d_in[2];
  const int*   ei      = (const int*)d_in[3];
  const int*   etype   = (const int*)d_in[4];
  const int*   batch   = (const int*)d_in[5];
  const float* idemb   = (const float*)d_in[6];
  const float* inw     = (const float*)d_in[7];
  const float* inb     = (const float*)d_in[8];
  const float* relemb  = (const float*)d_in[9];
  const float* linlw   = (const float*)d_in[10];
  const float* linlb   = (const float*)d_in[11];
  const float* linrw   = (const float*)d_in[12];
  const float* linrb   = (const float*)d_in[13];
  const float* linew   = (const float*)d_in[14];
  const float* attw    = (const float*)d_in[15];
  const float* convb   = (const float*)d_in[16];
  const float* relgate = (const float*)d_in[17];
  const float* n1w     = (const float*)d_in[18];
  const float* n1b     = (const float*)d_in[19];
  const float* n2w     = (const float*)d_in[20];
  const float* n2b     = (const float*)d_in[21];
  const float* f1w     = (const float*)d_in[22];
  const float* f1bias  = (const float*)d_in[23];
  const float* f2w     = (const float*)d_in[24];
  const float* f2bias  = (const float*)d_in[25];
  const float* rnw     = (const float*)d_in[26];
  const float* rnb     = (const float*)d_in[27];
  const float* bw1     = (const float*)d_in[28];
  const float* sw1     = (const float*)d_in[29];
  const float* sc1     = (const float*)d_in[30];
  const float* grid1   = (const float*)d_in[31];
  const float* bw2     = (const float*)d_in[32];
  const float* sw2     = (const float*)d_in[33];
  const float* sc2     = (const float*)d_in[34];
  const float* grid2   = (const float*)d_in[35];
  float* out = (float*)d_out;
  (void)in_sizes; (void)n_in; (void)out_size;

  auto needed = [](int HP) -> size_t {
    auto al = [](size_t b) { return (b + 255) & ~(size_t)255; };
    size_t o = 0;
    o += al((size_t)NN * HID * 4) * 2;            // h, hmsg
    o += al((size_t)NN * HID * 2);                // hbf
    o += al((size_t)NN * 128 * HP * 2) * 2;       // xlb, xrh
    o += al((size_t)NE * 4) * 2;                  // elist, rsrc
    o += al((size_t)NE * NEA * 4);                // eacsr
    o += al((size_t)NBIN * 8 + 8);                // bcnt+cur
    o += al((size_t)(NBIN + 1) * 4);              // csroff
    o += al((size_t)SCAN_BLK * 4);                // bsum
    o += al((size_t)NR * NN * 4) * 2;             // hotlist, worklist
    o += al((size_t)NBIN * 4);                    // hotidx
    o += al(64);                                  // nhot+nwork
    o += al((size_t)NL * NR * 512 * 128 * 2) * 2; // linlwb, linrwb
    o += al((size_t)NL * 256 * 128 * 2) * 2;      // f1wb, f2wb
    o += al((size_t)128 * 96 * 2);                // inwb
    o += al(NR * 4) + al(HID * 4);
    o += al((size_t)(NG + NG * HID * 2) * 4);
    o += al((size_t)NG * 256 * 4) + al((size_t)NG * KH * 4);
    return o;
  };
  const int HP = (needed(4) <= ws_size) ? 4 : 2;
  const int passes = NH / HP;
  const int stride = HP * 128;

  char* p = (char*)d_ws;
  auto alloc = [&](size_t bytes) { void* q = (void*)p; p += (bytes + 255) & ~(size_t)255; return q; };
  float* h    = (float*)alloc((size_t)NN * HID * 4);
  float* hmsg = (float*)alloc((size_t)NN * HID * 4);
  unsigned short* hbf = (unsigned short*)alloc((size_t)NN * HID * 2);
  unsigned short* xlb = (unsigned short*)alloc((size_t)NN * 128 * HP * 2);
  unsigned short* xrh = (unsigned short*)alloc((size_t)NN * 128 * HP * 2);
  int* elist = (int*)alloc((size_t)NE * 4);
  int* rsrc  = (int*)alloc((size_t)NE * 4);
  float* eacsr = (float*)alloc((size_t)NE * NEA * 4);
  int* bcnt  = (int*)alloc((size_t)NBIN * 8 + 8);
  int* cur   = bcnt + NBIN;
  int* csroff = (int*)alloc((size_t)(NBIN + 1) * 4);
  int* bsum  = (int*)alloc((size_t)SCAN_BLK * 4);
  int* hotlist  = (int*)alloc((size_t)NR * NN * 4);
  int* worklist = (int*)alloc((size_t)NR * NN * 4);
  int* hotidx   = (int*)alloc((size_t)NBIN * 4);
  int* nhot     = (int*)alloc(64);   // nhot[0..3], nwork[8..11]
  int* nwork    = nhot + 8;
  unsigned short* linlwb = (unsigned short*)alloc((size_t)NL * NR * 512 * 128 * 2);
  unsigned short* linrwb = (unsigned short*)alloc((size_t)NL * NR * 512 * 128 * 2);
  unsigned short* f1wb   = (unsigned short*)alloc((size_t)NL * 256 * 128 * 2);
  unsigned short* f2wb   = (unsigned short*)alloc((size_t)NL * 128 * 256 * 2);
  unsigned short* inwb   = (unsigned short*)alloc((size_t)128 * 96 * 2);
  float* gate = (float*)alloc(NR * 4);
  float* cb   = (float*)alloc(HID * 4);
  float* rcnt = (float*)alloc((size_t)(NG + NG * HID * 2) * 4);
  float* rsum = rcnt + NG;
  unsigned* rmaxk = (unsigned*)(rsum + (size_t)NG * HID);
  float* g = (float*)alloc((size_t)NG * 256 * 4);
  float* z = (float*)alloc((size_t)NG * KH * 4);
  unsigned short* xinbf = xlb;
  unsigned short* f1buf = xlb;

  const int NB = (NN + 127) / 128;
  const int RPX = (NB + 7) / 8;

  {
    int n;
    n = NL * NR * 512 * 128 / 4;
    cvt_bf16<<<(n + 255) / 256, 256, 0, stream>>>(linlw, linlwb, n);
    cvt_bf16<<<(n + 255) / 256, 256, 0, stream>>>(linrw, linrwb, n);
    n = NL * 256 * 128 / 4;
    cvt_bf16<<<(n + 255) / 256, 256, 0, stream>>>(f1w, f1wb, n);
    cvt_bf16<<<(n + 255) / 256, 256, 0, stream>>>(f2w, f2wb, n);
    n = 128 * 96 / 4;
    cvt_bf16<<<(n + 255) / 256, 256, 0, stream>>>(inw, inwb, n);
  }

  hipMemsetAsync(bcnt, 0, (size_t)NBIN * 8 + 8, stream);
  hipMemsetAsync(nhot, 0, 64, stream);
  hist_bin<<<(NE + 255) / 256, 256, 0, stream>>>(ei, etype, bcnt);
  scan1<<<SCAN_BLK, 256, 0, stream>>>(bcnt, csroff, bsum);
  scan2<<<1, 256, 0, stream>>>(bsum);
  scan3<<<(NBIN + 256) / 256, 256, 0, stream>>>(csroff, bsum);
  scatter_bin<<<(NE + 255) / 256, 256, 0, stream>>>(ei, etype, csroff, cur, elist);
  gather_edge<<<(NE + 255) / 256, 256, 0, stream>>>(ei, elist, eattr, rsrc, eacsr);
  build_hot<<<(NBIN + 255) / 256, 256, 0, stream>>>(csroff, nhot, nwork, hotlist, hotidx, worklist);

  build_xin_bf<<<(NN * 96 + 255) / 256, 256, 0, stream>>>(x, idtok, idemb, xinbf);
  gemm_bf16<<<8 * RPX, 256, 0, stream>>>(xinbf, inwb, inb, h, nullptr, NN, 96, 128, 1, 1);
  cvt_bf16<<<(NN * HID / 4 + 255) / 256, 256, 0, stream>>>(h, hbf, NN * HID / 4);

  for (int l = 0; l < NL; ++l) {
    gate_cb<<<1, 128, 0, stream>>>(relgate + l * NR, convb + (size_t)l * NR * HID, gate, cb);
    hipMemsetAsync(hmsg, 0, (size_t)NN * HID * 4, stream);
    for (int r = 0; r < NR; ++r) {
      int lr = l * NR + r;
      for (int hp = 0; hp < passes; ++hp) {
        int hpBase = hp * HP;
        const unsigned short* wl = linlwb + ((size_t)lr * 512 + hpBase * 128) * 128;
        const unsigned short* wr = linrwb + ((size_t)lr * 512 + hpBase * 128) * 128;
        const float* bl = linlb + (size_t)lr * 512 + hpBase * 128;
        const float* br = linrb + (size_t)lr * 512 + hpBase * 128;
        gemm_bf16<<<8 * RPX * HP, 256, 0, stream>>>(hbf, wl, bl, nullptr, xlb,
                                                    NN, 128, stride, 0, HP);
        gemm_rows<<<NB * HP, 256, 0, stream>>>(hbf, hotlist + (size_t)r * NN, nhot + r,
                                               wr, br, xrh, 128, stride, HP);
        edge_fused<<<8192, 256, 0, stream>>>(
            csroff, rsrc, eacsr, relemb + (size_t)lr * RED,
            linew + ((size_t)lr * 512 + hpBase * 128) * 24,
            attw + (size_t)lr * 512 + hpBase * 128,
            xlb, xrh, hotidx, worklist, nwork, hmsg, gate, r, HP, stride);
      }
    }
    add_ln<<<(NN + 3) / 4, 256, 0, stream>>>(h, hmsg, cb, n1w + l * HID, n1b + l * HID, hbf, NN);
    gemm_bf16<<<8 * RPX * 2, 256, 0, stream>>>(hbf, f1wb + (size_t)l * 256 * 128,
                                               f1bias + (size_t)l * 256, nullptr, f1buf,
                                               NN, 128, 256, 1, 2);
    gemm_bf16<<<8 * RPX, 256, 0, stream>>>(f1buf, f2wb + (size_t)l * 128 * 256,
                                           f2bias + (size_t)l * 128, hmsg, nullptr,
                                           NN, 256, 128, 0, 1);
    add_ln<<<(NN + 3) / 4, 256, 0, stream>>>(h, hmsg, nullptr, n2w + l * HID, n2b + l * HID, hbf, NN);
  }

  hipMemsetAsync(rcnt, 0, (size_t)(NG + NG * HID * 2) * 4, stream);
  hipMemsetAsync(z, 0, (size_t)NG * KH * 4, stream);
  readout_partial<<<NB, 128, 0, stream>>>(h, batch, rcnt, rsum, rmaxk);
  readout_final<<<NG, 256, 0, stream>>>(rcnt, rsum, rmaxk, rnw, rnb, g);
  kan1_part<<<dim3(NG, 8), 128, 0, stream>>>(g, bw1, sw1, sc1, grid1, z);
  kan2<<<NG, 128, 0, stream>>>(z, bw2, sw2, sc2, grid2, out);
}

// Round 13
// 1626.967 us; speedup vs baseline: 6.6529x; 1.1545x over previous
//
#include <hip/hip_runtime.h>
#include <math.h>

#define NN 50000
#define NE 120000
#define FN 64
#define NEA 16
#define NR 4
#define NH 4
#define HID 128
#define NL 3
#define IDE 32
#define RED 8
#define NG 64
#define NC 10
#define KH 128
#define FFH 256
#define NBIN (NR * NN)
#define SCAN_BLK ((NBIN + 1023) / 1024)

typedef short bf16x8 __attribute__((ext_vector_type(8)));
typedef float f32x4 __attribute__((ext_vector_type(4)));

__device__ __forceinline__ unsigned short f2b(float f) {
  unsigned u = __float_as_uint(f);
  unsigned r = (u + 0x7FFFu + ((u >> 16) & 1u)) >> 16;
  return (unsigned short)r;
}
__device__ __forceinline__ float b2f(unsigned short b) {
  return __uint_as_float((unsigned)b << 16);
}

__global__ void cvt_bf16(const float* __restrict__ s, unsigned short* __restrict__ d, int n4) {
  int i = blockIdx.x * blockDim.x + threadIdx.x;
  if (i >= n4) return;
  float4 v = ((const float4*)s)[i];
  ushort4 o;
  o.x = f2b(v.x); o.y = f2b(v.y); o.z = f2b(v.z); o.w = f2b(v.w);
  ((ushort4*)d)[i] = o;
}

// ---- GEMM core: 128x128 tile, optional A-row gather, LDS-staged bf16 epilogue ----
__device__ __forceinline__ void gemm_core(
    char* smem, const unsigned short* __restrict__ A, const int* __restrict__ rowlist,
    const unsigned short* __restrict__ W,
    const float* __restrict__ bias, float* __restrict__ Cf, unsigned short* __restrict__ Cb,
    int nrows, int K, int mout, int act, int rowBase, int colBase) {
  unsigned short (*As)[40] = (unsigned short (*)[40])smem;
  unsigned short (*Ws)[40] = (unsigned short (*)[40])(smem + 10240);
  int t = threadIdx.x;
  int lane = t & 63, w = t >> 6;
  int wm = w >> 1, wn = w & 1;
  int q = lane >> 4, mr = lane & 15;
  f32x4 acc[4][4] = {};
  for (int k0 = 0; k0 < K; k0 += 32) {
#pragma unroll
    for (int half = 0; half < 2; ++half) {
      int c = t + half * 256;
      int row = c >> 2, c16 = c & 3;
      int gr = rowBase + row;
      bf16x8 av = {0, 0, 0, 0, 0, 0, 0, 0};
      if (gr < nrows) {
        int ar = rowlist ? rowlist[gr] : gr;
        av = *(const bf16x8*)(A + (size_t)ar * K + k0 + c16 * 8);
      }
      *(bf16x8*)&As[row][c16 * 8] = av;
      bf16x8 wv = *(const bf16x8*)(W + (size_t)(colBase + row) * K + k0 + c16 * 8);
      *(bf16x8*)&Ws[row][c16 * 8] = wv;
    }
    __syncthreads();
    bf16x8 af[4], bfr[4];
#pragma unroll
    for (int mt = 0; mt < 4; ++mt) af[mt] = *(const bf16x8*)&As[wm * 64 + mt * 16 + mr][q * 8];
#pragma unroll
    for (int nt = 0; nt < 4; ++nt) bfr[nt] = *(const bf16x8*)&Ws[wn * 64 + nt * 16 + mr][q * 8];
#pragma unroll
    for (int mt = 0; mt < 4; ++mt)
#pragma unroll
      for (int nt = 0; nt < 4; ++nt)
        acc[mt][nt] = __builtin_amdgcn_mfma_f32_16x16x32_bf16(af[mt], bfr[nt], acc[mt][nt], 0, 0, 0);
    __syncthreads();
  }
  if (Cb) {
    unsigned short (*Es)[136] = (unsigned short (*)[136])smem;
#pragma unroll
    for (int ph = 0; ph < 2; ++ph) {
      if (wm == ph) {
#pragma unroll
        for (int mt = 0; mt < 4; ++mt)
#pragma unroll
          for (int nt = 0; nt < 4; ++nt)
#pragma unroll
            for (int r = 0; r < 4; ++r) {
              float v = acc[mt][nt][r] + bias[colBase + wn * 64 + nt * 16 + mr];
              if (act) v = v / (1.f + expf(-v));
              Es[mt * 16 + q * 4 + r][wn * 64 + nt * 16 + mr] = f2b(v);
            }
      }
      __syncthreads();
      int rl = t >> 2, co = (t & 3) * 32;
      int grow = rowBase + ph * 64 + rl;
      if (grow < nrows) {
        unsigned short* dst = Cb + (size_t)grow * mout + colBase + co;
#pragma unroll
        for (int j = 0; j < 4; ++j)
          *(bf16x8*)(dst + j * 8) = *(const bf16x8*)&Es[rl][co + j * 8];
      }
      __syncthreads();
    }
  } else {
#pragma unroll
    for (int mt = 0; mt < 4; ++mt)
#pragma unroll
      for (int nt = 0; nt < 4; ++nt)
#pragma unroll
        for (int r = 0; r < 4; ++r) {
          int row = rowBase + wm * 64 + mt * 16 + q * 4 + r;
          int col = colBase + wn * 64 + nt * 16 + mr;
          if (row < nrows) {
            float v = acc[mt][nt][r] + bias[col];
            if (act) v = v / (1.f + expf(-v));
            Cf[(size_t)row * mout + col] = v;
          }
        }
  }
}

// XCD-aware full GEMM (dispatch is round-robin over 8 XCDs: bid&7 = XCD)
__global__ __launch_bounds__(256) void gemm_bf16(
    const unsigned short* __restrict__ A, const unsigned short* __restrict__ W,
    const float* __restrict__ bias, float* __restrict__ Cf, unsigned short* __restrict__ Cb,
    int nrows, int K, int mout, int act, int ncol) {
  __shared__ char smem[20480];
  int nbr = (nrows + 127) >> 7;
  int rpx = (nbr + 7) >> 3;
  int xcd = blockIdx.x & 7, j = blockIdx.x >> 3;
  int rowT = xcd * rpx + j / ncol;
  int cy = j - (j / ncol) * ncol;
  if (rowT >= nbr) return;
  gemm_core(smem, A, nullptr, W, bias, Cf, Cb, nrows, K, mout, act, rowT * 128, cy * 128);
}

// row-gather GEMM over device-side row count (xr for deg>=2 dsts only)
__global__ __launch_bounds__(256) void gemm_rows(
    const unsigned short* __restrict__ A, const int* __restrict__ rowlist,
    const int* __restrict__ nrowsp, const unsigned short* __restrict__ W,
    const float* __restrict__ bias, unsigned short* __restrict__ Cb,
    int K, int mout, int ncol) {
  __shared__ char smem[20480];
  int nrows = *nrowsp;
  int bid = blockIdx.x;
  int rowT = bid / ncol, cy = bid - rowT * ncol;
  if (rowT * 128 >= nrows) return;
  gemm_core(smem, A, rowlist, W, bias, nullptr, Cb, nrows, K, mout, 0, rowT * 128, cy * 128);
}

__global__ void build_xin_bf(const float* __restrict__ x, const int* __restrict__ idtok,
                             const float* __restrict__ emb, unsigned short* __restrict__ xin) {
  int i = blockIdx.x * blockDim.x + threadIdx.x;
  if (i >= NN * 96) return;
  int n = i / 96, k = i - n * 96;
  float v = (k < FN) ? x[(size_t)n * FN + k] : emb[(size_t)idtok[n] * IDE + (k - FN)];
  xin[i] = f2b(v);
}

// ---- CSR by (rel, dst) ----
__global__ void hist_bin(const int* __restrict__ ei, const int* __restrict__ et,
                         int* __restrict__ bcnt) {
  int e = blockIdx.x * blockDim.x + threadIdx.x;
  if (e >= NE) return;
  atomicAdd(&bcnt[et[e] * NN + ei[NE + e]], 1);
}
__global__ __launch_bounds__(256) void scan1(const int* __restrict__ cnt,
                                             int* __restrict__ csroff, int* __restrict__ bsum) {
  __shared__ int lds[256];
  int b = blockIdx.x, t = threadIdx.x;
  int base = b * 1024 + t * 4;
  int v[4];
#pragma unroll
  for (int j = 0; j < 4; ++j) v[j] = (base + j < NBIN) ? cnt[base + j] : 0;
  int tot = v[0] + v[1] + v[2] + v[3];
  lds[t] = tot;
  __syncthreads();
  for (int off = 1; off < 256; off <<= 1) {
    int x = (t >= off) ? lds[t - off] : 0;
    __syncthreads();
    lds[t] += x;
    __syncthreads();
  }
  if (t == 255) bsum[b] = lds[255];
  int run = lds[t] - tot;
#pragma unroll
  for (int j = 0; j < 4; ++j) {
    if (base + j < NBIN) csroff[base + j] = run;
    run += v[j];
  }
}
__global__ __launch_bounds__(256) void scan2(int* __restrict__ bsum) {
  __shared__ int lds[256];
  int t = threadIdx.x;
  int v = (t < SCAN_BLK) ? bsum[t] : 0;
  lds[t] = v;
  __syncthreads();
  for (int off = 1; off < 256; off <<= 1) {
    int x = (t >= off) ? lds[t - off] : 0;
    __syncthreads();
    lds[t] += x;
    __syncthreads();
  }
  if (t < SCAN_BLK) bsum[t] = lds[t] - v;
}
__global__ void scan3(int* __restrict__ csroff, const int* __restrict__ bsum) {
  int i = blockIdx.x * blockDim.x + threadIdx.x;
  if (i < NBIN) csroff[i] += bsum[i >> 10];
  if (i == 0) csroff[NBIN] = NE;
}
__global__ void scatter_bin(const int* __restrict__ ei, const int* __restrict__ et,
                            const int* __restrict__ csroff, int* __restrict__ cur,
                            int* __restrict__ elist) {
  int e = blockIdx.x * blockDim.x + threadIdx.x;
  if (e >= NE) return;
  int bin = et[e] * NN + ei[NE + e];
  int p = atomicAdd(&cur[bin], 1);
  elist[csroff[bin] + p] = e;
}
// DETERMINISM: atomic scatter order varies call-to-call (cold vs warm caches);
// sorting each bin's edge ids makes elist (and all downstream fp orders) call-invariant.
__global__ void sort_bins(const int* __restrict__ csroff, int* __restrict__ elist) {
  int b = blockIdx.x * blockDim.x + threadIdx.x;
  if (b >= NBIN) return;
  int s = csroff[b], e = csroff[b + 1];
  for (int i = s + 1; i < e; ++i) {
    int key = elist[i];
    int j = i - 1;
    while (j >= s && elist[j] > key) { elist[j + 1] = elist[j]; --j; }
    elist[j + 1] = key;
  }
}
__global__ void gather_edge(const int* __restrict__ ei, const int* __restrict__ elist,
                            const float* __restrict__ eattr,
                            int* __restrict__ rsrc, float* __restrict__ eacsr) {
  int p = blockIdx.x * blockDim.x + threadIdx.x;
  if (p >= NE) return;
  int e = elist[p];
  rsrc[p] = ei[e];
  const float4* s = (const float4*)(eattr + (size_t)e * NEA);
  float4* d = (float4*)(eacsr + (size_t)p * NEA);
#pragma unroll
  for (int j = 0; j < 4; ++j) d[j] = s[j];
}
// per-rel solo (deg==1: src,dst precomputed) + hot (deg>=2) lists.
// List ORDER is nondeterministic but numerically neutral (each dst independent).
__global__ __launch_bounds__(256) void build_hot(
    const int* __restrict__ csroff, const int* __restrict__ rsrc,
    int* __restrict__ nsolo, int* __restrict__ nhot,
    int* __restrict__ solosrc, int* __restrict__ solodst, int* __restrict__ hotlist) {
  __shared__ int wsc[4][4], whc[4][4];
  __shared__ int sbase[4], hbase[4];
  int t = threadIdx.x, wave = t >> 6, lane = t & 63;
  int b = blockIdx.x * 256 + t;
  bool valid = b < NBIN;
  int cnt = 0, rel = 0, s = 0;
  if (valid) { s = csroff[b]; cnt = csroff[b + 1] - s; rel = b / NN; }
  bool solo = valid && cnt == 1;
  bool hot = valid && cnt >= 2;
#pragma unroll
  for (int rr = 0; rr < 4; ++rr) {
    unsigned long long ms = __ballot(solo && rel == rr);
    unsigned long long mh = __ballot(hot && rel == rr);
    if (lane == 0) { wsc[wave][rr] = __popcll(ms); whc[wave][rr] = __popcll(mh); }
  }
  __syncthreads();
  if (t < 4) {
    int ssum = wsc[0][t] + wsc[1][t] + wsc[2][t] + wsc[3][t];
    int hsum = whc[0][t] + whc[1][t] + whc[2][t] + whc[3][t];
    sbase[t] = ssum ? atomicAdd(&nsolo[t * 16], ssum) : 0;
    hbase[t] = hsum ? atomicAdd(&nhot[t * 16], hsum) : 0;
  }
  __syncthreads();
#pragma unroll
  for (int rr = 0; rr < 4; ++rr) {
    unsigned long long ms = __ballot(solo && rel == rr);
    if (solo && rel == rr) {
      int before = 0;
#pragma unroll
      for (int wv = 0; wv < 4; ++wv) if (wv < wave) before += wsc[wv][rr];
      int pos = sbase[rr] + before + __popcll(ms & ((1ull << lane) - 1ull));
      solosrc[rr * NN + pos] = rsrc[s];
      solodst[rr * NN + pos] = b - rr * NN;
    }
    unsigned long long mh = __ballot(hot && rel == rr);
    if (hot && rel == rr) {
      int before = 0;
#pragma unroll
      for (int wv = 0; wv < 4; ++wv) if (wv < wave) before += whc[wv][rr];
      int pos = hbase[rr] + before + __popcll(mh & ((1ull << lane) - 1ull));
      hotlist[rr * NN + pos] = b - rr * NN;
    }
  }
}

__global__ void gate_cb(const float* __restrict__ rg, const float* __restrict__ cbias,
                        float* __restrict__ gate, float* __restrict__ cb) {
  __shared__ float g[NR];
  int t = threadIdx.x;
  if (t == 0) {
    float mx = rg[0];
    for (int r = 1; r < NR; ++r) mx = fmaxf(mx, rg[r]);
    float s = 0.f, tmp[NR];
    for (int r = 0; r < NR; ++r) { tmp[r] = expf(rg[r] - mx); s += tmp[r]; }
    for (int r = 0; r < NR; ++r) { g[r] = tmp[r] / s; gate[r] = g[r]; }
  }
  __syncthreads();
  float c = 0.f;
  for (int r = 0; r < NR; ++r) c += g[r] * cbias[r * HID + t];
  cb[t] = c;
}

// ---- deg==1 dsts: softmax weight == 1 exactly. One WAVE per dst, no sync. ----
__global__ __launch_bounds__(256) void edge_solo(
    const int* __restrict__ solosrc, const int* __restrict__ solodst,
    const int* __restrict__ nsolo, const unsigned short* __restrict__ xlb,
    float* __restrict__ hmsg, const float* __restrict__ gate,
    int rel, int HP, int stride) {
  int wave = threadIdx.x >> 6, lane = threadIdx.x & 63;
  float g4 = gate[rel] * 0.25f;
  int nw = nsolo[rel * 16];
  for (int i = blockIdx.x * 4 + wave; i < nw; i += gridDim.x * 4) {
    int src = solosrc[rel * NN + i];
    int dst = solodst[rel * NN + i];
    const unsigned short* xp = xlb + (size_t)src * stride;
    float v0 = 0.f, v1 = 0.f;
    for (int h = 0; h < HP; ++h) {
      v0 += b2f(xp[h * 128 + lane]);
      v1 += b2f(xp[h * 128 + 64 + lane]);
    }
    hmsg[(size_t)dst * HID + lane] += g4 * v0;
    hmsg[(size_t)dst * HID + 64 + lane] += g4 * v1;
  }
}

// ---- deg>=2 dsts: block per dst, online softmax over SORTED csr order. ----
__global__ __launch_bounds__(256) void edge_hot(
    const int* __restrict__ csroff, const int* __restrict__ rsrc,
    const float* __restrict__ eacsr, const float* __restrict__ relembp,
    const float* __restrict__ wedgep, const float* __restrict__ attwp,
    const unsigned short* __restrict__ xlb, const unsigned short* __restrict__ xrh,
    const int* __restrict__ hotlist, const int* __restrict__ nhot,
    float* __restrict__ hmsg, const float* __restrict__ gate,
    int rel, int HP, int stride) {
  __shared__ float lds[4][128];
  int wave = threadIdx.x >> 6, lane = threadIdx.x & 63;
  bool act = wave < HP;
  int hh = act ? wave : 0;
  float wreg[2][24], areg[2];
#pragma unroll
  for (int j = 0; j < 2; ++j) {
    int col = hh * 128 + j * 64 + lane;
    const float* wp = wedgep + (size_t)col * 24;
#pragma unroll
    for (int k = 0; k < 24; ++k) wreg[j][k] = wp[k];
    areg[j] = attwp[col];
  }
  float evr0 = 0.f, evr1 = 0.f;
#pragma unroll
  for (int k = 0; k < 8; ++k) {
    float rk = relembp[k];
    evr0 += rk * wreg[0][NEA + k];
    evr1 += rk * wreg[1][NEA + k];
  }
  float g4 = gate[rel] * 0.25f;
  int nh = nhot[rel * 16];
  for (int wi = blockIdx.x; wi < nh; wi += gridDim.x) {
    int dst = hotlist[rel * NN + wi];
    int s = csroff[rel * NN + dst], e = csroff[rel * NN + dst + 1];
    if (act) {
      const unsigned short* xrp = xrh + (size_t)wi * stride;
      float xr0 = b2f(xrp[hh * 128 + lane]);
      float xr1 = b2f(xrp[hh * 128 + 64 + lane]);
      float m = -3.4e38f, den = 0.f, acc0 = 0.f, acc1 = 0.f;
      for (int p = s; p < e; ++p) {
        int src = rsrc[p];
        const float* eap = eacsr + (size_t)p * NEA;
        float er[NEA];
#pragma unroll
        for (int k = 0; k < NEA; ++k) er[k] = eap[k];
        float eev0 = evr0, eev1 = evr1;
#pragma unroll
        for (int k = 0; k < NEA; ++k) { eev0 += er[k] * wreg[0][k]; eev1 += er[k] * wreg[1][k]; }
        float xl0 = b2f(xlb[(size_t)src * stride + hh * 128 + lane]);
        float xl1 = b2f(xlb[(size_t)src * stride + hh * 128 + 64 + lane]);
        float s0 = xl0 + xr0 + eev0; s0 = (s0 > 0.f) ? s0 : 0.2f * s0;
        float s1 = xl1 + xr1 + eev1; s1 = (s1 > 0.f) ? s1 : 0.2f * s1;
        float lg = s0 * areg[0] + s1 * areg[1];
#pragma unroll
        for (int o = 32; o > 0; o >>= 1) lg += __shfl_xor(lg, o, 64);
        float mn = fmaxf(m, lg);
        float sc = expf(m - mn);
        float ex = expf(lg - mn);
        den = den * sc + ex;
        acc0 = acc0 * sc + ex * xl0;
        acc1 = acc1 * sc + ex * xl1;
        m = mn;
      }
      float w = g4 / den;
      lds[wave][lane] = acc0 * w;
      lds[wave][64 + lane] = acc1 * w;
    }
    __syncthreads();
    if (wave < 2) {
      int d = wave * 64 + lane;
      float v = 0.f;
      for (int h = 0; h < HP; ++h) v += lds[h][d];
      hmsg[(size_t)dst * HID + d] += v;
    }
    __syncthreads();
  }
}

// ---- h = layernorm(h + add (+ cb)); also emits bf16 copy ----
__global__ __launch_bounds__(256) void add_ln(
    float* __restrict__ h, const float* __restrict__ add, const float* __restrict__ cb,
    const float* __restrict__ w, const float* __restrict__ b,
    unsigned short* __restrict__ hbf, int nrows) {
  int wave = threadIdx.x >> 6, lane = threadIdx.x & 63;
  int row = blockIdx.x * 4 + wave;
  if (row >= nrows) return;
  size_t base = (size_t)row * HID;
  float x0 = h[base + lane] + add[base + lane];
  float x1 = h[base + 64 + lane] + add[base + 64 + lane];
  if (cb) { x0 += cb[lane]; x1 += cb[64 + lane]; }
  float s = x0 + x1;
#pragma unroll
  for (int o = 32; o > 0; o >>= 1) s += __shfl_xor(s, o, 64);
  float mean = s * (1.f / 128.f);
  float d0 = x0 - mean, d1 = x1 - mean;
  float v = d0 * d0 + d1 * d1;
#pragma unroll
  for (int o = 32; o > 0; o >>= 1) v += __shfl_xor(v, o, 64);
  float inv = 1.f / sqrtf(v * (1.f / 128.f) + 1e-5f);
  float y0 = d0 * inv * w[lane] + b[lane];
  float y1 = d1 * inv * w[64 + lane] + b[64 + lane];
  h[base + lane] = y0;
  h[base + 64 + lane] = y1;
  hbf[base + lane] = f2b(y0);
  hbf[base + 64 + lane] = f2b(y1);
}

// ---- readout: DETERMINISTIC. group starts via binary search (batch sorted),
// fixed partial slots [g][8][dim], fixed-order combine. No atomics. ----
__global__ void group_bounds(const int* __restrict__ batch, int* __restrict__ gstart) {
  int g = threadIdx.x + blockIdx.x * blockDim.x;
  if (g > NG) return;
  int lo = 0, hi = NN;
  while (lo < hi) {
    int mid = (lo + hi) >> 1;
    if (batch[mid] < g) lo = mid + 1; else hi = mid;
  }
  gstart[g] = lo;
}
__global__ __launch_bounds__(128) void readout_part2(
    const float* __restrict__ h, const int* __restrict__ gstart,
    float* __restrict__ psum, float* __restrict__ pmax) {
  int g = blockIdx.x, s = blockIdx.y, t = threadIdx.x;
  int r0 = gstart[g], r1 = gstart[g + 1];
  float acc = 0.f, mx = -3.4e38f;
  for (int row = r0 + s; row < r1; row += 8) {
    float v = h[(size_t)row * HID + t];
    acc += v;
    mx = fmaxf(mx, v);
  }
  psum[((size_t)g * 8 + s) * HID + t] = acc;
  pmax[((size_t)g * 8 + s) * HID + t] = mx;
}
__global__ __launch_bounds__(256) void readout_final(
    const int* __restrict__ gstart, const float* __restrict__ psum,
    const float* __restrict__ pmax, const float* __restrict__ w,
    const float* __restrict__ b, float* __restrict__ g) {
  int bg = blockIdx.x, t = threadIdx.x;
  __shared__ float red[256];
  float c = fmaxf((float)(gstart[bg + 1] - gstart[bg]), 1.f);
  float x;
  if (t < HID) {
    float ssum = 0.f;
    for (int s = 0; s < 8; ++s) ssum += psum[((size_t)bg * 8 + s) * HID + t];
    x = ssum / c;
  } else {
    float mx = -3.4e38f;
    for (int s = 0; s < 8; ++s) mx = fmaxf(mx, pmax[((size_t)bg * 8 + s) * HID + (t - HID)]);
    x = mx;
  }
  red[t] = x;
  __syncthreads();
  for (int s = 128; s > 0; s >>= 1) {
    if (t < s) red[t] += red[t + s];
    __syncthreads();
  }
  float mean = red[0] * (1.f / 256.f);
  __syncthreads();
  float d = x - mean;
  red[t] = d * d;
  __syncthreads();
  for (int s = 128; s > 0; s >>= 1) {
    if (t < s) red[t] += red[t + s];
    __syncthreads();
  }
  float inv = 1.f / sqrtf(red[0] * (1.f / 256.f) + 1e-5f);
  g[(size_t)bg * 256 + t] = d * inv * w[t] + b[t];
}

__device__ __forceinline__ void bspline8(float x, const float* __restrict__ t,
                                         float* __restrict__ out) {
  float bs[11];
#pragma unroll
  for (int j = 0; j < 11; ++j) bs[j] = (x >= t[j] && x < t[j + 1]) ? 1.f : 0.f;
#pragma unroll
  for (int k = 1; k <= 3; ++k) {
    for (int j = 0; j < 11 - k; ++j) {
      bs[j] = (x - t[j]) / (t[j + k] - t[j]) * bs[j] +
              (t[j + k + 1] - x) / (t[j + k + 1] - t[j + 1]) * bs[j + 1];
    }
  }
#pragma unroll
  for (int j = 0; j < 8; ++j) out[j] = bs[j];
}

// ---- KAN1, K-chunked into fixed partial slots (deterministic, no atomics) ----
__global__ __launch_bounds__(128) void kan1_part(
    const float* __restrict__ g, const float* __restrict__ bw,
    const float* __restrict__ sw, const float* __restrict__ sc,
    const float* __restrict__ grid, float* __restrict__ zpart) {
  int bg = blockIdx.x, ch = blockIdx.y, t = threadIdx.x;
  int base = ch * 32;
  __shared__ float B[32][8];
  __shared__ float sg[32];
  if (t < 32) {
    float x = g[(size_t)bg * 256 + base + t];
    sg[t] = x / (1.f + expf(-x));
    bspline8(x, grid + (size_t)(base + t) * 12, B[t]);
  }
  __syncthreads();
  float acc = 0.f;
  for (int i = 0; i < 32; ++i) {
    int col = base + i;
    acc += sg[i] * bw[(size_t)t * 256 + col];
    const float* swp = sw + ((size_t)t * 256 + col) * 8;
    float sp = 0.f;
#pragma unroll
    for (int k = 0; k < 8; ++k) sp += B[i][k] * swp[k];
    acc += sp * sc[(size_t)t * 256 + col];
  }
  zpart[((size_t)ch * NG + bg) * KH + t] = acc;
}

__global__ __launch_bounds__(128) void kan2(
    const float* __restrict__ zpart, const float* __restrict__ bw,
    const float* __restrict__ sw, const float* __restrict__ sc,
    const float* __restrict__ grid, float* __restrict__ out) {
  int bg = blockIdx.x, t = threadIdx.x;
  __shared__ float B[128][8];
  __shared__ float sz[128];
  float x = 0.f;
  for (int ch = 0; ch < 8; ++ch) x += zpart[((size_t)ch * NG + bg) * KH + t];
  sz[t] = x / (1.f + expf(-x));
  bspline8(x, grid + (size_t)t * 12, B[t]);
  __syncthreads();
  if (t < NC) {
    float acc = 0.f;
    for (int i = 0; i < 128; ++i) {
      acc += sz[i] * bw[(size_t)t * 128 + i];
      const float* swp = sw + ((size_t)t * 128 + i) * 8;
      float sp = 0.f;
#pragma unroll
      for (int k = 0; k < 8; ++k) sp += B[i][k] * swp[k];
      acc += sp * sc[(size_t)t * 128 + i];
    }
    out[(size_t)bg * NC + t] = acc;
  }
}

extern "C" void kernel_launch(void* const* d_in, const int* in_sizes, int n_in,
                              void* d_out, int out_size, void* d_ws, size_t ws_size,
                              hipStream_t stream) {
  const float* x       = (const float*)d_in[0];
  const float* eattr   = (const float*)d_in[1];
  const int*   idtok   = (const int*)d_in[2];
  const int*   ei      = (const int*)d_in[3];
  const int*   etype   = (const int*)d_in[4];
  const int*   batch   = (const int*)d_in[5];
  const float* idemb   = (const float*)d_in[6];
  const float* inw     = (const float*)d_in[7];
  const float* inb     = (const float*)d_in[8];
  const float* relemb  = (const float*)d_in[9];
  const float* linlw   = (const float*)d_in[10];
  const float* linlb   = (const float*)d_in[11];
  const float* linrw   = (const float*)d_in[12];
  const float* linrb   = (const float*)d_in[13];
  const float* linew   = (const float*)d_in[14];
  const float* attw    = (const float*)d_in[15];
  const float* convb   = (const float*)d_in[16];
  const float* relgate = (const float*)d_in[17];
  const float* n1w     = (const float*)d_in[18];
  const float* n1b     = (const float*)d_in[19];
  const float* n2w     = (const float*)d_in[20];
  const float* n2b     = (const float*)d_in[21];
  const float* f1w     = (const float*)d_in[22];
  const float* f1bias  = (const float*)d_in[23];
  const float* f2w     = (const float*)d_in[24];
  const float* f2bias  = (const float*)d_in[25];
  const float* rnw     = (const float*)d_in[26];
  const float* rnb     = (const float*)d_in[27];
  const float* bw1     = (const float*)d_in[28];
  const float* sw1     = (const float*)d_in[29];
  const float* sc1     = (const float*)d_in[30];
  const float* grid1   = (const float*)d_in[31];
  const float* bw2     = (const float*)d_in[32];
  const float* sw2     = (const float*)d_in[33];
  const float* sc2     = (const float*)d_in[34];
  const float* grid2   = (const float*)d_in[35];
  float* out = (float*)d_out;
  (void)in_sizes; (void)n_in; (void)out_size;

  auto needed = [](int HP) -> size_t {
    auto al = [](size_t b) { return (b + 255) & ~(size_t)255; };
    size_t o = 0;
    o += al((size_t)NN * HID * 4) * 2;            // h, hmsg
    o += al((size_t)NN * HID * 2);                // hbf
    o += al((size_t)NN * 128 * HP * 2) * 2;       // xlb, xrh
    o += al((size_t)NE * 4) * 2;                  // elist, rsrc
    o += al((size_t)NE * NEA * 4);                // eacsr
    o += al((size_t)NBIN * 8 + 8);                // bcnt+cur
    o += al((size_t)(NBIN + 1) * 4);              // csroff
    o += al((size_t)SCAN_BLK * 4);                // bsum
    o += al((size_t)NR * NN * 4) * 3;             // hotlist, solosrc, solodst
    o += al(512);                                 // padded counters
    o += al((size_t)NL * NR * 512 * 128 * 2) * 2; // linlwb, linrwb
    o += al((size_t)NL * 256 * 128 * 2) * 2;      // f1wb, f2wb
    o += al((size_t)128 * 96 * 2);                // inwb
    o += al(NR * 4) + al(HID * 4);
    o += al((size_t)(NG + 1) * 4);                // gstart
    o += al((size_t)NG * 8 * HID * 4) * 2;        // psum, pmax
    o += al((size_t)8 * NG * KH * 4);             // zpart
    o += al((size_t)NG * 256 * 4);                // g
    return o;
  };
  const int HP = (needed(4) <= ws_size) ? 4 : 2;
  const int passes = NH / HP;
  const int stride = HP * 128;

  char* p = (char*)d_ws;
  auto alloc = [&](size_t bytes) { void* q = (void*)p; p += (bytes + 255) & ~(size_t)255; return q; };
  float* h    = (float*)alloc((size_t)NN * HID * 4);
  float* hmsg = (float*)alloc((size_t)NN * HID * 4);
  unsigned short* hbf = (unsigned short*)alloc((size_t)NN * HID * 2);
  unsigned short* xlb = (unsigned short*)alloc((size_t)NN * 128 * HP * 2);
  unsigned short* xrh = (unsigned short*)alloc((size_t)NN * 128 * HP * 2);
  int* elist = (int*)alloc((size_t)NE * 4);
  int* rsrc  = (int*)alloc((size_t)NE * 4);
  float* eacsr = (float*)alloc((size_t)NE * NEA * 4);
  int* bcnt  = (int*)alloc((size_t)NBIN * 8 + 8);
  int* cur   = bcnt + NBIN;
  int* csroff = (int*)alloc((size_t)(NBIN + 1) * 4);
  int* bsum  = (int*)alloc((size_t)SCAN_BLK * 4);
  int* hotlist = (int*)alloc((size_t)NR * NN * 4);
  int* solosrc = (int*)alloc((size_t)NR * NN * 4);
  int* solodst = (int*)alloc((size_t)NR * NN * 4);
  int* cnts    = (int*)alloc(512);   // nsolo[r*16], nhot[64 + r*16] (padded)
  int* nsolo   = cnts;
  int* nhot    = cnts + 64;
  unsigned short* linlwb = (unsigned short*)alloc((size_t)NL * NR * 512 * 128 * 2);
  unsigned short* linrwb = (unsigned short*)alloc((size_t)NL * NR * 512 * 128 * 2);
  unsigned short* f1wb   = (unsigned short*)alloc((size_t)NL * 256 * 128 * 2);
  unsigned short* f2wb   = (unsigned short*)alloc((size_t)NL * 128 * 256 * 2);
  unsigned short* inwb   = (unsigned short*)alloc((size_t)128 * 96 * 2);
  float* gate = (float*)alloc(NR * 4);
  float* cb   = (float*)alloc(HID * 4);
  int* gstart = (int*)alloc((size_t)(NG + 1) * 4);
  float* psum = (float*)alloc((size_t)NG * 8 * HID * 4);
  float* pmax = (float*)alloc((size_t)NG * 8 * HID * 4);
  float* zpart = (float*)alloc((size_t)8 * NG * KH * 4);
  float* g = (float*)alloc((size_t)NG * 256 * 4);
  unsigned short* xinbf = xlb;
  unsigned short* f1buf = xlb;

  const int NB = (NN + 127) / 128;
  const int RPX = (NB + 7) / 8;

  {
    int n;
    n = NL * NR * 512 * 128 / 4;
    cvt_bf16<<<(n + 255) / 256, 256, 0, stream>>>(linlw, linlwb, n);
    cvt_bf16<<<(n + 255) / 256, 256, 0, stream>>>(linrw, linrwb, n);
    n = NL * 256 * 128 / 4;
    cvt_bf16<<<(n + 255) / 256, 256, 0, stream>>>(f1w, f1wb, n);
    cvt_bf16<<<(n + 255) / 256, 256, 0, stream>>>(f2w, f2wb, n);
    n = 128 * 96 / 4;
    cvt_bf16<<<(n + 255) / 256, 256, 0, stream>>>(inw, inwb, n);
  }

  hipMemsetAsync(bcnt, 0, (size_t)NBIN * 8 + 8, stream);
  hipMemsetAsync(cnts, 0, 512, stream);
  hist_bin<<<(NE + 255) / 256, 256, 0, stream>>>(ei, etype, bcnt);
  scan1<<<SCAN_BLK, 256, 0, stream>>>(bcnt, csroff, bsum);
  scan2<<<1, 256, 0, stream>>>(bsum);
  scan3<<<(NBIN + 256) / 256, 256, 0, stream>>>(csroff, bsum);
  scatter_bin<<<(NE + 255) / 256, 256, 0, stream>>>(ei, etype, csroff, cur, elist);
  sort_bins<<<(NBIN + 255) / 256, 256, 0, stream>>>(csroff, elist);
  gather_edge<<<(NE + 255) / 256, 256, 0, stream>>>(ei, elist, eattr, rsrc, eacsr);
  build_hot<<<(NBIN + 255) / 256, 256, 0, stream>>>(csroff, rsrc, nsolo, nhot,
                                                    solosrc, solodst, hotlist);

  build_xin_bf<<<(NN * 96 + 255) / 256, 256, 0, stream>>>(x, idtok, idemb, xinbf);
  gemm_bf16<<<8 * RPX, 256, 0, stream>>>(xinbf, inwb, inb, h, nullptr, NN, 96, 128, 1, 1);
  cvt_bf16<<<(NN * HID / 4 + 255) / 256, 256, 0, stream>>>(h, hbf, NN * HID / 4);

  for (int l = 0; l < NL; ++l) {
    gate_cb<<<1, 128, 0, stream>>>(relgate + l * NR, convb + (size_t)l * NR * HID, gate, cb);
    hipMemsetAsync(hmsg, 0, (size_t)NN * HID * 4, stream);
    for (int r = 0; r < NR; ++r) {
      int lr = l * NR + r;
      for (int hp = 0; hp < passes; ++hp) {
        int hpBase = hp * HP;
        const unsigned short* wl = linlwb + ((size_t)lr * 512 + hpBase * 128) * 128;
        const unsigned short* wr = linrwb + ((size_t)lr * 512 + hpBase * 128) * 128;
        const float* bl = linlb + (size_t)lr * 512 + hpBase * 128;
        const float* br = linrb + (size_t)lr * 512 + hpBase * 128;
        gemm_bf16<<<8 * RPX * HP, 256, 0, stream>>>(hbf, wl, bl, nullptr, xlb,
                                                    NN, 128, stride, 0, HP);
        gemm_rows<<<NB * HP, 256, 0, stream>>>(hbf, hotlist + (size_t)r * NN, nhot + r * 16,
                                               wr, br, xrh, 128, stride, HP);
        edge_solo<<<2048, 256, 0, stream>>>(solosrc, solodst, nsolo, xlb, hmsg,
                                            gate, r, HP, stride);
        edge_hot<<<4096, 256, 0, stream>>>(
            csroff, rsrc, eacsr, relemb + (size_t)lr * RED,
            linew + ((size_t)lr * 512 + hpBase * 128) * 24,
            attw + (size_t)lr * 512 + hpBase * 128,
            xlb, xrh, hotlist, nhot, hmsg, gate, r, HP, stride);
      }
    }
    add_ln<<<(NN + 3) / 4, 256, 0, stream>>>(h, hmsg, cb, n1w + l * HID, n1b + l * HID, hbf, NN);
    gemm_bf16<<<8 * RPX * 2, 256, 0, stream>>>(hbf, f1wb + (size_t)l * 256 * 128,
                                               f1bias + (size_t)l * 256, nullptr, f1buf,
                                               NN, 128, 256, 1, 2);
    gemm_bf16<<<8 * RPX, 256, 0, stream>>>(f1buf, f2wb + (size_t)l * 128 * 256,
                                           f2bias + (size_t)l * 128, hmsg, nullptr,
                                           NN, 256, 128, 0, 1);
    add_ln<<<(NN + 3) / 4, 256, 0, stream>>>(h, hmsg, nullptr, n2w + l * HID, n2b + l * HID, hbf, NN);
  }

  group_bounds<<<1, 128, 0, stream>>>(batch, gstart);
  readout_part2<<<dim3(NG, 8), 128, 0, stream>>>(h, gstart, psum, pmax);
  readout_final<<<NG, 256, 0, stream>>>(gstart, psum, pmax, rnw, rnb, g);
  kan1_part<<<dim3(NG, 8), 128, 0, stream>>>(g, bw1, sw1, sc1, grid1, zpart);
  kan2<<<NG, 128, 0, stream>>>(zpart, bw2, sw2, sc2, grid2, out);
}